// Round 13
// baseline (273.610 us; speedup 1.0000x reference)
//
#include <hip/hip_runtime.h>
#include <math.h>

#define B_ 8192

typedef __attribute__((ext_vector_type(8))) short short8;
typedef __attribute__((ext_vector_type(4))) float f32x4;

// ---------------- persistent device buffers (rewritten every call) ----------------
// weights (hi/lo split bf16, stored as B^T row-major [N][K])
__device__ unsigned short g_w1bh[53248], g_w1bl[53248];    // conv1 W^T [64 oc][832 (800+pad0)], /maxv
__device__ unsigned short g_w2hi[36864],  g_w2lo[36864];   // conv2 [64][576], k'=(kx*3+ky)*64+ic
__device__ unsigned short g_fc1hi[32768], g_fc1lo[32768];  // fc1   [128][256] (k'=pos*64+oc)
__device__ unsigned short g_enchi[16384], g_enclo[16384];  // enc   [128][128]
__device__ unsigned short g_crhi[131072], g_crlo[131072];  // critic[1024][128]
__device__ unsigned short g_achi[65536],  g_aclo[65536];   // actor [512][128]
__device__ unsigned short g_qWhi[8192],   g_qWlo[8192];    // actor_W^T [16][512]
// activations (hi/lo split bf16)
__device__ unsigned short g_ACT1hi[8192*1024], g_ACT1lo[8192*1024]; // conv1 out [s][pos*64+oc]
__device__ unsigned short g_A1hi[8192*256],  g_A1lo[8192*256];  // conv2 out [s][pos*64+oc]
__device__ unsigned short g_Hhi[8192*128],   g_Hlo[8192*128];   // enc out (hidden)

__device__ __forceinline__ unsigned short f2bf(float v){
    unsigned u = __builtin_bit_cast(unsigned, v);
    unsigned r = (u + 0x7fffu + ((u >> 16) & 1u)) >> 16;   // RN-even (finite inputs)
    return (unsigned short)r;
}
__device__ __forceinline__ float bf2f(unsigned short h){
    unsigned u = ((unsigned)h) << 16;
    return __builtin_bit_cast(float, u);
}
__device__ __forceinline__ void split_store(float v, unsigned short* hi, unsigned short* lo){
    unsigned short h = f2bf(v);
    *hi = h;
    *lo = f2bf(v - bf2f(h));
}

// ---------------- prep: transpose + split all weights ----------------
__global__ __launch_bounds__(256) void prep_kernel(
    const float* __restrict__ w1, const float* __restrict__ maxv,
    const float* __restrict__ w2, const float* __restrict__ fc1,
    const float* __restrict__ enc, const float* __restrict__ cr,
    const float* __restrict__ ac, const float* __restrict__ aW)
{
    int d = blockIdx.x * 256 + threadIdx.x;
    if (d < 53248){
        int n = d / 832, k = d - n*832;
        float v = 0.f;
        if (k < 800){ int l = k / 25; v = w1[n*800 + k] / maxv[l]; }
        split_store(v, &g_w1bh[d], &g_w1bl[d]);
        return;
    }
    d -= 53248;
    if (d < 36864){
        int oc = d / 576, k2 = d - oc*576;
        int kxy = k2 >> 6, ic = k2 & 63;               // k' = kxy*64 + ic
        split_store(w2[oc*576 + ic*9 + kxy], &g_w2hi[d], &g_w2lo[d]);
        return;
    }
    d -= 36864;
    if (d < 32768){
        int o = d >> 8, kp = d & 255;                  // k' = pos*64+oc
        split_store(fc1[o*256 + (kp & 63)*4 + (kp >> 6)], &g_fc1hi[d], &g_fc1lo[d]);
        return;
    }
    d -= 32768;
    if (d < 16384){ split_store(enc[d], &g_enchi[d], &g_enclo[d]); return; }
    d -= 16384;
    if (d < 131072){ split_store(cr[d], &g_crhi[d], &g_crlo[d]); return; }
    d -= 131072;
    if (d < 65536){ split_store(ac[d], &g_achi[d], &g_aclo[d]); return; }
    d -= 65536;
    { int e = d >> 9, j = d & 511; split_store(aW[j*16 + e], &g_qWhi[d], &g_qWlo[d]); }
}

// ---------------- conv1: scatter -> bf16 im2col A-tile in LDS -> split-K MFMA GEMM --------
// 2 samples/block, 512 threads (8 waves). Wave = (kh, ng): kh owns a 416-element K-half
// (K padded to 832 with zero B), ng owns 16 N-cols; both m-tiles per B-load; 2-deep
// B prefetch; partials reduced via LDS. 16 waves/CU at 2 blocks/CU.
#define APITCH 840   // 832 + 8 shorts pad
__global__ __launch_bounds__(512) void conv1_kernel(const int* __restrict__ obs,
                                                    const float* __restrict__ b1)
{
    const int b = blockIdx.x;                 // samples b*2, b*2+1
    const int tid = threadIdx.x;
    const int wave = tid >> 6, lane = tid & 63;
    const int l15 = lane & 15, lhi = lane >> 4;

    __shared__ unsigned short sA[32 * APITCH];      // 53.8 KB
    __shared__ float pf[32][68];                    // 8.7 KB partial-sum buffer
    __shared__ int s_cell[2][200];

    // zero the FULL A-tile: 32*APITCH shorts = 4*APITCH short8s (was halved in R12 - bug)
    for (int i = tid; i < 4 * APITCH; i += 512)
        *(short8*)&sA[i * 8] = short8{0,0,0,0,0,0,0,0};

    int my_cell = 0, my_x = 0, my_y = 0, my_l = 0;
    float my_val = 0.f;
    bool my_valid = false;
    if (tid < 400){
        const int si = (tid >= 200) ? 1 : 0;
        const int k  = tid - si*200;
        const int base = (b*2 + si)*600 + k*3;
        int coord = obs[base], atr = obs[base+1], val = obs[base+2];
        my_valid = (coord != 255) && (atr < 32);
        my_x = (coord >> 4) & 15;  my_y = coord & 15;  my_l = atr;
        my_cell = my_valid ? (atr*256 + my_x*16 + my_y) : 0;   // invalid claims cell 0
        my_val  = (float)val;
        s_cell[si][k] = my_cell;
    }
    __syncthreads();
    if (tid < 400){
        const int si = (tid >= 200) ? 1 : 0;
        const int k  = tid - si*200;
        bool kept = true;
        #pragma unroll 4
        for (int j = 0; j < 200; j++){
            int cj = s_cell[si][j];
            kept &= (j <= k) | (cj != my_cell);
        }
        if (kept && my_valid){
            const int x3 = my_x/3, rx = my_x - 3*x3;
            const int y3 = my_y/3, ry = my_y - 3*y3;
            const unsigned short hv = f2bf(my_val);      // exact (integer <= 255)
            #pragma unroll
            for (int d = 0; d < 4; d++){
                const int dxd = d >> 1, dyd = d & 1;
                const int ox = x3 - dxd, oy = y3 - dyd;
                const int wx = rx + 3*dxd, wy = ry + 3*dyd;
                if (((unsigned)ox <= 3u) && ((unsigned)oy <= 3u) && (wx < 5) && (wy < 5))
                    sA[((tid >= 200 ? 16 : 0) + ox*4 + oy)*APITCH + my_l*25 + wx*5 + wy] = hv;
            }
        }
    }
    __syncthreads();

    // MFMA: wave (kh, ng); 13 chunks of K=32 each half (second half ends in zero pad)
    const int kh = wave >> 2, ng = wave & 3;
    const int n = ng*16 + l15;
    const int kbase = kh * 416;
    const unsigned short* Bh = &g_w1bh[n*832 + kbase];
    const unsigned short* Bl = &g_w1bl[n*832 + kbase];
    const unsigned short* A0 = &sA[l15*APITCH + kbase];
    const unsigned short* A1 = &sA[(16 + l15)*APITCH + kbase];
    f32x4 acc0 = {0,0,0,0}, acc1 = {0,0,0,0};
    short8 bh0 = *(const short8*)&Bh[lhi*8];
    short8 bl0 = *(const short8*)&Bl[lhi*8];
    short8 bh1 = *(const short8*)&Bh[32 + lhi*8];
    short8 bl1 = *(const short8*)&Bl[32 + lhi*8];
    #pragma unroll
    for (int kc = 0; kc < 13; kc++){
        const int kk = kc*32 + lhi*8;
        short8 a0 = *(const short8*)&A0[kk];
        short8 a1 = *(const short8*)&A1[kk];
        short8 bhn, bln;
        if (kc < 11){
            bhn = *(const short8*)&Bh[kk + 64];
            bln = *(const short8*)&Bl[kk + 64];
        }
        acc0 = __builtin_amdgcn_mfma_f32_16x16x32_bf16(a0, bh0, acc0, 0, 0, 0);
        acc1 = __builtin_amdgcn_mfma_f32_16x16x32_bf16(a1, bh0, acc1, 0, 0, 0);
        acc0 = __builtin_amdgcn_mfma_f32_16x16x32_bf16(a0, bl0, acc0, 0, 0, 0);
        acc1 = __builtin_amdgcn_mfma_f32_16x16x32_bf16(a1, bl0, acc1, 0, 0, 0);
        bh0 = bh1; bl0 = bl1; bh1 = bhn; bl1 = bln;
    }
    // reduce the two K-halves via LDS
    if (kh == 0){
        #pragma unroll
        for (int j = 0; j < 4; j++){
            pf[lhi*4 + j][n]      = acc0[j];
            pf[16 + lhi*4 + j][n] = acc1[j];
        }
    }
    __syncthreads();
    if (kh == 1){
        #pragma unroll
        for (int j = 0; j < 4; j++){
            pf[lhi*4 + j][n]      += acc0[j];
            pf[16 + lhi*4 + j][n] += acc1[j];
        }
    }
    __syncthreads();
    // epilogue: bias + relu + split-store (coalesced)
    #pragma unroll
    for (int u = 0; u < 4; u++){
        const int o = tid + u*512;            // o = row*64 + col, row = si*16 + pos
        const int row = o >> 6, col = o & 63;
        float v = fmaxf(pf[row][col] + b1[col], 0.f);
        unsigned short h = f2bf(v);
        const int gi = (b*2 + (row >> 4))*1024 + (row & 15)*64 + col;
        g_ACT1hi[gi] = h;
        g_ACT1lo[gi] = f2bf(v - bf2f(h));
    }
}

// ---------------- conv2: im2col-on-load MFMA GEMM (M=32768, N=64, K=576) ----------------
__global__ __launch_bounds__(256) void conv2_kernel(const float* __restrict__ bias)
{
    const int r0 = blockIdx.x * 64;                      // 16 samples x 4 pos
    const int tid = threadIdx.x, wave = tid >> 6, lane = tid & 63;
    const int l15 = lane & 15, lhi = lane >> 4;

    __shared__ unsigned short sAhi[64][72];
    __shared__ unsigned short sAlo[64][72];

    f32x4 acc[4] = {{0,0,0,0},{0,0,0,0},{0,0,0,0},{0,0,0,0}};
    for (int kc = 0; kc < 9; kc++){                      // (kx,ky) chunk of 64 k's
        const int kx = kc / 3, ky = kc - 3*kx;
        __syncthreads();
        #pragma unroll
        for (int u = 0; u < 2; u++){
            int unit = tid + u*256;
            int row = unit >> 3, ch8 = (unit & 7) * 8;
            int px = (row >> 1) & 1, py = row & 1;       // pos = row&3
            int cell = (px + kx)*4 + (py + ky);
            int g = ((r0 >> 2) + (row >> 2))*1024 + cell*64 + ch8;
            *(short8*)&sAhi[row][ch8] = *(const short8*)&g_ACT1hi[g];
            *(short8*)&sAlo[row][ch8] = *(const short8*)&g_ACT1lo[g];
        }
        __syncthreads();
        #pragma unroll
        for (int ks = 0; ks < 2; ks++){
            const int kk = ks*32 + lhi*8;
            short8 ah = *(const short8*)&sAhi[wave*16 + l15][kk];
            short8 al = *(const short8*)&sAlo[wave*16 + l15][kk];
            #pragma unroll
            for (int nt = 0; nt < 4; nt++){
                const int n = nt*16 + l15;
                const short8 bh = *(const short8*)&g_w2hi[n*576 + kc*64 + kk];
                const short8 bl = *(const short8*)&g_w2lo[n*576 + kc*64 + kk];
                acc[nt] = __builtin_amdgcn_mfma_f32_16x16x32_bf16(ah, bh, acc[nt], 0, 0, 0);
                acc[nt] = __builtin_amdgcn_mfma_f32_16x16x32_bf16(al, bh, acc[nt], 0, 0, 0);
                acc[nt] = __builtin_amdgcn_mfma_f32_16x16x32_bf16(ah, bl, acc[nt], 0, 0, 0);
            }
        }
    }
    #pragma unroll
    for (int nt = 0; nt < 4; nt++){
        const int col = nt*16 + l15;
        const float bb = bias[col];
        #pragma unroll
        for (int j = 0; j < 4; j++){
            const int row = r0 + wave*16 + lhi*4 + j;
            float v = fmaxf(acc[nt][j] + bb, 0.f);
            unsigned short h = f2bf(v);
            g_A1hi[row*64 + col] = h;                    // == [s][pos*64+oc]
            g_A1lo[row*64 + col] = f2bf(v - bf2f(h));
        }
    }
}

// ---------------- tailA: fc1 + enc fused (32 samples/block, chained via LDS) ----------------
__global__ __launch_bounds__(256) void tailA_kernel(const float* __restrict__ fc1b,
                                                    const float* __restrict__ encb)
{
    const int r0 = blockIdx.x * 32;
    const int tid = threadIdx.x, wave = tid >> 6, lane = tid & 63;
    const int l15 = lane & 15, lhi = lane >> 4;

    __shared__ unsigned short sA1h[32][264], sA1l[32][264];   // 33.8 KB
    __shared__ unsigned short sXh[32][136],  sXl[32][136];    // 17.4 KB

    // stage A1 [32][256] hi/lo
    for (int u = tid; u < 1024; u += 256){
        int row = u >> 5, ch8 = (u & 31) * 8;
        *(short8*)&sA1h[row][ch8] = *(const short8*)&g_A1hi[(r0+row)*256 + ch8];
        *(short8*)&sA1l[row][ch8] = *(const short8*)&g_A1lo[(r0+row)*256 + ch8];
    }
    __syncthreads();

    // fc1: M=32, N=128 (wave owns nt = 2w, 2w+1), K=256
    {
        f32x4 acc[2][2] = {{{0,0,0,0},{0,0,0,0}},{{0,0,0,0},{0,0,0,0}}}; // [t][mt]
        #pragma unroll
        for (int kk8 = 0; kk8 < 8; kk8++){
            const int kk = kk8*32 + lhi*8;
            short8 ah0 = *(const short8*)&sA1h[l15][kk];
            short8 al0 = *(const short8*)&sA1l[l15][kk];
            short8 ah1 = *(const short8*)&sA1h[16 + l15][kk];
            short8 al1 = *(const short8*)&sA1l[16 + l15][kk];
            #pragma unroll
            for (int t = 0; t < 2; t++){
                const int n = (wave*2 + t)*16 + l15;
                const short8 bh = *(const short8*)&g_fc1hi[n*256 + kk];
                const short8 bl = *(const short8*)&g_fc1lo[n*256 + kk];
                acc[t][0] = __builtin_amdgcn_mfma_f32_16x16x32_bf16(ah0, bh, acc[t][0], 0, 0, 0);
                acc[t][1] = __builtin_amdgcn_mfma_f32_16x16x32_bf16(ah1, bh, acc[t][1], 0, 0, 0);
                acc[t][0] = __builtin_amdgcn_mfma_f32_16x16x32_bf16(al0, bh, acc[t][0], 0, 0, 0);
                acc[t][1] = __builtin_amdgcn_mfma_f32_16x16x32_bf16(al1, bh, acc[t][1], 0, 0, 0);
                acc[t][0] = __builtin_amdgcn_mfma_f32_16x16x32_bf16(ah0, bl, acc[t][0], 0, 0, 0);
                acc[t][1] = __builtin_amdgcn_mfma_f32_16x16x32_bf16(ah1, bl, acc[t][1], 0, 0, 0);
            }
        }
        #pragma unroll
        for (int t = 0; t < 2; t++){
            const int col = (wave*2 + t)*16 + l15;
            const float bb = fc1b[col];
            #pragma unroll
            for (int mt = 0; mt < 2; mt++){
                #pragma unroll
                for (int j = 0; j < 4; j++){
                    const int row = mt*16 + lhi*4 + j;
                    float v = fmaxf(acc[t][mt][j] + bb, 0.f);
                    unsigned short h = f2bf(v);
                    sXh[row][col] = h;
                    sXl[row][col] = f2bf(v - bf2f(h));
                }
            }
        }
    }
    __syncthreads();

    // enc: M=32, N=128, K=128 -> H global (hi/lo)
    {
        f32x4 acc[2][2] = {{{0,0,0,0},{0,0,0,0}},{{0,0,0,0},{0,0,0,0}}};
        #pragma unroll
        for (int kk4 = 0; kk4 < 4; kk4++){
            const int kk = kk4*32 + lhi*8;
            short8 ah0 = *(const short8*)&sXh[l15][kk];
            short8 al0 = *(const short8*)&sXl[l15][kk];
            short8 ah1 = *(const short8*)&sXh[16 + l15][kk];
            short8 al1 = *(const short8*)&sXl[16 + l15][kk];
            #pragma unroll
            for (int t = 0; t < 2; t++){
                const int n = (wave*2 + t)*16 + l15;
                const short8 bh = *(const short8*)&g_enchi[n*128 + kk];
                const short8 bl = *(const short8*)&g_enclo[n*128 + kk];
                acc[t][0] = __builtin_amdgcn_mfma_f32_16x16x32_bf16(ah0, bh, acc[t][0], 0, 0, 0);
                acc[t][1] = __builtin_amdgcn_mfma_f32_16x16x32_bf16(ah1, bh, acc[t][1], 0, 0, 0);
                acc[t][0] = __builtin_amdgcn_mfma_f32_16x16x32_bf16(al0, bh, acc[t][0], 0, 0, 0);
                acc[t][1] = __builtin_amdgcn_mfma_f32_16x16x32_bf16(al1, bh, acc[t][1], 0, 0, 0);
                acc[t][0] = __builtin_amdgcn_mfma_f32_16x16x32_bf16(ah0, bl, acc[t][0], 0, 0, 0);
                acc[t][1] = __builtin_amdgcn_mfma_f32_16x16x32_bf16(ah1, bl, acc[t][1], 0, 0, 0);
            }
        }
        #pragma unroll
        for (int t = 0; t < 2; t++){
            const int col = (wave*2 + t)*16 + l15;
            const float bb = encb[col];
            #pragma unroll
            for (int mt = 0; mt < 2; mt++){
                #pragma unroll
                for (int j = 0; j < 4; j++){
                    const int row = mt*16 + lhi*4 + j;
                    float v = fmaxf(acc[t][mt][j] + bb, 0.f);
                    unsigned short h = f2bf(v);
                    const int gi = (r0 + row)*128 + col;
                    g_Hhi[gi] = h;
                    g_Hlo[gi] = f2bf(v - bf2f(h));
                }
            }
        }
    }
}

// ---------------- tailB: critic + actor + query + logits fused (32 samples/block) ---------
__global__ __launch_bounds__(256, 2) void tailB_kernel(
    const float* __restrict__ crb, const float* __restrict__ vw,
    const float* __restrict__ vb,  const float* __restrict__ acb,
    const float* __restrict__ emb, const float* __restrict__ abias,
    float* __restrict__ out)
{
    const int r0 = blockIdx.x * 32;
    const int tid = threadIdx.x, wave = tid >> 6, lane = tid & 63;
    const int l15 = lane & 15, lhi = lane >> 4;

    __shared__ unsigned short sHh[32][136], sHl[32][136];     // 17.4 KB
    __shared__ unsigned short cbh[4][32][72], cbl[4][32][72]; // 36.9 KB per-wave actor chunks
    __shared__ float qpart[4][32][16];                        // 8 KB
    __shared__ float sq[32][17];                              // 2.2 KB
    __shared__ float svred[4][32];                            // 0.5 KB
    __shared__ float semb[1600];                              // 6.4 KB

    for (int u = tid; u < 512; u += 256){
        int row = u >> 4, ch8 = (u & 15) * 8;
        *(short8*)&sHh[row][ch8] = *(const short8*)&g_Hhi[(r0+row)*128 + ch8];
        *(short8*)&sHl[row][ch8] = *(const short8*)&g_Hlo[(r0+row)*128 + ch8];
    }
    for (int k = tid; k < 1600; k += 256) semb[k] = emb[k];
    __syncthreads();

    // hoist H A-fragments (shared by critic and actor; K=128)
    short8 Ah[2][4], Al[2][4];
    #pragma unroll
    for (int mt = 0; mt < 2; mt++)
        #pragma unroll
        for (int kk4 = 0; kk4 < 4; kk4++){
            const int kk = kk4*32 + lhi*8;
            Ah[mt][kk4] = *(const short8*)&sHh[mt*16 + l15][kk];
            Al[mt][kk4] = *(const short8*)&sHl[mt*16 + l15][kk];
        }

    // ---- critic: wave owns 256 cols; tanh + vw dot ----
    {
        f32x4 cacc[2][16];
        #pragma unroll
        for (int mt = 0; mt < 2; mt++)
            #pragma unroll
            for (int nt = 0; nt < 16; nt++) cacc[mt][nt] = f32x4{0,0,0,0};
        #pragma unroll
        for (int nt = 0; nt < 16; nt++){
            const int n = wave*256 + nt*16 + l15;
            #pragma unroll
            for (int kk4 = 0; kk4 < 4; kk4++){
                const int kk = kk4*32 + lhi*8;
                const short8 bh = *(const short8*)&g_crhi[n*128 + kk];
                const short8 bl = *(const short8*)&g_crlo[n*128 + kk];
                cacc[0][nt] = __builtin_amdgcn_mfma_f32_16x16x32_bf16(Ah[0][kk4], bh, cacc[0][nt], 0, 0, 0);
                cacc[1][nt] = __builtin_amdgcn_mfma_f32_16x16x32_bf16(Ah[1][kk4], bh, cacc[1][nt], 0, 0, 0);
                cacc[0][nt] = __builtin_amdgcn_mfma_f32_16x16x32_bf16(Al[0][kk4], bh, cacc[0][nt], 0, 0, 0);
                cacc[1][nt] = __builtin_amdgcn_mfma_f32_16x16x32_bf16(Al[1][kk4], bh, cacc[1][nt], 0, 0, 0);
                cacc[0][nt] = __builtin_amdgcn_mfma_f32_16x16x32_bf16(Ah[0][kk4], bl, cacc[0][nt], 0, 0, 0);
                cacc[1][nt] = __builtin_amdgcn_mfma_f32_16x16x32_bf16(Ah[1][kk4], bl, cacc[1][nt], 0, 0, 0);
            }
        }
        float vp[8] = {0,0,0,0,0,0,0,0};       // [mt*4+j]
        #pragma unroll
        for (int nt = 0; nt < 16; nt++){
            const int n = wave*256 + nt*16 + l15;
            const float w = vw[n], bb = crb[n];
            #pragma unroll
            for (int mt = 0; mt < 2; mt++)
                #pragma unroll
                for (int j = 0; j < 4; j++)
                    vp[mt*4+j] += tanhf(cacc[mt][nt][j] + bb) * w;
        }
        #pragma unroll
        for (int m = 1; m < 16; m <<= 1)
            #pragma unroll
            for (int q = 0; q < 8; q++) vp[q] += __shfl_xor(vp[q], m, 64);
        if (l15 == 0){
            #pragma unroll
            for (int mt = 0; mt < 2; mt++)
                #pragma unroll
                for (int j = 0; j < 4; j++)
                    svred[wave][mt*16 + lhi*4 + j] = vp[mt*4+j];
        }
    }

    // ---- actor chunks + query mini-GEMM (wave-split K) ----
    f32x4 qacc[2] = {{0,0,0,0},{0,0,0,0}};
    #pragma unroll
    for (int cc = 0; cc < 2; cc++){
        const int c = wave*2 + cc;                       // chunk 0..7 (64 actor cols each)
        f32x4 aacc[2][4];
        #pragma unroll
        for (int mt = 0; mt < 2; mt++)
            #pragma unroll
            for (int nt = 0; nt < 4; nt++) aacc[mt][nt] = f32x4{0,0,0,0};
        #pragma unroll
        for (int kk4 = 0; kk4 < 4; kk4++){
            const int kk = kk4*32 + lhi*8;
            #pragma unroll
            for (int nt = 0; nt < 4; nt++){
                const int n = c*64 + nt*16 + l15;
                const short8 bh = *(const short8*)&g_achi[n*128 + kk];
                const short8 bl = *(const short8*)&g_aclo[n*128 + kk];
                aacc[0][nt] = __builtin_amdgcn_mfma_f32_16x16x32_bf16(Ah[0][kk4], bh, aacc[0][nt], 0, 0, 0);
                aacc[1][nt] = __builtin_amdgcn_mfma_f32_16x16x32_bf16(Ah[1][kk4], bh, aacc[1][nt], 0, 0, 0);
                aacc[0][nt] = __builtin_amdgcn_mfma_f32_16x16x32_bf16(Al[0][kk4], bh, aacc[0][nt], 0, 0, 0);
                aacc[1][nt] = __builtin_amdgcn_mfma_f32_16x16x32_bf16(Al[1][kk4], bh, aacc[1][nt], 0, 0, 0);
                aacc[0][nt] = __builtin_amdgcn_mfma_f32_16x16x32_bf16(Ah[0][kk4], bl, aacc[0][nt], 0, 0, 0);
                aacc[1][nt] = __builtin_amdgcn_mfma_f32_16x16x32_bf16(Ah[1][kk4], bl, aacc[1][nt], 0, 0, 0);
            }
        }
        // relu + bias -> per-wave LDS chunk [32 rows][64 cols]
        #pragma unroll
        for (int nt = 0; nt < 4; nt++){
            const int col = nt*16 + l15;
            const float bb = acb[c*64 + col];
            #pragma unroll
            for (int mt = 0; mt < 2; mt++)
                #pragma unroll
                for (int j = 0; j < 4; j++){
                    const int row = mt*16 + lhi*4 + j;
                    float v = fmaxf(aacc[mt][nt][j] + bb, 0.f);
                    unsigned short h = f2bf(v);
                    cbh[wave][row][col] = h;
                    cbl[wave][row][col] = f2bf(v - bf2f(h));
                }
        }
        // query partial over this chunk (K=64), B = qW^T rows e=l15
        #pragma unroll
        for (int kk2 = 0; kk2 < 2; kk2++){
            const int kk = kk2*32 + lhi*8;
            const short8 qbh = *(const short8*)&g_qWhi[l15*512 + c*64 + kk];
            const short8 qbl = *(const short8*)&g_qWlo[l15*512 + c*64 + kk];
            #pragma unroll
            for (int mt = 0; mt < 2; mt++){
                const short8 qah = *(const short8*)&cbh[wave][mt*16 + l15][kk];
                const short8 qal = *(const short8*)&cbl[wave][mt*16 + l15][kk];
                qacc[mt] = __builtin_amdgcn_mfma_f32_16x16x32_bf16(qah, qbh, qacc[mt], 0, 0, 0);
                qacc[mt] = __builtin_amdgcn_mfma_f32_16x16x32_bf16(qal, qbh, qacc[mt], 0, 0, 0);
                qacc[mt] = __builtin_amdgcn_mfma_f32_16x16x32_bf16(qah, qbl, qacc[mt], 0, 0, 0);
            }
        }
    }
    #pragma unroll
    for (int mt = 0; mt < 2; mt++)
        #pragma unroll
        for (int j = 0; j < 4; j++)
            qpart[wave][mt*16 + lhi*4 + j][l15] = qacc[mt][j];
    __syncthreads();

    // value out
    if (tid < 32)
        out[B_*100 + r0 + tid] = svred[0][tid] + svred[1][tid] + svred[2][tid]
                               + svred[3][tid] + vb[0];
    // finalize q
    for (int i = tid; i < 512; i += 256){
        int row = i >> 4, e = i & 15;
        sq[row][e] = tanhf(qpart[0][row][e] + qpart[1][row][e]
                         + qpart[2][row][e] + qpart[3][row][e]);
    }
    __syncthreads();
    // logits
    for (int i = tid; i < 3200; i += 256){
        int row = i / 100, a = i - row*100;
        float s = abias[0];
        #pragma unroll
        for (int e = 0; e < 16; e++) s += sq[row][e] * semb[a*16 + e];
        out[(r0 + row)*100 + a] = s;
    }
}

// ---------------- launch ----------------
extern "C" void kernel_launch(void* const* d_in, const int* in_sizes, int n_in,
                              void* d_out, int out_size, void* d_ws, size_t ws_size,
                              hipStream_t stream) {
    const int*   obs   = (const int*)  d_in[0];
    const float* maxv  = (const float*)d_in[1];
    const float* w1    = (const float*)d_in[2];
    const float* b1    = (const float*)d_in[3];
    const float* w2    = (const float*)d_in[4];
    const float* b2    = (const float*)d_in[5];
    const float* fc1w  = (const float*)d_in[6];
    const float* fc1b  = (const float*)d_in[7];
    const float* encw  = (const float*)d_in[8];
    const float* encb  = (const float*)d_in[9];
    const float* crw   = (const float*)d_in[10];
    const float* crb   = (const float*)d_in[11];
    const float* vw    = (const float*)d_in[12];
    const float* vb    = (const float*)d_in[13];
    const float* acw   = (const float*)d_in[14];
    const float* acb   = (const float*)d_in[15];
    const float* emb   = (const float*)d_in[16];
    const float* aW    = (const float*)d_in[17];
    const float* abias = (const float*)d_in[18];
    float* out = (float*)d_out;

    prep_kernel<<<1344, 256, 0, stream>>>(w1, maxv, w2, fc1w, encw, crw, acw, aW);
    conv1_kernel<<<B_/2, 512, 0, stream>>>(obs, b1);
    conv2_kernel<<<512, 256, 0, stream>>>(b2);
    tailA_kernel<<<256, 256, 0, stream>>>(fc1b, encb);
    tailB_kernel<<<256, 256, 0, stream>>>(crb, vw, vb, acb, emb, abias, out);
}

// Round 14
// 230.989 us; speedup vs baseline: 1.1845x; 1.1845x over previous
//
#include <hip/hip_runtime.h>
#include <math.h>

#define B_ 8192

typedef __attribute__((ext_vector_type(8))) short short8;
typedef __attribute__((ext_vector_type(4))) float f32x4;

// ---------------- persistent device buffers (rewritten every call) ----------------
// weights (hi/lo split bf16, stored as B^T row-major [N][K])
__device__ unsigned short g_w1bh[51200], g_w1bl[51200];    // conv1 W^T [64 oc][800 k], /maxv
__device__ unsigned short g_w2hi[36864],  g_w2lo[36864];   // conv2 [64][576], k'=(kx*3+ky)*64+ic
__device__ unsigned short g_fc1hi[32768], g_fc1lo[32768];  // fc1   [128][256] (k'=pos*64+oc)
__device__ unsigned short g_enchi[16384], g_enclo[16384];  // enc   [128][128]
__device__ unsigned short g_crhi[131072], g_crlo[131072];  // critic[1024][128]
__device__ unsigned short g_achi[65536],  g_aclo[65536];   // actor [512][128]
__device__ unsigned short g_qWhi[8192],   g_qWlo[8192];    // actor_W^T [16][512]
// activations (hi/lo split bf16)
__device__ unsigned short g_ACT1hi[8192*1024], g_ACT1lo[8192*1024]; // conv1 out [s][pos*64+oc]
__device__ unsigned short g_A1hi[8192*256],  g_A1lo[8192*256];  // conv2 out [s][pos*64+oc]

__device__ __forceinline__ unsigned short f2bf(float v){
    unsigned u = __builtin_bit_cast(unsigned, v);
    unsigned r = (u + 0x7fffu + ((u >> 16) & 1u)) >> 16;   // RN-even (finite inputs)
    return (unsigned short)r;
}
__device__ __forceinline__ float bf2f(unsigned short h){
    unsigned u = ((unsigned)h) << 16;
    return __builtin_bit_cast(float, u);
}
__device__ __forceinline__ void split_store(float v, unsigned short* hi, unsigned short* lo){
    unsigned short h = f2bf(v);
    *hi = h;
    *lo = f2bf(v - bf2f(h));
}

// ---------------- prep: transpose + split all weights ----------------
__global__ __launch_bounds__(256) void prep_kernel(
    const float* __restrict__ w1, const float* __restrict__ maxv,
    const float* __restrict__ w2, const float* __restrict__ fc1,
    const float* __restrict__ enc, const float* __restrict__ cr,
    const float* __restrict__ ac, const float* __restrict__ aW)
{
    int d = blockIdx.x * 256 + threadIdx.x;
    if (d < 51200){
        // w1 natural layout [oc][l][dx][dy] IS the B^T [oc][k] layout; scale by 1/maxv[l]
        int k = d % 800, l = k / 25;
        split_store(w1[d] / maxv[l], &g_w1bh[d], &g_w1bl[d]);
        return;
    }
    d -= 51200;
    if (d < 36864){
        int oc = d / 576, k2 = d - oc*576;
        int kxy = k2 >> 6, ic = k2 & 63;               // k' = kxy*64 + ic
        split_store(w2[oc*576 + ic*9 + kxy], &g_w2hi[d], &g_w2lo[d]);
        return;
    }
    d -= 36864;
    if (d < 32768){
        int o = d >> 8, kp = d & 255;                  // k' = pos*64+oc
        split_store(fc1[o*256 + (kp & 63)*4 + (kp >> 6)], &g_fc1hi[d], &g_fc1lo[d]);
        return;
    }
    d -= 32768;
    if (d < 16384){ split_store(enc[d], &g_enchi[d], &g_enclo[d]); return; }
    d -= 16384;
    if (d < 131072){ split_store(cr[d], &g_crhi[d], &g_crlo[d]); return; }
    d -= 131072;
    if (d < 65536){ split_store(ac[d], &g_achi[d], &g_aclo[d]); return; }
    d -= 65536;
    { int e = d >> 9, j = d & 511; split_store(aW[j*16 + e], &g_qWhi[d], &g_qWlo[d]); }
}

// ---------------- conv1 (REVERTED to round-11 proven version) ----------------
// 2 samples/block, 256 threads (4 waves). Wave = nt; both m-tiles per B-load; 2-deep
// B prefetch. 3 blocks/CU (53.3 KB LDS).
#define APITCH 808   // 800 + 8 shorts pad
__global__ __launch_bounds__(256) void conv1_kernel(const int* __restrict__ obs,
                                                    const float* __restrict__ b1)
{
    const int b = blockIdx.x;                 // samples b*2, b*2+1
    const int tid = threadIdx.x;
    const int wave = tid >> 6, lane = tid & 63;
    const int l15 = lane & 15, lhi = lane >> 4;

    __shared__ unsigned short sA[32 * APITCH];      // 51.7 KB
    __shared__ int s_cell[2][200];

    for (int i = tid; i < 4 * APITCH; i += 256)
        *(short8*)&sA[i * 8] = short8{0,0,0,0,0,0,0,0};

    int   cells[2], xs[2], ys[2], ls[2];
    float vals[2];
    bool  valids[2];
    #pragma unroll
    for (int u = 0; u < 2; u++){
        const int slot = tid + u*256;
        valids[u] = false; cells[u] = 0;
        if (slot < 400){
            const int si = (slot >= 200) ? 1 : 0;
            const int k  = slot - si*200;
            const int base = (b*2 + si)*600 + k*3;
            int coord = obs[base], atr = obs[base+1], val = obs[base+2];
            bool valid = (coord != 255) && (atr < 32);
            xs[u] = (coord >> 4) & 15;  ys[u] = coord & 15;  ls[u] = atr;
            cells[u] = valid ? (atr*256 + xs[u]*16 + ys[u]) : 0;   // invalid claims cell 0
            vals[u]  = (float)val;
            valids[u] = valid;
            s_cell[si][k] = cells[u];
        }
    }
    __syncthreads();
    // last-wins dedup + scatter (writes exclusive: (pos,l,dx,dy) <-> box cell bijective;
    // x>=14 / y>=14 taps are auto-excluded by the wx/wy < 5 bounds)
    #pragma unroll
    for (int u = 0; u < 2; u++){
        const int slot = tid + u*256;
        if (slot < 400){
            const int si = (slot >= 200) ? 1 : 0;
            const int k  = slot - si*200;
            const int c  = cells[u];
            bool kept = true;
            #pragma unroll 4
            for (int j = 0; j < 200; j++){
                int cj = s_cell[si][j];
                kept &= (j <= k) | (cj != c);
            }
            if (kept && valids[u]){
                const int x3 = xs[u]/3, rx = xs[u] - 3*x3;
                const int y3 = ys[u]/3, ry = ys[u] - 3*y3;
                const unsigned short hv = f2bf(vals[u]);     // exact (integer <= 255)
                #pragma unroll
                for (int d = 0; d < 4; d++){
                    const int dxd = d >> 1, dyd = d & 1;
                    const int ox = x3 - dxd, oy = y3 - dyd;
                    const int wx = rx + 3*dxd, wy = ry + 3*dyd;
                    if (((unsigned)ox <= 3u) && ((unsigned)oy <= 3u) && (wx < 5) && (wy < 5))
                        sA[(si*16 + ox*4 + oy)*APITCH + ls[u]*25 + wx*5 + wy] = hv;
                }
            }
        }
    }
    __syncthreads();

    // MFMA: wave = nt; n = wave*16 + l15; both m-tiles per B-load; 2-deep B prefetch.
    const int n = wave*16 + l15;
    const unsigned short* Bh = &g_w1bh[n*800];
    const unsigned short* Bl = &g_w1bl[n*800];
    const unsigned short* A0 = &sA[l15*APITCH];
    const unsigned short* A1 = &sA[(16 + l15)*APITCH];
    f32x4 acc0 = {0,0,0,0}, acc1 = {0,0,0,0};
    short8 bh0 = *(const short8*)&Bh[lhi*8];
    short8 bl0 = *(const short8*)&Bl[lhi*8];
    short8 bh1 = *(const short8*)&Bh[32 + lhi*8];
    short8 bl1 = *(const short8*)&Bl[32 + lhi*8];
    #pragma unroll
    for (int kc = 0; kc < 25; kc++){
        const int kk = kc*32 + lhi*8;
        short8 a0 = *(const short8*)&A0[kk];
        short8 a1 = *(const short8*)&A1[kk];
        short8 bhn, bln;
        if (kc < 23){
            bhn = *(const short8*)&Bh[kk + 64];
            bln = *(const short8*)&Bl[kk + 64];
        }
        acc0 = __builtin_amdgcn_mfma_f32_16x16x32_bf16(a0, bh0, acc0, 0, 0, 0);
        acc1 = __builtin_amdgcn_mfma_f32_16x16x32_bf16(a1, bh0, acc1, 0, 0, 0);
        acc0 = __builtin_amdgcn_mfma_f32_16x16x32_bf16(a0, bl0, acc0, 0, 0, 0);
        acc1 = __builtin_amdgcn_mfma_f32_16x16x32_bf16(a1, bl0, acc1, 0, 0, 0);
        bh0 = bh1; bl0 = bl1; bh1 = bhn; bl1 = bln;
    }
    const float bb = b1[n];
    #pragma unroll
    for (int j = 0; j < 4; j++){
        const int pos = lhi*4 + j;
        float v0 = fmaxf(acc0[j] + bb, 0.f);
        float v1 = fmaxf(acc1[j] + bb, 0.f);
        unsigned short h0 = f2bf(v0), h1 = f2bf(v1);
        const int g0 = (b*2    )*1024 + pos*64 + n;
        const int g1 = (b*2 + 1)*1024 + pos*64 + n;
        g_ACT1hi[g0] = h0;  g_ACT1lo[g0] = f2bf(v0 - bf2f(h0));
        g_ACT1hi[g1] = h1;  g_ACT1lo[g1] = f2bf(v1 - bf2f(h1));
    }
}

// ---------------- conv2: im2col-on-load MFMA GEMM (M=32768, N=64, K=576) ----------------
__global__ __launch_bounds__(256) void conv2_kernel(const float* __restrict__ bias)
{
    const int r0 = blockIdx.x * 64;                      // 16 samples x 4 pos
    const int tid = threadIdx.x, wave = tid >> 6, lane = tid & 63;
    const int l15 = lane & 15, lhi = lane >> 4;

    __shared__ unsigned short sAhi[64][72];
    __shared__ unsigned short sAlo[64][72];

    f32x4 acc[4] = {{0,0,0,0},{0,0,0,0},{0,0,0,0},{0,0,0,0}};
    for (int kc = 0; kc < 9; kc++){                      // (kx,ky) chunk of 64 k's
        const int kx = kc / 3, ky = kc - 3*kx;
        __syncthreads();
        #pragma unroll
        for (int u = 0; u < 2; u++){
            int unit = tid + u*256;
            int row = unit >> 3, ch8 = (unit & 7) * 8;
            int px = (row >> 1) & 1, py = row & 1;       // pos = row&3
            int cell = (px + kx)*4 + (py + ky);
            int g = ((r0 >> 2) + (row >> 2))*1024 + cell*64 + ch8;
            *(short8*)&sAhi[row][ch8] = *(const short8*)&g_ACT1hi[g];
            *(short8*)&sAlo[row][ch8] = *(const short8*)&g_ACT1lo[g];
        }
        __syncthreads();
        #pragma unroll
        for (int ks = 0; ks < 2; ks++){
            const int kk = ks*32 + lhi*8;
            short8 ah = *(const short8*)&sAhi[wave*16 + l15][kk];
            short8 al = *(const short8*)&sAlo[wave*16 + l15][kk];
            #pragma unroll
            for (int nt = 0; nt < 4; nt++){
                const int n = nt*16 + l15;
                const short8 bh = *(const short8*)&g_w2hi[n*576 + kc*64 + kk];
                const short8 bl = *(const short8*)&g_w2lo[n*576 + kc*64 + kk];
                acc[nt] = __builtin_amdgcn_mfma_f32_16x16x32_bf16(ah, bh, acc[nt], 0, 0, 0);
                acc[nt] = __builtin_amdgcn_mfma_f32_16x16x32_bf16(al, bh, acc[nt], 0, 0, 0);
                acc[nt] = __builtin_amdgcn_mfma_f32_16x16x32_bf16(ah, bl, acc[nt], 0, 0, 0);
            }
        }
    }
    #pragma unroll
    for (int nt = 0; nt < 4; nt++){
        const int col = nt*16 + l15;
        const float bb = bias[col];
        #pragma unroll
        for (int j = 0; j < 4; j++){
            const int row = r0 + wave*16 + lhi*4 + j;
            float v = fmaxf(acc[nt][j] + bb, 0.f);
            unsigned short h = f2bf(v);
            g_A1hi[row*64 + col] = h;                    // == [s][pos*64+oc]
            g_A1lo[row*64 + col] = f2bf(v - bf2f(h));
        }
    }
}

// ---------------- tail: fc1+enc+critic+actor+query+logits fused (32 samples/block) --------
// LDS overlay plan (static char buffer, 63104 B):
//   phase1: sA1 [0..33792) + sX [33792..51200)
//   phase2: sH  [0..17408) (overlays dead sA1), reads sX
//   phase3: sH + cb(hi-only actor chunks) [33792..52224) + qpart [52224..60416)
//           + sq [60416..62592) + svred [62592..63104)
//   phase4: semb [33792..40192) (overlays dead cb)
__global__ __launch_bounds__(256, 2) void tail_kernel(
    const float* __restrict__ fc1b, const float* __restrict__ encb,
    const float* __restrict__ crb,  const float* __restrict__ vw,
    const float* __restrict__ vb,   const float* __restrict__ acb,
    const float* __restrict__ emb,  const float* __restrict__ abias,
    float* __restrict__ out)
{
    const int r0 = blockIdx.x * 32;
    const int tid = threadIdx.x, wave = tid >> 6, lane = tid & 63;
    const int l15 = lane & 15, lhi = lane >> 4;

    __shared__ char smem[63104];
    unsigned short* sA1h = (unsigned short*)smem;                 // [32][264]
    unsigned short* sA1l = (unsigned short*)(smem + 16896);
    unsigned short* sXh  = (unsigned short*)(smem + 33792);       // [32][136]
    unsigned short* sXl  = (unsigned short*)(smem + 42496);
    unsigned short* sHh  = (unsigned short*)smem;                 // [32][136] overlays sA1
    unsigned short* sHl  = (unsigned short*)(smem + 8704);
    unsigned short* cb   = (unsigned short*)(smem + 33792);       // [4][32][72] hi-only
    float* qpart = (float*)(smem + 52224);                        // [4][32][16]
    float* sq    = (float*)(smem + 60416);                        // [32][17]
    float* svred = (float*)(smem + 62592);                        // [4][32]
    float* semb  = (float*)(smem + 33792);                        // [1600] overlays cb

    // ---- stage A1 [32][256] hi/lo ----
    for (int u = tid; u < 1024; u += 256){
        int row = u >> 5, ch8 = (u & 31) * 8;
        *(short8*)&sA1h[row*264 + ch8] = *(const short8*)&g_A1hi[(r0+row)*256 + ch8];
        *(short8*)&sA1l[row*264 + ch8] = *(const short8*)&g_A1lo[(r0+row)*256 + ch8];
    }
    __syncthreads();

    // ---- fc1: M=32, N=128 (wave owns nt = 2w, 2w+1), K=256 -> sX ----
    {
        f32x4 acc[2][2] = {{{0,0,0,0},{0,0,0,0}},{{0,0,0,0},{0,0,0,0}}}; // [t][mt]
        #pragma unroll
        for (int kk8 = 0; kk8 < 8; kk8++){
            const int kk = kk8*32 + lhi*8;
            short8 ah0 = *(const short8*)&sA1h[l15*264 + kk];
            short8 al0 = *(const short8*)&sA1l[l15*264 + kk];
            short8 ah1 = *(const short8*)&sA1h[(16 + l15)*264 + kk];
            short8 al1 = *(const short8*)&sA1l[(16 + l15)*264 + kk];
            #pragma unroll
            for (int t = 0; t < 2; t++){
                const int n = (wave*2 + t)*16 + l15;
                const short8 bh = *(const short8*)&g_fc1hi[n*256 + kk];
                const short8 bl = *(const short8*)&g_fc1lo[n*256 + kk];
                acc[t][0] = __builtin_amdgcn_mfma_f32_16x16x32_bf16(ah0, bh, acc[t][0], 0, 0, 0);
                acc[t][1] = __builtin_amdgcn_mfma_f32_16x16x32_bf16(ah1, bh, acc[t][1], 0, 0, 0);
                acc[t][0] = __builtin_amdgcn_mfma_f32_16x16x32_bf16(al0, bh, acc[t][0], 0, 0, 0);
                acc[t][1] = __builtin_amdgcn_mfma_f32_16x16x32_bf16(al1, bh, acc[t][1], 0, 0, 0);
                acc[t][0] = __builtin_amdgcn_mfma_f32_16x16x32_bf16(ah0, bl, acc[t][0], 0, 0, 0);
                acc[t][1] = __builtin_amdgcn_mfma_f32_16x16x32_bf16(ah1, bl, acc[t][1], 0, 0, 0);
            }
        }
        __syncthreads();   // all reads of sA1 done before phase-2 overwrites it via sH? (sH write is next phase; this barrier also orders sX writes)
        #pragma unroll
        for (int t = 0; t < 2; t++){
            const int col = (wave*2 + t)*16 + l15;
            const float bb = fc1b[col];
            #pragma unroll
            for (int mt = 0; mt < 2; mt++){
                #pragma unroll
                for (int j = 0; j < 4; j++){
                    const int row = mt*16 + lhi*4 + j;
                    float v = fmaxf(acc[t][mt][j] + bb, 0.f);
                    unsigned short h = f2bf(v);
                    sXh[row*136 + col] = h;
                    sXl[row*136 + col] = f2bf(v - bf2f(h));
                }
            }
        }
    }
    __syncthreads();

    // ---- enc: M=32, N=128, K=128 -> sH (overlays dead sA1) ----
    {
        f32x4 acc[2][2] = {{{0,0,0,0},{0,0,0,0}},{{0,0,0,0},{0,0,0,0}}};
        #pragma unroll
        for (int kk4 = 0; kk4 < 4; kk4++){
            const int kk = kk4*32 + lhi*8;
            short8 ah0 = *(const short8*)&sXh[l15*136 + kk];
            short8 al0 = *(const short8*)&sXl[l15*136 + kk];
            short8 ah1 = *(const short8*)&sXh[(16 + l15)*136 + kk];
            short8 al1 = *(const short8*)&sXl[(16 + l15)*136 + kk];
            #pragma unroll
            for (int t = 0; t < 2; t++){
                const int n = (wave*2 + t)*16 + l15;
                const short8 bh = *(const short8*)&g_enchi[n*128 + kk];
                const short8 bl = *(const short8*)&g_enclo[n*128 + kk];
                acc[t][0] = __builtin_amdgcn_mfma_f32_16x16x32_bf16(ah0, bh, acc[t][0], 0, 0, 0);
                acc[t][1] = __builtin_amdgcn_mfma_f32_16x16x32_bf16(ah1, bh, acc[t][1], 0, 0, 0);
                acc[t][0] = __builtin_amdgcn_mfma_f32_16x16x32_bf16(al0, bh, acc[t][0], 0, 0, 0);
                acc[t][1] = __builtin_amdgcn_mfma_f32_16x16x32_bf16(al1, bh, acc[t][1], 0, 0, 0);
                acc[t][0] = __builtin_amdgcn_mfma_f32_16x16x32_bf16(ah0, bl, acc[t][0], 0, 0, 0);
                acc[t][1] = __builtin_amdgcn_mfma_f32_16x16x32_bf16(ah1, bl, acc[t][1], 0, 0, 0);
            }
        }
        __syncthreads();   // sA1 reads long done; ensure no wave still in fc1 region (defensive)
        #pragma unroll
        for (int t = 0; t < 2; t++){
            const int col = (wave*2 + t)*16 + l15;
            const float bb = encb[col];
            #pragma unroll
            for (int mt = 0; mt < 2; mt++){
                #pragma unroll
                for (int j = 0; j < 4; j++){
                    const int row = mt*16 + lhi*4 + j;
                    float v = fmaxf(acc[t][mt][j] + bb, 0.f);
                    unsigned short h = f2bf(v);
                    sHh[row*136 + col] = h;
                    sHl[row*136 + col] = f2bf(v - bf2f(h));
                }
            }
        }
    }
    __syncthreads();

    // ---- hoist H A-fragments (shared by critic and actor; K=128) ----
    short8 Ah[2][4], Al[2][4];
    #pragma unroll
    for (int mt = 0; mt < 2; mt++)
        #pragma unroll
        for (int kk4 = 0; kk4 < 4; kk4++){
            const int kk = kk4*32 + lhi*8;
            Ah[mt][kk4] = *(const short8*)&sHh[(mt*16 + l15)*136 + kk];
            Al[mt][kk4] = *(const short8*)&sHl[(mt*16 + l15)*136 + kk];
        }

    // ---- critic: wave owns 256 cols; tanh + vw dot ----
    {
        f32x4 cacc[2][16];
        #pragma unroll
        for (int mt = 0; mt < 2; mt++)
            #pragma unroll
            for (int nt = 0; nt < 16; nt++) cacc[mt][nt] = f32x4{0,0,0,0};
        #pragma unroll
        for (int nt = 0; nt < 16; nt++){
            const int n = wave*256 + nt*16 + l15;
            #pragma unroll
            for (int kk4 = 0; kk4 < 4; kk4++){
                const short8 bh = *(const short8*)&g_crhi[n*128 + kk4*32 + lhi*8];
                const short8 bl = *(const short8*)&g_crlo[n*128 + kk4*32 + lhi*8];
                cacc[0][nt] = __builtin_amdgcn_mfma_f32_16x16x32_bf16(Ah[0][kk4], bh, cacc[0][nt], 0, 0, 0);
                cacc[1][nt] = __builtin_amdgcn_mfma_f32_16x16x32_bf16(Ah[1][kk4], bh, cacc[1][nt], 0, 0, 0);
                cacc[0][nt] = __builtin_amdgcn_mfma_f32_16x16x32_bf16(Al[0][kk4], bh, cacc[0][nt], 0, 0, 0);
                cacc[1][nt] = __builtin_amdgcn_mfma_f32_16x16x32_bf16(Al[1][kk4], bh, cacc[1][nt], 0, 0, 0);
                cacc[0][nt] = __builtin_amdgcn_mfma_f32_16x16x32_bf16(Ah[0][kk4], bl, cacc[0][nt], 0, 0, 0);
                cacc[1][nt] = __builtin_amdgcn_mfma_f32_16x16x32_bf16(Ah[1][kk4], bl, cacc[1][nt], 0, 0, 0);
            }
        }
        float vp[8] = {0,0,0,0,0,0,0,0};       // [mt*4+j]
        #pragma unroll
        for (int nt = 0; nt < 16; nt++){
            const int n = wave*256 + nt*16 + l15;
            const float w = vw[n], bb = crb[n];
            #pragma unroll
            for (int mt = 0; mt < 2; mt++)
                #pragma unroll
                for (int j = 0; j < 4; j++)
                    vp[mt*4+j] += tanhf(cacc[mt][nt][j] + bb) * w;
        }
        #pragma unroll
        for (int m = 1; m < 16; m <<= 1)
            #pragma unroll
            for (int q = 0; q < 8; q++) vp[q] += __shfl_xor(vp[q], m, 64);
        if (l15 == 0){
            #pragma unroll
            for (int mt = 0; mt < 2; mt++)
                #pragma unroll
                for (int j = 0; j < 4; j++)
                    svred[wave*32 + mt*16 + lhi*4 + j] = vp[mt*4+j];
        }
    }

    // ---- actor chunks (hi-only LDS) + query mini-GEMM (wave-split K) ----
    f32x4 qacc[2] = {{0,0,0,0},{0,0,0,0}};
    #pragma unroll
    for (int cc = 0; cc < 2; cc++){
        const int c = wave*2 + cc;                       // chunk 0..7 (64 actor cols each)
        f32x4 aacc[2][4];
        #pragma unroll
        for (int mt = 0; mt < 2; mt++)
            #pragma unroll
            for (int nt = 0; nt < 4; nt++) aacc[mt][nt] = f32x4{0,0,0,0};
        #pragma unroll
        for (int kk4 = 0; kk4 < 4; kk4++){
            #pragma unroll
            for (int nt = 0; nt < 4; nt++){
                const int n = c*64 + nt*16 + l15;
                const short8 bh = *(const short8*)&g_achi[n*128 + kk4*32 + lhi*8];
                const short8 bl = *(const short8*)&g_aclo[n*128 + kk4*32 + lhi*8];
                aacc[0][nt] = __builtin_amdgcn_mfma_f32_16x16x32_bf16(Ah[0][kk4], bh, aacc[0][nt], 0, 0, 0);
                aacc[1][nt] = __builtin_amdgcn_mfma_f32_16x16x32_bf16(Ah[1][kk4], bh, aacc[1][nt], 0, 0, 0);
                aacc[0][nt] = __builtin_amdgcn_mfma_f32_16x16x32_bf16(Al[0][kk4], bh, aacc[0][nt], 0, 0, 0);
                aacc[1][nt] = __builtin_amdgcn_mfma_f32_16x16x32_bf16(Al[1][kk4], bh, aacc[1][nt], 0, 0, 0);
                aacc[0][nt] = __builtin_amdgcn_mfma_f32_16x16x32_bf16(Ah[0][kk4], bl, aacc[0][nt], 0, 0, 0);
                aacc[1][nt] = __builtin_amdgcn_mfma_f32_16x16x32_bf16(Al[1][kk4], bl, aacc[1][nt], 0, 0, 0);
            }
        }
        // relu + bias -> per-wave LDS chunk [32 rows][64 cols], hi only
        #pragma unroll
        for (int nt = 0; nt < 4; nt++){
            const int col = nt*16 + l15;
            const float bb = acb[c*64 + col];
            #pragma unroll
            for (int mt = 0; mt < 2; mt++)
                #pragma unroll
                for (int j = 0; j < 4; j++){
                    const int row = mt*16 + lhi*4 + j;
                    cb[(wave*32 + row)*72 + col] = f2bf(fmaxf(aacc[mt][nt][j] + bb, 0.f));
                }
        }
        // query partial over this chunk (K=64), B = qW^T rows e=l15 (A hi-only: 2 MFMAs)
        #pragma unroll
        for (int kk2 = 0; kk2 < 2; kk2++){
            const int kk = kk2*32 + lhi*8;
            const short8 qbh = *(const short8*)&g_qWhi[l15*512 + c*64 + kk];
            const short8 qbl = *(const short8*)&g_qWlo[l15*512 + c*64 + kk];
            #pragma unroll
            for (int mt = 0; mt < 2; mt++){
                const short8 qah = *(const short8*)&cb[(wave*32 + mt*16 + l15)*72 + kk];
                qacc[mt] = __builtin_amdgcn_mfma_f32_16x16x32_bf16(qah, qbh, qacc[mt], 0, 0, 0);
                qacc[mt] = __builtin_amdgcn_mfma_f32_16x16x32_bf16(qah, qbl, qacc[mt], 0, 0, 0);
            }
        }
    }
    #pragma unroll
    for (int mt = 0; mt < 2; mt++)
        #pragma unroll
        for (int j = 0; j < 4; j++)
            qpart[(wave*32 + mt*16 + lhi*4 + j)*16 + l15] = qacc[mt][j];
    __syncthreads();

    // value out
    if (tid < 32)
        out[B_*100 + r0 + tid] = svred[tid] + svred[32 + tid] + svred[64 + tid]
                               + svred[96 + tid] + vb[0];
    // finalize q; load semb (overlays dead cb region)
    for (int i = tid; i < 512; i += 256){
        int row = i >> 4, e = i & 15;
        sq[row*17 + e] = tanhf(qpart[row*16 + e] + qpart[(32 + row)*16 + e]
                             + qpart[(64 + row)*16 + e] + qpart[(96 + row)*16 + e]);
    }
    for (int k = tid; k < 1600; k += 256) semb[k] = emb[k];
    __syncthreads();
    // logits
    for (int i = tid; i < 3200; i += 256){
        int row = i / 100, a = i - row*100;
        float s = abias[0];
        #pragma unroll
        for (int e = 0; e < 16; e++) s += sq[row*17 + e] * semb[a*16 + e];
        out[(r0 + row)*100 + a] = s;
    }
}

// ---------------- launch ----------------
extern "C" void kernel_launch(void* const* d_in, const int* in_sizes, int n_in,
                              void* d_out, int out_size, void* d_ws, size_t ws_size,
                              hipStream_t stream) {
    const int*   obs   = (const int*)  d_in[0];
    const float* maxv  = (const float*)d_in[1];
    const float* w1    = (const float*)d_in[2];
    const float* b1    = (const float*)d_in[3];
    const float* w2    = (const float*)d_in[4];
    const float* b2    = (const float*)d_in[5];
    const float* fc1w  = (const float*)d_in[6];
    const float* fc1b  = (const float*)d_in[7];
    const float* encw  = (const float*)d_in[8];
    const float* encb  = (const float*)d_in[9];
    const float* crw   = (const float*)d_in[10];
    const float* crb   = (const float*)d_in[11];
    const float* vw    = (const float*)d_in[12];
    const float* vb    = (const float*)d_in[13];
    const float* acw   = (const float*)d_in[14];
    const float* acb   = (const float*)d_in[15];
    const float* emb   = (const float*)d_in[16];
    const float* aW    = (const float*)d_in[17];
    const float* abias = (const float*)d_in[18];
    float* out = (float*)d_out;

    prep_kernel<<<1336, 256, 0, stream>>>(w1, maxv, w2, fc1w, encw, crw, acw, aW);
    conv1_kernel<<<B_/2, 256, 0, stream>>>(obs, b1);
    conv2_kernel<<<512, 256, 0, stream>>>(b2);
    tail_kernel<<<256, 256, 0, stream>>>(fc1b, encb, crb, vw, vb, acb, emb, abias, out);
}

// Round 15
// 229.401 us; speedup vs baseline: 1.1927x; 1.0069x over previous
//
#include <hip/hip_runtime.h>
#include <math.h>

#define B_ 8192

typedef __attribute__((ext_vector_type(8))) short short8;
typedef __attribute__((ext_vector_type(4))) float f32x4;

// ---------------- persistent device buffers (rewritten every call) ----------------
// weights (hi/lo split bf16, stored as B^T row-major [N][K])
__device__ unsigned short g_w1bh[51200], g_w1bl[51200];    // conv1 W^T [64 oc][800 k], /maxv
__device__ unsigned short g_w2hi[36864],  g_w2lo[36864];   // conv2 [64][576], k'=(kx*3+ky)*64+ic
__device__ unsigned short g_fc1hi[32768], g_fc1lo[32768];  // fc1   [128][256] (k'=pos*64+oc)
__device__ unsigned short g_enchi[16384], g_enclo[16384];  // enc   [128][128]
__device__ unsigned short g_crhi[131072], g_crlo[131072];  // critic[1024][128]
__device__ unsigned short g_achi[65536],  g_aclo[65536];   // actor [512][128]
__device__ unsigned short g_qWhi[8192],   g_qWlo[8192];    // actor_W^T [16][512]
// activations (hi/lo split bf16)
__device__ unsigned short g_ACT1hi[8192*1024], g_ACT1lo[8192*1024]; // conv1 out [s][pos*64+oc]
__device__ unsigned short g_A1hi[8192*256],  g_A1lo[8192*256];  // conv2 out [s][pos*64+oc]

__device__ __forceinline__ unsigned short f2bf(float v){
    unsigned u = __builtin_bit_cast(unsigned, v);
    unsigned r = (u + 0x7fffu + ((u >> 16) & 1u)) >> 16;   // RN-even (finite inputs)
    return (unsigned short)r;
}
__device__ __forceinline__ float bf2f(unsigned short h){
    unsigned u = ((unsigned)h) << 16;
    return __builtin_bit_cast(float, u);
}
__device__ __forceinline__ void split_store(float v, unsigned short* hi, unsigned short* lo){
    unsigned short h = f2bf(v);
    *hi = h;
    *lo = f2bf(v - bf2f(h));
}

// ---------------- prep: transpose + split all weights ----------------
__global__ __launch_bounds__(256) void prep_kernel(
    const float* __restrict__ w1, const float* __restrict__ maxv,
    const float* __restrict__ w2, const float* __restrict__ fc1,
    const float* __restrict__ enc, const float* __restrict__ cr,
    const float* __restrict__ ac, const float* __restrict__ aW)
{
    int d = blockIdx.x * 256 + threadIdx.x;
    if (d < 51200){
        // w1 natural layout [oc][l][dx][dy] IS the B^T [oc][k] layout; scale by 1/maxv[l]
        int k = d % 800, l = k / 25;
        split_store(w1[d] / maxv[l], &g_w1bh[d], &g_w1bl[d]);
        return;
    }
    d -= 51200;
    if (d < 36864){
        int oc = d / 576, k2 = d - oc*576;
        int kxy = k2 >> 6, ic = k2 & 63;               // k' = kxy*64 + ic
        split_store(w2[oc*576 + ic*9 + kxy], &g_w2hi[d], &g_w2lo[d]);
        return;
    }
    d -= 36864;
    if (d < 32768){
        int o = d >> 8, kp = d & 255;                  // k' = pos*64+oc
        split_store(fc1[o*256 + (kp & 63)*4 + (kp >> 6)], &g_fc1hi[d], &g_fc1lo[d]);
        return;
    }
    d -= 32768;
    if (d < 16384){ split_store(enc[d], &g_enchi[d], &g_enclo[d]); return; }
    d -= 16384;
    if (d < 131072){ split_store(cr[d], &g_crhi[d], &g_crlo[d]); return; }
    d -= 131072;
    if (d < 65536){ split_store(ac[d], &g_achi[d], &g_aclo[d]); return; }
    d -= 65536;
    { int e = d >> 9, j = d & 511; split_store(aW[j*16 + e], &g_qWhi[d], &g_qWlo[d]); }
}

// ---------------- conv1 (round-11 proven version) ----------------
// 2 samples/block, 256 threads (4 waves). Wave = nt; both m-tiles per B-load; 2-deep
// B prefetch. 3 blocks/CU (53.3 KB LDS).
#define APITCH 808   // 800 + 8 shorts pad
__global__ __launch_bounds__(256) void conv1_kernel(const int* __restrict__ obs,
                                                    const float* __restrict__ b1)
{
    const int b = blockIdx.x;                 // samples b*2, b*2+1
    const int tid = threadIdx.x;
    const int wave = tid >> 6, lane = tid & 63;
    const int l15 = lane & 15, lhi = lane >> 4;

    __shared__ unsigned short sA[32 * APITCH];      // 51.7 KB
    __shared__ int s_cell[2][200];

    for (int i = tid; i < 4 * APITCH; i += 256)
        *(short8*)&sA[i * 8] = short8{0,0,0,0,0,0,0,0};

    int   cells[2], xs[2], ys[2], ls[2];
    float vals[2];
    bool  valids[2];
    #pragma unroll
    for (int u = 0; u < 2; u++){
        const int slot = tid + u*256;
        valids[u] = false; cells[u] = 0;
        if (slot < 400){
            const int si = (slot >= 200) ? 1 : 0;
            const int k  = slot - si*200;
            const int base = (b*2 + si)*600 + k*3;
            int coord = obs[base], atr = obs[base+1], val = obs[base+2];
            bool valid = (coord != 255) && (atr < 32);
            xs[u] = (coord >> 4) & 15;  ys[u] = coord & 15;  ls[u] = atr;
            cells[u] = valid ? (atr*256 + xs[u]*16 + ys[u]) : 0;   // invalid claims cell 0
            vals[u]  = (float)val;
            valids[u] = valid;
            s_cell[si][k] = cells[u];
        }
    }
    __syncthreads();
    // last-wins dedup + scatter (writes exclusive: (pos,l,dx,dy) <-> box cell bijective;
    // x>=14 / y>=14 taps are auto-excluded by the wx/wy < 5 bounds)
    #pragma unroll
    for (int u = 0; u < 2; u++){
        const int slot = tid + u*256;
        if (slot < 400){
            const int si = (slot >= 200) ? 1 : 0;
            const int k  = slot - si*200;
            const int c  = cells[u];
            bool kept = true;
            #pragma unroll 4
            for (int j = 0; j < 200; j++){
                int cj = s_cell[si][j];
                kept &= (j <= k) | (cj != c);
            }
            if (kept && valids[u]){
                const int x3 = xs[u]/3, rx = xs[u] - 3*x3;
                const int y3 = ys[u]/3, ry = ys[u] - 3*y3;
                const unsigned short hv = f2bf(vals[u]);     // exact (integer <= 255)
                #pragma unroll
                for (int d = 0; d < 4; d++){
                    const int dxd = d >> 1, dyd = d & 1;
                    const int ox = x3 - dxd, oy = y3 - dyd;
                    const int wx = rx + 3*dxd, wy = ry + 3*dyd;
                    if (((unsigned)ox <= 3u) && ((unsigned)oy <= 3u) && (wx < 5) && (wy < 5))
                        sA[(si*16 + ox*4 + oy)*APITCH + ls[u]*25 + wx*5 + wy] = hv;
                }
            }
        }
    }
    __syncthreads();

    // MFMA: wave = nt; n = wave*16 + l15; both m-tiles per B-load; 2-deep B prefetch.
    const int n = wave*16 + l15;
    const unsigned short* Bh = &g_w1bh[n*800];
    const unsigned short* Bl = &g_w1bl[n*800];
    const unsigned short* A0 = &sA[l15*APITCH];
    const unsigned short* A1 = &sA[(16 + l15)*APITCH];
    f32x4 acc0 = {0,0,0,0}, acc1 = {0,0,0,0};
    short8 bh0 = *(const short8*)&Bh[lhi*8];
    short8 bl0 = *(const short8*)&Bl[lhi*8];
    short8 bh1 = *(const short8*)&Bh[32 + lhi*8];
    short8 bl1 = *(const short8*)&Bl[32 + lhi*8];
    #pragma unroll
    for (int kc = 0; kc < 25; kc++){
        const int kk = kc*32 + lhi*8;
        short8 a0 = *(const short8*)&A0[kk];
        short8 a1 = *(const short8*)&A1[kk];
        short8 bhn, bln;
        if (kc < 23){
            bhn = *(const short8*)&Bh[kk + 64];
            bln = *(const short8*)&Bl[kk + 64];
        }
        acc0 = __builtin_amdgcn_mfma_f32_16x16x32_bf16(a0, bh0, acc0, 0, 0, 0);
        acc1 = __builtin_amdgcn_mfma_f32_16x16x32_bf16(a1, bh0, acc1, 0, 0, 0);
        acc0 = __builtin_amdgcn_mfma_f32_16x16x32_bf16(a0, bl0, acc0, 0, 0, 0);
        acc1 = __builtin_amdgcn_mfma_f32_16x16x32_bf16(a1, bl0, acc1, 0, 0, 0);
        bh0 = bh1; bl0 = bl1; bh1 = bhn; bl1 = bln;
    }
    const float bb = b1[n];
    #pragma unroll
    for (int j = 0; j < 4; j++){
        const int pos = lhi*4 + j;
        float v0 = fmaxf(acc0[j] + bb, 0.f);
        float v1 = fmaxf(acc1[j] + bb, 0.f);
        unsigned short h0 = f2bf(v0), h1 = f2bf(v1);
        const int g0 = (b*2    )*1024 + pos*64 + n;
        const int g1 = (b*2 + 1)*1024 + pos*64 + n;
        g_ACT1hi[g0] = h0;  g_ACT1lo[g0] = f2bf(v0 - bf2f(h0));
        g_ACT1hi[g1] = h1;  g_ACT1lo[g1] = f2bf(v1 - bf2f(h1));
    }
}

// ---------------- conv2: im2col-on-load MFMA GEMM (M=32768, N=64, K=576) ----------------
__global__ __launch_bounds__(256) void conv2_kernel(const float* __restrict__ bias)
{
    const int r0 = blockIdx.x * 64;                      // 16 samples x 4 pos
    const int tid = threadIdx.x, wave = tid >> 6, lane = tid & 63;
    const int l15 = lane & 15, lhi = lane >> 4;

    __shared__ unsigned short sAhi[64][72];
    __shared__ unsigned short sAlo[64][72];

    f32x4 acc[4] = {{0,0,0,0},{0,0,0,0},{0,0,0,0},{0,0,0,0}};
    for (int kc = 0; kc < 9; kc++){                      // (kx,ky) chunk of 64 k's
        const int kx = kc / 3, ky = kc - 3*kx;
        __syncthreads();
        #pragma unroll
        for (int u = 0; u < 2; u++){
            int unit = tid + u*256;
            int row = unit >> 3, ch8 = (unit & 7) * 8;
            int px = (row >> 1) & 1, py = row & 1;       // pos = row&3
            int cell = (px + kx)*4 + (py + ky);
            int g = ((r0 >> 2) + (row >> 2))*1024 + cell*64 + ch8;
            *(short8*)&sAhi[row][ch8] = *(const short8*)&g_ACT1hi[g];
            *(short8*)&sAlo[row][ch8] = *(const short8*)&g_ACT1lo[g];
        }
        __syncthreads();
        #pragma unroll
        for (int ks = 0; ks < 2; ks++){
            const int kk = ks*32 + lhi*8;
            short8 ah = *(const short8*)&sAhi[wave*16 + l15][kk];
            short8 al = *(const short8*)&sAlo[wave*16 + l15][kk];
            #pragma unroll
            for (int nt = 0; nt < 4; nt++){
                const int n = nt*16 + l15;
                const short8 bh = *(const short8*)&g_w2hi[n*576 + kc*64 + kk];
                const short8 bl = *(const short8*)&g_w2lo[n*576 + kc*64 + kk];
                acc[nt] = __builtin_amdgcn_mfma_f32_16x16x32_bf16(ah, bh, acc[nt], 0, 0, 0);
                acc[nt] = __builtin_amdgcn_mfma_f32_16x16x32_bf16(al, bh, acc[nt], 0, 0, 0);
                acc[nt] = __builtin_amdgcn_mfma_f32_16x16x32_bf16(ah, bl, acc[nt], 0, 0, 0);
            }
        }
    }
    #pragma unroll
    for (int nt = 0; nt < 4; nt++){
        const int col = nt*16 + l15;
        const float bb = bias[col];
        #pragma unroll
        for (int j = 0; j < 4; j++){
            const int row = r0 + wave*16 + lhi*4 + j;
            float v = fmaxf(acc[nt][j] + bb, 0.f);
            unsigned short h = f2bf(v);
            g_A1hi[row*64 + col] = h;                    // == [s][pos*64+oc]
            g_A1lo[row*64 + col] = f2bf(v - bf2f(h));
        }
    }
}

// ---------------- tail: fc1+enc+critic+actor+query+logits fused (32 samples/block) --------
// Register-budget discipline: critic processes its 256 columns in 4 chunks of 4 n-tiles
// (cacc[2][4] = 32 VGPRs live) consumed immediately -> no spill (R14 had cacc[2][16] = 128
// accumulators + 64 frag regs at VGPR cap 128 => catastrophic scratch spill, 108us @ 0.2% busy).
__global__ __launch_bounds__(256, 2) void tail_kernel(
    const float* __restrict__ fc1b, const float* __restrict__ encb,
    const float* __restrict__ crb,  const float* __restrict__ vw,
    const float* __restrict__ vb,   const float* __restrict__ acb,
    const float* __restrict__ emb,  const float* __restrict__ abias,
    float* __restrict__ out)
{
    const int r0 = blockIdx.x * 32;
    const int tid = threadIdx.x, wave = tid >> 6, lane = tid & 63;
    const int l15 = lane & 15, lhi = lane >> 4;

    __shared__ char smem[63104];
    unsigned short* sA1h = (unsigned short*)smem;                 // [32][264]
    unsigned short* sA1l = (unsigned short*)(smem + 16896);
    unsigned short* sXh  = (unsigned short*)(smem + 33792);       // [32][136]
    unsigned short* sXl  = (unsigned short*)(smem + 42496);
    unsigned short* sHh  = (unsigned short*)smem;                 // [32][136] overlays sA1
    unsigned short* sHl  = (unsigned short*)(smem + 8704);
    unsigned short* cb   = (unsigned short*)(smem + 33792);       // [4][32][72] hi-only
    float* qpart = (float*)(smem + 52224);                        // [4][32][16]
    float* sq    = (float*)(smem + 60416);                        // [32][17]
    float* svred = (float*)(smem + 62592);                        // [4][32]
    float* semb  = (float*)(smem + 33792);                        // [1600] overlays cb

    // ---- stage A1 [32][256] hi/lo ----
    for (int u = tid; u < 1024; u += 256){
        int row = u >> 5, ch8 = (u & 31) * 8;
        *(short8*)&sA1h[row*264 + ch8] = *(const short8*)&g_A1hi[(r0+row)*256 + ch8];
        *(short8*)&sA1l[row*264 + ch8] = *(const short8*)&g_A1lo[(r0+row)*256 + ch8];
    }
    __syncthreads();

    // ---- fc1: M=32, N=128 (wave owns nt = 2w, 2w+1), K=256 -> sX ----
    {
        f32x4 acc[2][2] = {{{0,0,0,0},{0,0,0,0}},{{0,0,0,0},{0,0,0,0}}}; // [t][mt]
        #pragma unroll
        for (int kk8 = 0; kk8 < 8; kk8++){
            const int kk = kk8*32 + lhi*8;
            short8 ah0 = *(const short8*)&sA1h[l15*264 + kk];
            short8 al0 = *(const short8*)&sA1l[l15*264 + kk];
            short8 ah1 = *(const short8*)&sA1h[(16 + l15)*264 + kk];
            short8 al1 = *(const short8*)&sA1l[(16 + l15)*264 + kk];
            #pragma unroll
            for (int t = 0; t < 2; t++){
                const int n = (wave*2 + t)*16 + l15;
                const short8 bh = *(const short8*)&g_fc1hi[n*256 + kk];
                const short8 bl = *(const short8*)&g_fc1lo[n*256 + kk];
                acc[t][0] = __builtin_amdgcn_mfma_f32_16x16x32_bf16(ah0, bh, acc[t][0], 0, 0, 0);
                acc[t][1] = __builtin_amdgcn_mfma_f32_16x16x32_bf16(ah1, bh, acc[t][1], 0, 0, 0);
                acc[t][0] = __builtin_amdgcn_mfma_f32_16x16x32_bf16(al0, bh, acc[t][0], 0, 0, 0);
                acc[t][1] = __builtin_amdgcn_mfma_f32_16x16x32_bf16(al1, bh, acc[t][1], 0, 0, 0);
                acc[t][0] = __builtin_amdgcn_mfma_f32_16x16x32_bf16(ah0, bl, acc[t][0], 0, 0, 0);
                acc[t][1] = __builtin_amdgcn_mfma_f32_16x16x32_bf16(ah1, bl, acc[t][1], 0, 0, 0);
            }
        }
        __syncthreads();
        #pragma unroll
        for (int t = 0; t < 2; t++){
            const int col = (wave*2 + t)*16 + l15;
            const float bb = fc1b[col];
            #pragma unroll
            for (int mt = 0; mt < 2; mt++){
                #pragma unroll
                for (int j = 0; j < 4; j++){
                    const int row = mt*16 + lhi*4 + j;
                    float v = fmaxf(acc[t][mt][j] + bb, 0.f);
                    unsigned short h = f2bf(v);
                    sXh[row*136 + col] = h;
                    sXl[row*136 + col] = f2bf(v - bf2f(h));
                }
            }
        }
    }
    __syncthreads();

    // ---- enc: M=32, N=128, K=128 -> sH (overlays dead sA1) ----
    {
        f32x4 acc[2][2] = {{{0,0,0,0},{0,0,0,0}},{{0,0,0,0},{0,0,0,0}}};
        #pragma unroll
        for (int kk4 = 0; kk4 < 4; kk4++){
            const int kk = kk4*32 + lhi*8;
            short8 ah0 = *(const short8*)&sXh[l15*136 + kk];
            short8 al0 = *(const short8*)&sXl[l15*136 + kk];
            short8 ah1 = *(const short8*)&sXh[(16 + l15)*136 + kk];
            short8 al1 = *(const short8*)&sXl[(16 + l15)*136 + kk];
            #pragma unroll
            for (int t = 0; t < 2; t++){
                const int n = (wave*2 + t)*16 + l15;
                const short8 bh = *(const short8*)&g_enchi[n*128 + kk];
                const short8 bl = *(const short8*)&g_enclo[n*128 + kk];
                acc[t][0] = __builtin_amdgcn_mfma_f32_16x16x32_bf16(ah0, bh, acc[t][0], 0, 0, 0);
                acc[t][1] = __builtin_amdgcn_mfma_f32_16x16x32_bf16(ah1, bh, acc[t][1], 0, 0, 0);
                acc[t][0] = __builtin_amdgcn_mfma_f32_16x16x32_bf16(al0, bh, acc[t][0], 0, 0, 0);
                acc[t][1] = __builtin_amdgcn_mfma_f32_16x16x32_bf16(al1, bh, acc[t][1], 0, 0, 0);
                acc[t][0] = __builtin_amdgcn_mfma_f32_16x16x32_bf16(ah0, bl, acc[t][0], 0, 0, 0);
                acc[t][1] = __builtin_amdgcn_mfma_f32_16x16x32_bf16(ah1, bl, acc[t][1], 0, 0, 0);
            }
        }
        __syncthreads();
        #pragma unroll
        for (int t = 0; t < 2; t++){
            const int col = (wave*2 + t)*16 + l15;
            const float bb = encb[col];
            #pragma unroll
            for (int mt = 0; mt < 2; mt++){
                #pragma unroll
                for (int j = 0; j < 4; j++){
                    const int row = mt*16 + lhi*4 + j;
                    float v = fmaxf(acc[t][mt][j] + bb, 0.f);
                    unsigned short h = f2bf(v);
                    sHh[row*136 + col] = h;
                    sHl[row*136 + col] = f2bf(v - bf2f(h));
                }
            }
        }
    }
    __syncthreads();

    // ---- hoist H A-fragments (shared by critic and actor; K=128) ----
    short8 Ah[2][4], Al[2][4];
    #pragma unroll
    for (int mt = 0; mt < 2; mt++)
        #pragma unroll
        for (int kk4 = 0; kk4 < 4; kk4++){
            const int kk = kk4*32 + lhi*8;
            Ah[mt][kk4] = *(const short8*)&sHh[(mt*16 + l15)*136 + kk];
            Al[mt][kk4] = *(const short8*)&sHl[(mt*16 + l15)*136 + kk];
        }

    // ---- critic: wave owns 256 cols; CHUNKED accumulate (4 n-tiles at a time) ----
    {
        float vp[8] = {0,0,0,0,0,0,0,0};       // [mt*4+j]
        #pragma unroll
        for (int ntc = 0; ntc < 4; ntc++){
            f32x4 cacc[2][4];
            #pragma unroll
            for (int mt = 0; mt < 2; mt++)
                #pragma unroll
                for (int q = 0; q < 4; q++) cacc[mt][q] = f32x4{0,0,0,0};
            #pragma unroll
            for (int q = 0; q < 4; q++){
                const int n = wave*256 + (ntc*4 + q)*16 + l15;
                #pragma unroll
                for (int kk4 = 0; kk4 < 4; kk4++){
                    const short8 bh = *(const short8*)&g_crhi[n*128 + kk4*32 + lhi*8];
                    const short8 bl = *(const short8*)&g_crlo[n*128 + kk4*32 + lhi*8];
                    cacc[0][q] = __builtin_amdgcn_mfma_f32_16x16x32_bf16(Ah[0][kk4], bh, cacc[0][q], 0, 0, 0);
                    cacc[1][q] = __builtin_amdgcn_mfma_f32_16x16x32_bf16(Ah[1][kk4], bh, cacc[1][q], 0, 0, 0);
                    cacc[0][q] = __builtin_amdgcn_mfma_f32_16x16x32_bf16(Al[0][kk4], bh, cacc[0][q], 0, 0, 0);
                    cacc[1][q] = __builtin_amdgcn_mfma_f32_16x16x32_bf16(Al[1][kk4], bh, cacc[1][q], 0, 0, 0);
                    cacc[0][q] = __builtin_amdgcn_mfma_f32_16x16x32_bf16(Ah[0][kk4], bl, cacc[0][q], 0, 0, 0);
                    cacc[1][q] = __builtin_amdgcn_mfma_f32_16x16x32_bf16(Ah[1][kk4], bl, cacc[1][q], 0, 0, 0);
                }
            }
            #pragma unroll
            for (int q = 0; q < 4; q++){
                const int n = wave*256 + (ntc*4 + q)*16 + l15;
                const float w = vw[n], bb = crb[n];
                #pragma unroll
                for (int mt = 0; mt < 2; mt++)
                    #pragma unroll
                    for (int j = 0; j < 4; j++)
                        vp[mt*4+j] += tanhf(cacc[mt][q][j] + bb) * w;
            }
        }
        #pragma unroll
        for (int m = 1; m < 16; m <<= 1)
            #pragma unroll
            for (int q = 0; q < 8; q++) vp[q] += __shfl_xor(vp[q], m, 64);
        if (l15 == 0){
            #pragma unroll
            for (int mt = 0; mt < 2; mt++)
                #pragma unroll
                for (int j = 0; j < 4; j++)
                    svred[wave*32 + mt*16 + lhi*4 + j] = vp[mt*4+j];
        }
    }

    // ---- actor chunks (hi-only LDS) + query mini-GEMM (wave-split K) ----
    f32x4 qacc[2] = {{0,0,0,0},{0,0,0,0}};
    #pragma unroll
    for (int cc = 0; cc < 2; cc++){
        const int c = wave*2 + cc;                       // chunk 0..7 (64 actor cols each)
        f32x4 aacc[2][4];
        #pragma unroll
        for (int mt = 0; mt < 2; mt++)
            #pragma unroll
            for (int nt = 0; nt < 4; nt++) aacc[mt][nt] = f32x4{0,0,0,0};
        #pragma unroll
        for (int kk4 = 0; kk4 < 4; kk4++){
            #pragma unroll
            for (int nt = 0; nt < 4; nt++){
                const int n = c*64 + nt*16 + l15;
                const short8 bh = *(const short8*)&g_achi[n*128 + kk4*32 + lhi*8];
                const short8 bl = *(const short8*)&g_aclo[n*128 + kk4*32 + lhi*8];
                aacc[0][nt] = __builtin_amdgcn_mfma_f32_16x16x32_bf16(Ah[0][kk4], bh, aacc[0][nt], 0, 0, 0);
                aacc[1][nt] = __builtin_amdgcn_mfma_f32_16x16x32_bf16(Ah[1][kk4], bh, aacc[1][nt], 0, 0, 0);
                aacc[0][nt] = __builtin_amdgcn_mfma_f32_16x16x32_bf16(Al[0][kk4], bh, aacc[0][nt], 0, 0, 0);
                aacc[1][nt] = __builtin_amdgcn_mfma_f32_16x16x32_bf16(Al[1][kk4], bh, aacc[1][nt], 0, 0, 0);
                aacc[0][nt] = __builtin_amdgcn_mfma_f32_16x16x32_bf16(Ah[0][kk4], bl, aacc[0][nt], 0, 0, 0);
                aacc[1][nt] = __builtin_amdgcn_mfma_f32_16x16x32_bf16(Ah[1][kk4], bl, aacc[1][nt], 0, 0, 0);
            }
        }
        // relu + bias -> per-wave LDS chunk [32 rows][64 cols], hi only
        #pragma unroll
        for (int nt = 0; nt < 4; nt++){
            const int col = nt*16 + l15;
            const float bb = acb[c*64 + col];
            #pragma unroll
            for (int mt = 0; mt < 2; mt++)
                #pragma unroll
                for (int j = 0; j < 4; j++){
                    const int row = mt*16 + lhi*4 + j;
                    cb[(wave*32 + row)*72 + col] = f2bf(fmaxf(aacc[mt][nt][j] + bb, 0.f));
                }
        }
        // query partial over this chunk (K=64), B = qW^T rows e=l15 (A hi-only: 2 MFMAs)
        #pragma unroll
        for (int kk2 = 0; kk2 < 2; kk2++){
            const int kk = kk2*32 + lhi*8;
            const short8 qbh = *(const short8*)&g_qWhi[l15*512 + c*64 + kk];
            const short8 qbl = *(const short8*)&g_qWlo[l15*512 + c*64 + kk];
            #pragma unroll
            for (int mt = 0; mt < 2; mt++){
                const short8 qah = *(const short8*)&cb[(wave*32 + mt*16 + l15)*72 + kk];
                qacc[mt] = __builtin_amdgcn_mfma_f32_16x16x32_bf16(qah, qbh, qacc[mt], 0, 0, 0);
                qacc[mt] = __builtin_amdgcn_mfma_f32_16x16x32_bf16(qah, qbl, qacc[mt], 0, 0, 0);
            }
        }
    }
    #pragma unroll
    for (int mt = 0; mt < 2; mt++)
        #pragma unroll
        for (int j = 0; j < 4; j++)
            qpart[(wave*32 + mt*16 + lhi*4 + j)*16 + l15] = qacc[mt][j];
    __syncthreads();

    // value out
    if (tid < 32)
        out[B_*100 + r0 + tid] = svred[tid] + svred[32 + tid] + svred[64 + tid]
                               + svred[96 + tid] + vb[0];
    // finalize q; load semb (overlays dead cb region)
    for (int i = tid; i < 512; i += 256){
        int row = i >> 4, e = i & 15;
        sq[row*17 + e] = tanhf(qpart[row*16 + e] + qpart[(32 + row)*16 + e]
                             + qpart[(64 + row)*16 + e] + qpart[(96 + row)*16 + e]);
    }
    for (int k = tid; k < 1600; k += 256) semb[k] = emb[k];
    __syncthreads();
    // logits
    for (int i = tid; i < 3200; i += 256){
        int row = i / 100, a = i - row*100;
        float s = abias[0];
        #pragma unroll
        for (int e = 0; e < 16; e++) s += sq[row*17 + e] * semb[a*16 + e];
        out[(r0 + row)*100 + a] = s;
    }
}

// ---------------- launch ----------------
extern "C" void kernel_launch(void* const* d_in, const int* in_sizes, int n_in,
                              void* d_out, int out_size, void* d_ws, size_t ws_size,
                              hipStream_t stream) {
    const int*   obs   = (const int*)  d_in[0];
    const float* maxv  = (const float*)d_in[1];
    const float* w1    = (const float*)d_in[2];
    const float* b1    = (const float*)d_in[3];
    const float* w2    = (const float*)d_in[4];
    const float* b2    = (const float*)d_in[5];
    const float* fc1w  = (const float*)d_in[6];
    const float* fc1b  = (const float*)d_in[7];
    const float* encw  = (const float*)d_in[8];
    const float* encb  = (const float*)d_in[9];
    const float* crw   = (const float*)d_in[10];
    const float* crb   = (const float*)d_in[11];
    const float* vw    = (const float*)d_in[12];
    const float* vb    = (const float*)d_in[13];
    const float* acw   = (const float*)d_in[14];
    const float* acb   = (const float*)d_in[15];
    const float* emb   = (const float*)d_in[16];
    const float* aW    = (const float*)d_in[17];
    const float* abias = (const float*)d_in[18];
    float* out = (float*)d_out;

    prep_kernel<<<1336, 256, 0, stream>>>(w1, maxv, w2, fc1w, encw, crw, acw, aW);
    conv1_kernel<<<B_/2, 256, 0, stream>>>(obs, b1);
    conv2_kernel<<<512, 256, 0, stream>>>(b2);
    tail_kernel<<<256, 256, 0, stream>>>(fc1b, encb, crb, vw, vb, acb, emb, abias, out);
}

// Round 16
// 217.815 us; speedup vs baseline: 1.2562x; 1.0532x over previous
//
#include <hip/hip_runtime.h>
#include <math.h>

#define B_ 8192

typedef __attribute__((ext_vector_type(8))) short short8;
typedef __attribute__((ext_vector_type(4))) float f32x4;

// ---------------- persistent device buffers (rewritten every call) ----------------
// weights (hi/lo split bf16, stored as B^T row-major [N][K])
__device__ unsigned short g_w1bh[51200], g_w1bl[51200];    // conv1 W^T [64 oc][800 k], /maxv
__device__ unsigned short g_w2hi[36864],  g_w2lo[36864];   // conv2 [64][576], k'=(kx*3+ky)*64+ic
__device__ unsigned short g_fc1hi[32768], g_fc1lo[32768];  // fc1   [128][256] (k'=pos*64+oc)
__device__ unsigned short g_enchi[16384], g_enclo[16384];  // enc   [128][128]
__device__ unsigned short g_crhi[131072], g_crlo[131072];  // critic[1024][128]
__device__ unsigned short g_achi[65536],  g_aclo[65536];   // actor [512][128]
__device__ unsigned short g_qWhi[8192],   g_qWlo[8192];    // actor_W^T [16][512]
// activations (hi/lo split bf16)
__device__ unsigned short g_ACT1hi[8192*1024], g_ACT1lo[8192*1024]; // conv1 out [s][pos*64+oc]
__device__ unsigned short g_A1hi[8192*256],  g_A1lo[8192*256];  // conv2 out [s][pos*64+oc]

__device__ __forceinline__ unsigned short f2bf(float v){
    unsigned u = __builtin_bit_cast(unsigned, v);
    unsigned r = (u + 0x7fffu + ((u >> 16) & 1u)) >> 16;   // RN-even (finite inputs)
    return (unsigned short)r;
}
__device__ __forceinline__ float bf2f(unsigned short h){
    unsigned u = ((unsigned)h) << 16;
    return __builtin_bit_cast(float, u);
}
__device__ __forceinline__ void split_store(float v, unsigned short* hi, unsigned short* lo){
    unsigned short h = f2bf(v);
    *hi = h;
    *lo = f2bf(v - bf2f(h));
}

// ---------------- prep: transpose + split all weights ----------------
__global__ __launch_bounds__(256) void prep_kernel(
    const float* __restrict__ w1, const float* __restrict__ maxv,
    const float* __restrict__ w2, const float* __restrict__ fc1,
    const float* __restrict__ enc, const float* __restrict__ cr,
    const float* __restrict__ ac, const float* __restrict__ aW)
{
    int d = blockIdx.x * 256 + threadIdx.x;
    if (d < 51200){
        // w1 natural layout [oc][l][dx][dy] IS the B^T [oc][k] layout; scale by 1/maxv[l]
        int k = d % 800, l = k / 25;
        split_store(w1[d] / maxv[l], &g_w1bh[d], &g_w1bl[d]);
        return;
    }
    d -= 51200;
    if (d < 36864){
        int oc = d / 576, k2 = d - oc*576;
        int kxy = k2 >> 6, ic = k2 & 63;               // k' = kxy*64 + ic
        split_store(w2[oc*576 + ic*9 + kxy], &g_w2hi[d], &g_w2lo[d]);
        return;
    }
    d -= 36864;
    if (d < 32768){
        int o = d >> 8, kp = d & 255;                  // k' = pos*64+oc
        split_store(fc1[o*256 + (kp & 63)*4 + (kp >> 6)], &g_fc1hi[d], &g_fc1lo[d]);
        return;
    }
    d -= 32768;
    if (d < 16384){ split_store(enc[d], &g_enchi[d], &g_enclo[d]); return; }
    d -= 16384;
    if (d < 131072){ split_store(cr[d], &g_crhi[d], &g_crlo[d]); return; }
    d -= 131072;
    if (d < 65536){ split_store(ac[d], &g_achi[d], &g_aclo[d]); return; }
    d -= 65536;
    { int e = d >> 9, j = d & 511; split_store(aW[j*16 + e], &g_qWhi[d], &g_qWlo[d]); }
}

// ---------------- conv1 (round-11 proven version) ----------------
// 2 samples/block, 256 threads (4 waves). Wave = nt; both m-tiles per B-load; 2-deep
// B prefetch. 3 blocks/CU (53.3 KB LDS).
#define APITCH 808   // 800 + 8 shorts pad
__global__ __launch_bounds__(256) void conv1_kernel(const int* __restrict__ obs,
                                                    const float* __restrict__ b1)
{
    const int b = blockIdx.x;                 // samples b*2, b*2+1
    const int tid = threadIdx.x;
    const int wave = tid >> 6, lane = tid & 63;
    const int l15 = lane & 15, lhi = lane >> 4;

    __shared__ unsigned short sA[32 * APITCH];      // 51.7 KB
    __shared__ int s_cell[2][200];

    for (int i = tid; i < 4 * APITCH; i += 256)
        *(short8*)&sA[i * 8] = short8{0,0,0,0,0,0,0,0};

    int   cells[2], xs[2], ys[2], ls[2];
    float vals[2];
    bool  valids[2];
    #pragma unroll
    for (int u = 0; u < 2; u++){
        const int slot = tid + u*256;
        valids[u] = false; cells[u] = 0;
        if (slot < 400){
            const int si = (slot >= 200) ? 1 : 0;
            const int k  = slot - si*200;
            const int base = (b*2 + si)*600 + k*3;
            int coord = obs[base], atr = obs[base+1], val = obs[base+2];
            bool valid = (coord != 255) && (atr < 32);
            xs[u] = (coord >> 4) & 15;  ys[u] = coord & 15;  ls[u] = atr;
            cells[u] = valid ? (atr*256 + xs[u]*16 + ys[u]) : 0;   // invalid claims cell 0
            vals[u]  = (float)val;
            valids[u] = valid;
            s_cell[si][k] = cells[u];
        }
    }
    __syncthreads();
    // last-wins dedup + scatter (writes exclusive: (pos,l,dx,dy) <-> box cell bijective;
    // x>=14 / y>=14 taps are auto-excluded by the wx/wy < 5 bounds)
    #pragma unroll
    for (int u = 0; u < 2; u++){
        const int slot = tid + u*256;
        if (slot < 400){
            const int si = (slot >= 200) ? 1 : 0;
            const int k  = slot - si*200;
            const int c  = cells[u];
            bool kept = true;
            #pragma unroll 4
            for (int j = 0; j < 200; j++){
                int cj = s_cell[si][j];
                kept &= (j <= k) | (cj != c);
            }
            if (kept && valids[u]){
                const int x3 = xs[u]/3, rx = xs[u] - 3*x3;
                const int y3 = ys[u]/3, ry = ys[u] - 3*y3;
                const unsigned short hv = f2bf(vals[u]);     // exact (integer <= 255)
                #pragma unroll
                for (int d = 0; d < 4; d++){
                    const int dxd = d >> 1, dyd = d & 1;
                    const int ox = x3 - dxd, oy = y3 - dyd;
                    const int wx = rx + 3*dxd, wy = ry + 3*dyd;
                    if (((unsigned)ox <= 3u) && ((unsigned)oy <= 3u) && (wx < 5) && (wy < 5))
                        sA[(si*16 + ox*4 + oy)*APITCH + ls[u]*25 + wx*5 + wy] = hv;
                }
            }
        }
    }
    __syncthreads();

    // MFMA: wave = nt; n = wave*16 + l15; both m-tiles per B-load; 2-deep B prefetch.
    const int n = wave*16 + l15;
    const unsigned short* Bh = &g_w1bh[n*800];
    const unsigned short* Bl = &g_w1bl[n*800];
    const unsigned short* A0 = &sA[l15*APITCH];
    const unsigned short* A1 = &sA[(16 + l15)*APITCH];
    f32x4 acc0 = {0,0,0,0}, acc1 = {0,0,0,0};
    short8 bh0 = *(const short8*)&Bh[lhi*8];
    short8 bl0 = *(const short8*)&Bl[lhi*8];
    short8 bh1 = *(const short8*)&Bh[32 + lhi*8];
    short8 bl1 = *(const short8*)&Bl[32 + lhi*8];
    #pragma unroll
    for (int kc = 0; kc < 25; kc++){
        const int kk = kc*32 + lhi*8;
        short8 a0 = *(const short8*)&A0[kk];
        short8 a1 = *(const short8*)&A1[kk];
        short8 bhn, bln;
        if (kc < 23){
            bhn = *(const short8*)&Bh[kk + 64];
            bln = *(const short8*)&Bl[kk + 64];
        }
        acc0 = __builtin_amdgcn_mfma_f32_16x16x32_bf16(a0, bh0, acc0, 0, 0, 0);
        acc1 = __builtin_amdgcn_mfma_f32_16x16x32_bf16(a1, bh0, acc1, 0, 0, 0);
        acc0 = __builtin_amdgcn_mfma_f32_16x16x32_bf16(a0, bl0, acc0, 0, 0, 0);
        acc1 = __builtin_amdgcn_mfma_f32_16x16x32_bf16(a1, bl0, acc1, 0, 0, 0);
        bh0 = bh1; bl0 = bl1; bh1 = bhn; bl1 = bln;
    }
    const float bb = b1[n];
    #pragma unroll
    for (int j = 0; j < 4; j++){
        const int pos = lhi*4 + j;
        float v0 = fmaxf(acc0[j] + bb, 0.f);
        float v1 = fmaxf(acc1[j] + bb, 0.f);
        unsigned short h0 = f2bf(v0), h1 = f2bf(v1);
        const int g0 = (b*2    )*1024 + pos*64 + n;
        const int g1 = (b*2 + 1)*1024 + pos*64 + n;
        g_ACT1hi[g0] = h0;  g_ACT1lo[g0] = f2bf(v0 - bf2f(h0));
        g_ACT1hi[g1] = h1;  g_ACT1lo[g1] = f2bf(v1 - bf2f(h1));
    }
}

// ---------------- conv2: im2col-on-load MFMA GEMM (M=32768, N=64, K=576) ----------------
__global__ __launch_bounds__(256) void conv2_kernel(const float* __restrict__ bias)
{
    const int r0 = blockIdx.x * 64;                      // 16 samples x 4 pos
    const int tid = threadIdx.x, wave = tid >> 6, lane = tid & 63;
    const int l15 = lane & 15, lhi = lane >> 4;

    __shared__ unsigned short sAhi[64][72];
    __shared__ unsigned short sAlo[64][72];

    f32x4 acc[4] = {{0,0,0,0},{0,0,0,0},{0,0,0,0},{0,0,0,0}};
    for (int kc = 0; kc < 9; kc++){                      // (kx,ky) chunk of 64 k's
        const int kx = kc / 3, ky = kc - 3*kx;
        __syncthreads();
        #pragma unroll
        for (int u = 0; u < 2; u++){
            int unit = tid + u*256;
            int row = unit >> 3, ch8 = (unit & 7) * 8;
            int px = (row >> 1) & 1, py = row & 1;       // pos = row&3
            int cell = (px + kx)*4 + (py + ky);
            int g = ((r0 >> 2) + (row >> 2))*1024 + cell*64 + ch8;
            *(short8*)&sAhi[row][ch8] = *(const short8*)&g_ACT1hi[g];
            *(short8*)&sAlo[row][ch8] = *(const short8*)&g_ACT1lo[g];
        }
        __syncthreads();
        #pragma unroll
        for (int ks = 0; ks < 2; ks++){
            const int kk = ks*32 + lhi*8;
            short8 ah = *(const short8*)&sAhi[wave*16 + l15][kk];
            short8 al = *(const short8*)&sAlo[wave*16 + l15][kk];
            #pragma unroll
            for (int nt = 0; nt < 4; nt++){
                const int n = nt*16 + l15;
                const short8 bh = *(const short8*)&g_w2hi[n*576 + kc*64 + kk];
                const short8 bl = *(const short8*)&g_w2lo[n*576 + kc*64 + kk];
                acc[nt] = __builtin_amdgcn_mfma_f32_16x16x32_bf16(ah, bh, acc[nt], 0, 0, 0);
                acc[nt] = __builtin_amdgcn_mfma_f32_16x16x32_bf16(al, bh, acc[nt], 0, 0, 0);
                acc[nt] = __builtin_amdgcn_mfma_f32_16x16x32_bf16(ah, bl, acc[nt], 0, 0, 0);
            }
        }
    }
    #pragma unroll
    for (int nt = 0; nt < 4; nt++){
        const int col = nt*16 + l15;
        const float bb = bias[col];
        #pragma unroll
        for (int j = 0; j < 4; j++){
            const int row = r0 + wave*16 + lhi*4 + j;
            float v = fmaxf(acc[nt][j] + bb, 0.f);
            unsigned short h = f2bf(v);
            g_A1hi[row*64 + col] = h;                    // == [s][pos*64+oc]
            g_A1lo[row*64 + col] = f2bf(v - bf2f(h));
        }
    }
}

// ---------------- tail: fc1+enc+critic+actor+query+logits fused ----------------
// M=16 samples/block, grid 512 -> 2 blocks/CU x 4 waves = 8 waves/CU (R15 had 1 block/CU,
// 4 waves, and a ~900-deep serial L2-load chain per wave => 99.9% idle). Halved per-wave
// chain + doubled concurrency; no LDS overlays (55.4 KB); VGPR cap 256 gives the compiler
// room to batch B-loads.
__global__ __launch_bounds__(256, 2) void tail_kernel(
    const float* __restrict__ fc1b, const float* __restrict__ encb,
    const float* __restrict__ crb,  const float* __restrict__ vw,
    const float* __restrict__ vb,   const float* __restrict__ acb,
    const float* __restrict__ emb,  const float* __restrict__ abias,
    float* __restrict__ out)
{
    const int r0 = blockIdx.x * 16;
    const int tid = threadIdx.x, wave = tid >> 6, lane = tid & 63;
    const int l15 = lane & 15, lhi = lane >> 4;

    __shared__ unsigned short sA1h[16*264], sA1l[16*264];   // 16.9 KB
    __shared__ unsigned short sXh[16*136],  sXl[16*136];    // 8.7 KB
    __shared__ unsigned short sHh[16*136],  sHl[16*136];    // 8.7 KB
    __shared__ unsigned short cb[4*16*72];                  // 9.2 KB (hi-only actor chunks)
    __shared__ float qpart[4*16*16];                        // 4 KB
    __shared__ float sq[16*17];                             // 1.1 KB
    __shared__ float svred[4*16];                           // 0.25 KB
    __shared__ float semb[1600];                            // 6.4 KB

    // ---- stage A1 [16][256] hi/lo ----
    for (int u = tid; u < 512; u += 256){
        int row = u >> 5, ch8 = (u & 31) * 8;
        *(short8*)&sA1h[row*264 + ch8] = *(const short8*)&g_A1hi[(r0+row)*256 + ch8];
        *(short8*)&sA1l[row*264 + ch8] = *(const short8*)&g_A1lo[(r0+row)*256 + ch8];
    }
    __syncthreads();

    // ---- fc1: M=16, N=128 (wave owns nt = 2w, 2w+1), K=256 -> sX ----
    {
        f32x4 acc[2] = {{0,0,0,0},{0,0,0,0}};
        #pragma unroll
        for (int kk8 = 0; kk8 < 8; kk8++){
            const int kk = kk8*32 + lhi*8;
            short8 ah = *(const short8*)&sA1h[l15*264 + kk];
            short8 al = *(const short8*)&sA1l[l15*264 + kk];
            #pragma unroll
            for (int t = 0; t < 2; t++){
                const int n = (wave*2 + t)*16 + l15;
                const short8 bh = *(const short8*)&g_fc1hi[n*256 + kk];
                const short8 bl = *(const short8*)&g_fc1lo[n*256 + kk];
                acc[t] = __builtin_amdgcn_mfma_f32_16x16x32_bf16(ah, bh, acc[t], 0, 0, 0);
                acc[t] = __builtin_amdgcn_mfma_f32_16x16x32_bf16(al, bh, acc[t], 0, 0, 0);
                acc[t] = __builtin_amdgcn_mfma_f32_16x16x32_bf16(ah, bl, acc[t], 0, 0, 0);
            }
        }
        #pragma unroll
        for (int t = 0; t < 2; t++){
            const int col = (wave*2 + t)*16 + l15;
            const float bb = fc1b[col];
            #pragma unroll
            for (int j = 0; j < 4; j++){
                const int row = lhi*4 + j;
                float v = fmaxf(acc[t][j] + bb, 0.f);
                unsigned short h = f2bf(v);
                sXh[row*136 + col] = h;
                sXl[row*136 + col] = f2bf(v - bf2f(h));
            }
        }
    }
    __syncthreads();

    // ---- enc: M=16, N=128, K=128 -> sH ----
    {
        f32x4 acc[2] = {{0,0,0,0},{0,0,0,0}};
        #pragma unroll
        for (int kk4 = 0; kk4 < 4; kk4++){
            const int kk = kk4*32 + lhi*8;
            short8 ah = *(const short8*)&sXh[l15*136 + kk];
            short8 al = *(const short8*)&sXl[l15*136 + kk];
            #pragma unroll
            for (int t = 0; t < 2; t++){
                const int n = (wave*2 + t)*16 + l15;
                const short8 bh = *(const short8*)&g_enchi[n*128 + kk];
                const short8 bl = *(const short8*)&g_enclo[n*128 + kk];
                acc[t] = __builtin_amdgcn_mfma_f32_16x16x32_bf16(ah, bh, acc[t], 0, 0, 0);
                acc[t] = __builtin_amdgcn_mfma_f32_16x16x32_bf16(al, bh, acc[t], 0, 0, 0);
                acc[t] = __builtin_amdgcn_mfma_f32_16x16x32_bf16(ah, bl, acc[t], 0, 0, 0);
            }
        }
        #pragma unroll
        for (int t = 0; t < 2; t++){
            const int col = (wave*2 + t)*16 + l15;
            const float bb = encb[col];
            #pragma unroll
            for (int j = 0; j < 4; j++){
                const int row = lhi*4 + j;
                float v = fmaxf(acc[t][j] + bb, 0.f);
                unsigned short h = f2bf(v);
                sHh[row*136 + col] = h;
                sHl[row*136 + col] = f2bf(v - bf2f(h));
            }
        }
    }
    __syncthreads();

    // ---- hoist H A-fragments (shared by critic and actor; K=128) ----
    short8 Ah[4], Al[4];
    #pragma unroll
    for (int kk4 = 0; kk4 < 4; kk4++){
        const int kk = kk4*32 + lhi*8;
        Ah[kk4] = *(const short8*)&sHh[l15*136 + kk];
        Al[kk4] = *(const short8*)&sHl[l15*136 + kk];
    }

    // ---- critic: wave owns 256 cols (16 n-tiles); chunks of 4; tanh + vw dot ----
    {
        float vp[4] = {0,0,0,0};
        #pragma unroll
        for (int ntc = 0; ntc < 4; ntc++){
            f32x4 cacc[4];
            #pragma unroll
            for (int q = 0; q < 4; q++) cacc[q] = f32x4{0,0,0,0};
            #pragma unroll
            for (int q = 0; q < 4; q++){
                const int n = wave*256 + (ntc*4 + q)*16 + l15;
                #pragma unroll
                for (int kk4 = 0; kk4 < 4; kk4++){
                    const short8 bh = *(const short8*)&g_crhi[n*128 + kk4*32 + lhi*8];
                    const short8 bl = *(const short8*)&g_crlo[n*128 + kk4*32 + lhi*8];
                    cacc[q] = __builtin_amdgcn_mfma_f32_16x16x32_bf16(Ah[kk4], bh, cacc[q], 0, 0, 0);
                    cacc[q] = __builtin_amdgcn_mfma_f32_16x16x32_bf16(Al[kk4], bh, cacc[q], 0, 0, 0);
                    cacc[q] = __builtin_amdgcn_mfma_f32_16x16x32_bf16(Ah[kk4], bl, cacc[q], 0, 0, 0);
                }
            }
            #pragma unroll
            for (int q = 0; q < 4; q++){
                const int n = wave*256 + (ntc*4 + q)*16 + l15;
                const float w = vw[n], bb = crb[n];
                #pragma unroll
                for (int j = 0; j < 4; j++)
                    vp[j] += tanhf(cacc[q][j] + bb) * w;
            }
        }
        #pragma unroll
        for (int m = 1; m < 16; m <<= 1)
            #pragma unroll
            for (int j = 0; j < 4; j++) vp[j] += __shfl_xor(vp[j], m, 64);
        if (l15 == 0){
            #pragma unroll
            for (int j = 0; j < 4; j++)
                svred[wave*16 + lhi*4 + j] = vp[j];
        }
    }

    // ---- actor chunks (hi-only LDS) + query mini-GEMM (wave-split K) ----
    f32x4 qacc = {0,0,0,0};
    #pragma unroll
    for (int cc = 0; cc < 2; cc++){
        const int c = wave*2 + cc;                       // chunk 0..7 (64 actor cols each)
        f32x4 aacc[4];
        #pragma unroll
        for (int nt = 0; nt < 4; nt++) aacc[nt] = f32x4{0,0,0,0};
        #pragma unroll
        for (int kk4 = 0; kk4 < 4; kk4++){
            #pragma unroll
            for (int nt = 0; nt < 4; nt++){
                const int n = c*64 + nt*16 + l15;
                const short8 bh = *(const short8*)&g_achi[n*128 + kk4*32 + lhi*8];
                const short8 bl = *(const short8*)&g_aclo[n*128 + kk4*32 + lhi*8];
                aacc[nt] = __builtin_amdgcn_mfma_f32_16x16x32_bf16(Ah[kk4], bh, aacc[nt], 0, 0, 0);
                aacc[nt] = __builtin_amdgcn_mfma_f32_16x16x32_bf16(Al[kk4], bh, aacc[nt], 0, 0, 0);
                aacc[nt] = __builtin_amdgcn_mfma_f32_16x16x32_bf16(Ah[kk4], bl, aacc[nt], 0, 0, 0);
            }
        }
        // relu + bias -> per-wave LDS chunk [16 rows][64 cols], hi only
        #pragma unroll
        for (int nt = 0; nt < 4; nt++){
            const int col = nt*16 + l15;
            const float bb = acb[c*64 + col];
            #pragma unroll
            for (int j = 0; j < 4; j++){
                const int row = lhi*4 + j;
                cb[(wave*16 + row)*72 + col] = f2bf(fmaxf(aacc[nt][j] + bb, 0.f));
            }
        }
        // query partial over this chunk (K=64), B = qW^T rows e=l15 (A hi-only: 2 MFMAs)
        #pragma unroll
        for (int kk2 = 0; kk2 < 2; kk2++){
            const int kk = kk2*32 + lhi*8;
            const short8 qbh = *(const short8*)&g_qWhi[l15*512 + c*64 + kk];
            const short8 qbl = *(const short8*)&g_qWlo[l15*512 + c*64 + kk];
            const short8 qah = *(const short8*)&cb[(wave*16 + l15)*72 + kk];
            qacc = __builtin_amdgcn_mfma_f32_16x16x32_bf16(qah, qbh, qacc, 0, 0, 0);
            qacc = __builtin_amdgcn_mfma_f32_16x16x32_bf16(qah, qbl, qacc, 0, 0, 0);
        }
    }
    #pragma unroll
    for (int j = 0; j < 4; j++)
        qpart[wave*256 + (lhi*4 + j)*16 + l15] = qacc[j];
    __syncthreads();

    // value out
    if (tid < 16)
        out[B_*100 + r0 + tid] = svred[tid] + svred[16 + tid] + svred[32 + tid]
                               + svred[48 + tid] + vb[0];
    // finalize q (exactly 256 entries = 1 per thread)
    {
        int row = tid >> 4, e = tid & 15;
        sq[row*17 + e] = tanhf(qpart[row*16 + e] + qpart[256 + row*16 + e]
                             + qpart[512 + row*16 + e] + qpart[768 + row*16 + e]);
    }
    for (int k = tid; k < 1600; k += 256) semb[k] = emb[k];
    __syncthreads();
    // logits
    for (int i = tid; i < 1600; i += 256){
        int row = i / 100, a = i - row*100;
        float s = abias[0];
        #pragma unroll
        for (int e = 0; e < 16; e++) s += sq[row*17 + e] * semb[a*16 + e];
        out[(r0 + row)*100 + a] = s;
    }
}

// ---------------- launch ----------------
extern "C" void kernel_launch(void* const* d_in, const int* in_sizes, int n_in,
                              void* d_out, int out_size, void* d_ws, size_t ws_size,
                              hipStream_t stream) {
    const int*   obs   = (const int*)  d_in[0];
    const float* maxv  = (const float*)d_in[1];
    const float* w1    = (const float*)d_in[2];
    const float* b1    = (const float*)d_in[3];
    const float* w2    = (const float*)d_in[4];
    const float* b2    = (const float*)d_in[5];
    const float* fc1w  = (const float*)d_in[6];
    const float* fc1b  = (const float*)d_in[7];
    const float* encw  = (const float*)d_in[8];
    const float* encb  = (const float*)d_in[9];
    const float* crw   = (const float*)d_in[10];
    const float* crb   = (const float*)d_in[11];
    const float* vw    = (const float*)d_in[12];
    const float* vb    = (const float*)d_in[13];
    const float* acw   = (const float*)d_in[14];
    const float* acb   = (const float*)d_in[15];
    const float* emb   = (const float*)d_in[16];
    const float* aW    = (const float*)d_in[17];
    const float* abias = (const float*)d_in[18];
    float* out = (float*)d_out;

    prep_kernel<<<1336, 256, 0, stream>>>(w1, maxv, w2, fc1w, encw, crw, acw, aW);
    conv1_kernel<<<B_/2, 256, 0, stream>>>(obs, b1);
    conv2_kernel<<<512, 256, 0, stream>>>(b2);
    tail_kernel<<<512, 256, 0, stream>>>(fc1b, encb, crb, vw, vb, acb, emb, abias, out);
}

// Round 17
// 198.839 us; speedup vs baseline: 1.3760x; 1.0954x over previous
//
#include <hip/hip_runtime.h>
#include <math.h>

#define B_ 8192

typedef __attribute__((ext_vector_type(8))) short short8;
typedef __attribute__((ext_vector_type(4))) float f32x4;

// ---------------- persistent device buffers (rewritten every call) ----------------
// weights (hi/lo split bf16, stored as B^T row-major [N][K])
__device__ unsigned short g_w1bh[51200], g_w1bl[51200];    // conv1 W^T [64 oc][800 k], /maxv
__device__ unsigned short g_w2hi[36864],  g_w2lo[36864];   // conv2 [64][576], k'=(kx*3+ky)*64+ic
__device__ unsigned short g_fc1hi[32768], g_fc1lo[32768];  // fc1   [128][256] (k'=pos*64+oc)
__device__ unsigned short g_enchi[16384], g_enclo[16384];  // enc   [128][128]
__device__ unsigned short g_crhi[131072], g_crlo[131072];  // critic[1024][128]
__device__ unsigned short g_achi[65536],  g_aclo[65536];   // actor [512][128]
__device__ unsigned short g_qWhi[8192],   g_qWlo[8192];    // actor_W^T [16][512]
// activations (hi/lo split bf16)
__device__ unsigned short g_ACT1hi[8192*1024], g_ACT1lo[8192*1024]; // conv1 out [s][pos*64+oc]
__device__ unsigned short g_A1hi[8192*256],  g_A1lo[8192*256];  // conv2 out [s][pos*64+oc]

__device__ __forceinline__ unsigned short f2bf(float v){
    unsigned u = __builtin_bit_cast(unsigned, v);
    unsigned r = (u + 0x7fffu + ((u >> 16) & 1u)) >> 16;   // RN-even (finite inputs)
    return (unsigned short)r;
}
__device__ __forceinline__ float bf2f(unsigned short h){
    unsigned u = ((unsigned)h) << 16;
    return __builtin_bit_cast(float, u);
}
__device__ __forceinline__ void split_store(float v, unsigned short* hi, unsigned short* lo){
    unsigned short h = f2bf(v);
    *hi = h;
    *lo = f2bf(v - bf2f(h));
}

// ---------------- prep: transpose + split all weights ----------------
__global__ __launch_bounds__(256) void prep_kernel(
    const float* __restrict__ w1, const float* __restrict__ maxv,
    const float* __restrict__ w2, const float* __restrict__ fc1,
    const float* __restrict__ enc, const float* __restrict__ cr,
    const float* __restrict__ ac, const float* __restrict__ aW)
{
    int d = blockIdx.x * 256 + threadIdx.x;
    if (d < 51200){
        // w1 natural layout [oc][l][dx][dy] IS the B^T [oc][k] layout; scale by 1/maxv[l]
        int k = d % 800, l = k / 25;
        split_store(w1[d] / maxv[l], &g_w1bh[d], &g_w1bl[d]);
        return;
    }
    d -= 51200;
    if (d < 36864){
        int oc = d / 576, k2 = d - oc*576;
        int kxy = k2 >> 6, ic = k2 & 63;               // k' = kxy*64 + ic
        split_store(w2[oc*576 + ic*9 + kxy], &g_w2hi[d], &g_w2lo[d]);
        return;
    }
    d -= 36864;
    if (d < 32768){
        int o = d >> 8, kp = d & 255;                  // k' = pos*64+oc
        split_store(fc1[o*256 + (kp & 63)*4 + (kp >> 6)], &g_fc1hi[d], &g_fc1lo[d]);
        return;
    }
    d -= 32768;
    if (d < 16384){ split_store(enc[d], &g_enchi[d], &g_enclo[d]); return; }
    d -= 16384;
    if (d < 131072){ split_store(cr[d], &g_crhi[d], &g_crlo[d]); return; }
    d -= 131072;
    if (d < 65536){ split_store(ac[d], &g_achi[d], &g_aclo[d]); return; }
    d -= 65536;
    { int e = d >> 9, j = d & 511; split_store(aW[j*16 + e], &g_qWhi[d], &g_qWlo[d]); }
}

// ---------------- conv1: pack-max dedup (table overlaid on A-tile) + MFMA GEMM ------------
// 2 samples/block, 256 threads (4 waves). Wave = nt; both m-tiles per B-load; 2-deep
// B prefetch. LDS = exactly the 51712B A-tile (winner table overlays it pre-zeroing,
// s_cell eliminated) -> 3 blocks/CU. Dedup is O(1)/token: init -1, atomicMax(slot), compare.
#define APITCH 808   // 800 + 8 shorts pad
__global__ __launch_bounds__(256) void conv1_kernel(const int* __restrict__ obs,
                                                    const float* __restrict__ b1)
{
    const int b = blockIdx.x;                 // samples b*2, b*2+1
    const int tid = threadIdx.x;
    const int wave = tid >> 6, lane = tid & 63;
    const int l15 = lane & 15, lhi = lane >> 4;

    __shared__ unsigned short sA[32 * APITCH];      // 51712 B; first 32KB doubles as wtab
    int* wtab = (int*)sA;                           // 8192-entry winner table (per pass)

    // slot mapping: slot = tid + u*256 (<400); si = slot>=200; k = slot - si*200
    //   u=0: tid<200 -> (s0, k=tid); tid in [200,256) -> (s1, k=tid-200)
    //   u=1: tid<144 -> (s1, k=tid+56)
    int   cells[2], xs[2], ys[2], ls[2];
    float vals[2];
    bool  valids[2], kept[2];
    #pragma unroll
    for (int u = 0; u < 2; u++){
        const int slot = tid + u*256;
        valids[u] = false; kept[u] = false; cells[u] = 0;
        if (slot < 400){
            const int si = (slot >= 200) ? 1 : 0;
            const int k  = slot - si*200;
            const int base = (b*2 + si)*600 + k*3;
            int coord = obs[base], atr = obs[base+1], val = obs[base+2];
            bool valid = (coord != 255) && (atr < 32);
            xs[u] = (coord >> 4) & 15;  ys[u] = coord & 15;  ls[u] = atr;
            cells[u] = valid ? (atr*256 + xs[u]*16 + ys[u]) : 0;   // invalid claims cell 0
            vals[u]  = (float)val;
            valids[u] = valid;
        }
    }
    // ---- dedup pass A: sample 0 (all in u=0, tid<200); last slot-index wins ----
    if (tid < 200) wtab[cells[0]] = -1;
    __syncthreads();
    if (tid < 200) atomicMax(&wtab[cells[0]], tid);
    __syncthreads();
    if (tid < 200) kept[0] = (wtab[cells[0]] == tid);
    __syncthreads();
    // ---- dedup pass B: sample 1 (u=0 tid>=200 -> k=tid-200; u=1 tid<144 -> k=tid+56) ----
    if (tid >= 200) wtab[cells[0]] = -1;
    if (tid < 144)  wtab[cells[1]] = -1;
    __syncthreads();
    if (tid >= 200) atomicMax(&wtab[cells[0]], tid - 200);
    if (tid < 144)  atomicMax(&wtab[cells[1]], tid + 56);
    __syncthreads();
    if (tid >= 200) kept[0] = (wtab[cells[0]] == tid - 200);
    if (tid < 144)  kept[1] = (wtab[cells[1]] == tid + 56);
    __syncthreads();

    // ---- zero A-tile (overwrites winner table) ----
    for (int i = tid; i < 4 * APITCH; i += 256)
        *(short8*)&sA[i * 8] = short8{0,0,0,0,0,0,0,0};
    __syncthreads();

    // ---- scatter (writes exclusive: (pos,l,dx,dy) <-> box cell bijective;
    //      x>=14 / y>=14 taps auto-excluded by wx/wy < 5 bounds) ----
    #pragma unroll
    for (int u = 0; u < 2; u++){
        const int slot = tid + u*256;
        if (slot < 400 && kept[u] && valids[u]){
            const int si = (slot >= 200) ? 1 : 0;
            const int x3 = xs[u]/3, rx = xs[u] - 3*x3;
            const int y3 = ys[u]/3, ry = ys[u] - 3*y3;
            const unsigned short hv = f2bf(vals[u]);     // exact (integer <= 255)
            #pragma unroll
            for (int d = 0; d < 4; d++){
                const int dxd = d >> 1, dyd = d & 1;
                const int ox = x3 - dxd, oy = y3 - dyd;
                const int wx = rx + 3*dxd, wy = ry + 3*dyd;
                if (((unsigned)ox <= 3u) && ((unsigned)oy <= 3u) && (wx < 5) && (wy < 5))
                    sA[(si*16 + ox*4 + oy)*APITCH + ls[u]*25 + wx*5 + wy] = hv;
            }
        }
    }
    __syncthreads();

    // MFMA: wave = nt; n = wave*16 + l15; both m-tiles per B-load; 2-deep B prefetch.
    const int n = wave*16 + l15;
    const unsigned short* Bh = &g_w1bh[n*800];
    const unsigned short* Bl = &g_w1bl[n*800];
    const unsigned short* A0 = &sA[l15*APITCH];
    const unsigned short* A1 = &sA[(16 + l15)*APITCH];
    f32x4 acc0 = {0,0,0,0}, acc1 = {0,0,0,0};
    short8 bh0 = *(const short8*)&Bh[lhi*8];
    short8 bl0 = *(const short8*)&Bl[lhi*8];
    short8 bh1 = *(const short8*)&Bh[32 + lhi*8];
    short8 bl1 = *(const short8*)&Bl[32 + lhi*8];
    #pragma unroll
    for (int kc = 0; kc < 25; kc++){
        const int kk = kc*32 + lhi*8;
        short8 a0 = *(const short8*)&A0[kk];
        short8 a1 = *(const short8*)&A1[kk];
        short8 bhn, bln;
        if (kc < 23){
            bhn = *(const short8*)&Bh[kk + 64];
            bln = *(const short8*)&Bl[kk + 64];
        }
        acc0 = __builtin_amdgcn_mfma_f32_16x16x32_bf16(a0, bh0, acc0, 0, 0, 0);
        acc1 = __builtin_amdgcn_mfma_f32_16x16x32_bf16(a1, bh0, acc1, 0, 0, 0);
        acc0 = __builtin_amdgcn_mfma_f32_16x16x32_bf16(a0, bl0, acc0, 0, 0, 0);
        acc1 = __builtin_amdgcn_mfma_f32_16x16x32_bf16(a1, bl0, acc1, 0, 0, 0);
        bh0 = bh1; bl0 = bl1; bh1 = bhn; bl1 = bln;
    }
    const float bb = b1[n];
    #pragma unroll
    for (int j = 0; j < 4; j++){
        const int pos = lhi*4 + j;
        float v0 = fmaxf(acc0[j] + bb, 0.f);
        float v1 = fmaxf(acc1[j] + bb, 0.f);
        unsigned short h0 = f2bf(v0), h1 = f2bf(v1);
        const int g0 = (b*2    )*1024 + pos*64 + n;
        const int g1 = (b*2 + 1)*1024 + pos*64 + n;
        g_ACT1hi[g0] = h0;  g_ACT1lo[g0] = f2bf(v0 - bf2f(h0));
        g_ACT1hi[g1] = h1;  g_ACT1lo[g1] = f2bf(v1 - bf2f(h1));
    }
}

// ---------------- conv2: im2col-on-load MFMA GEMM (M=32768, N=64, K=576) ----------------
__global__ __launch_bounds__(256) void conv2_kernel(const float* __restrict__ bias)
{
    const int r0 = blockIdx.x * 64;                      // 16 samples x 4 pos
    const int tid = threadIdx.x, wave = tid >> 6, lane = tid & 63;
    const int l15 = lane & 15, lhi = lane >> 4;

    __shared__ unsigned short sAhi[64][72];
    __shared__ unsigned short sAlo[64][72];

    f32x4 acc[4] = {{0,0,0,0},{0,0,0,0},{0,0,0,0},{0,0,0,0}};
    for (int kc = 0; kc < 9; kc++){                      // (kx,ky) chunk of 64 k's
        const int kx = kc / 3, ky = kc - 3*kx;
        __syncthreads();
        #pragma unroll
        for (int u = 0; u < 2; u++){
            int unit = tid + u*256;
            int row = unit >> 3, ch8 = (unit & 7) * 8;
            int px = (row >> 1) & 1, py = row & 1;       // pos = row&3
            int cell = (px + kx)*4 + (py + ky);
            int g = ((r0 >> 2) + (row >> 2))*1024 + cell*64 + ch8;
            *(short8*)&sAhi[row][ch8] = *(const short8*)&g_ACT1hi[g];
            *(short8*)&sAlo[row][ch8] = *(const short8*)&g_ACT1lo[g];
        }
        __syncthreads();
        #pragma unroll
        for (int ks = 0; ks < 2; ks++){
            const int kk = ks*32 + lhi*8;
            short8 ah = *(const short8*)&sAhi[wave*16 + l15][kk];
            short8 al = *(const short8*)&sAlo[wave*16 + l15][kk];
            #pragma unroll
            for (int nt = 0; nt < 4; nt++){
                const int n = nt*16 + l15;
                const short8 bh = *(const short8*)&g_w2hi[n*576 + kc*64 + kk];
                const short8 bl = *(const short8*)&g_w2lo[n*576 + kc*64 + kk];
                acc[nt] = __builtin_amdgcn_mfma_f32_16x16x32_bf16(ah, bh, acc[nt], 0, 0, 0);
                acc[nt] = __builtin_amdgcn_mfma_f32_16x16x32_bf16(al, bh, acc[nt], 0, 0, 0);
                acc[nt] = __builtin_amdgcn_mfma_f32_16x16x32_bf16(ah, bl, acc[nt], 0, 0, 0);
            }
        }
    }
    #pragma unroll
    for (int nt = 0; nt < 4; nt++){
        const int col = nt*16 + l15;
        const float bb = bias[col];
        #pragma unroll
        for (int j = 0; j < 4; j++){
            const int row = r0 + wave*16 + lhi*4 + j;
            float v = fmaxf(acc[nt][j] + bb, 0.f);
            unsigned short h = f2bf(v);
            g_A1hi[row*64 + col] = h;                    // == [s][pos*64+oc]
            g_A1lo[row*64 + col] = f2bf(v - bf2f(h));
        }
    }
}

// ---------------- tail: fc1+enc+critic+actor+query+logits fused ----------------
// M=16 samples/block, grid 512 -> 2 blocks/CU x 4 waves = 8 waves/CU.
__global__ __launch_bounds__(256, 2) void tail_kernel(
    const float* __restrict__ fc1b, const float* __restrict__ encb,
    const float* __restrict__ crb,  const float* __restrict__ vw,
    const float* __restrict__ vb,   const float* __restrict__ acb,
    const float* __restrict__ emb,  const float* __restrict__ abias,
    float* __restrict__ out)
{
    const int r0 = blockIdx.x * 16;
    const int tid = threadIdx.x, wave = tid >> 6, lane = tid & 63;
    const int l15 = lane & 15, lhi = lane >> 4;

    __shared__ unsigned short sA1h[16*264], sA1l[16*264];   // 16.9 KB
    __shared__ unsigned short sXh[16*136],  sXl[16*136];    // 8.7 KB
    __shared__ unsigned short sHh[16*136],  sHl[16*136];    // 8.7 KB
    __shared__ unsigned short cb[4*16*72];                  // 9.2 KB (hi-only actor chunks)
    __shared__ float qpart[4*16*16];                        // 4 KB
    __shared__ float sq[16*17];                             // 1.1 KB
    __shared__ float svred[4*16];                           // 0.25 KB
    __shared__ float semb[1600];                            // 6.4 KB

    // ---- stage A1 [16][256] hi/lo ----
    for (int u = tid; u < 512; u += 256){
        int row = u >> 5, ch8 = (u & 31) * 8;
        *(short8*)&sA1h[row*264 + ch8] = *(const short8*)&g_A1hi[(r0+row)*256 + ch8];
        *(short8*)&sA1l[row*264 + ch8] = *(const short8*)&g_A1lo[(r0+row)*256 + ch8];
    }
    __syncthreads();

    // ---- fc1: M=16, N=128 (wave owns nt = 2w, 2w+1), K=256 -> sX ----
    {
        f32x4 acc[2] = {{0,0,0,0},{0,0,0,0}};
        #pragma unroll
        for (int kk8 = 0; kk8 < 8; kk8++){
            const int kk = kk8*32 + lhi*8;
            short8 ah = *(const short8*)&sA1h[l15*264 + kk];
            short8 al = *(const short8*)&sA1l[l15*264 + kk];
            #pragma unroll
            for (int t = 0; t < 2; t++){
                const int n = (wave*2 + t)*16 + l15;
                const short8 bh = *(const short8*)&g_fc1hi[n*256 + kk];
                const short8 bl = *(const short8*)&g_fc1lo[n*256 + kk];
                acc[t] = __builtin_amdgcn_mfma_f32_16x16x32_bf16(ah, bh, acc[t], 0, 0, 0);
                acc[t] = __builtin_amdgcn_mfma_f32_16x16x32_bf16(al, bh, acc[t], 0, 0, 0);
                acc[t] = __builtin_amdgcn_mfma_f32_16x16x32_bf16(ah, bl, acc[t], 0, 0, 0);
            }
        }
        #pragma unroll
        for (int t = 0; t < 2; t++){
            const int col = (wave*2 + t)*16 + l15;
            const float bb = fc1b[col];
            #pragma unroll
            for (int j = 0; j < 4; j++){
                const int row = lhi*4 + j;
                float v = fmaxf(acc[t][j] + bb, 0.f);
                unsigned short h = f2bf(v);
                sXh[row*136 + col] = h;
                sXl[row*136 + col] = f2bf(v - bf2f(h));
            }
        }
    }
    __syncthreads();

    // ---- enc: M=16, N=128, K=128 -> sH ----
    {
        f32x4 acc[2] = {{0,0,0,0},{0,0,0,0}};
        #pragma unroll
        for (int kk4 = 0; kk4 < 4; kk4++){
            const int kk = kk4*32 + lhi*8;
            short8 ah = *(const short8*)&sXh[l15*136 + kk];
            short8 al = *(const short8*)&sXl[l15*136 + kk];
            #pragma unroll
            for (int t = 0; t < 2; t++){
                const int n = (wave*2 + t)*16 + l15;
                const short8 bh = *(const short8*)&g_enchi[n*128 + kk];
                const short8 bl = *(const short8*)&g_enclo[n*128 + kk];
                acc[t] = __builtin_amdgcn_mfma_f32_16x16x32_bf16(ah, bh, acc[t], 0, 0, 0);
                acc[t] = __builtin_amdgcn_mfma_f32_16x16x32_bf16(al, bh, acc[t], 0, 0, 0);
                acc[t] = __builtin_amdgcn_mfma_f32_16x16x32_bf16(ah, bl, acc[t], 0, 0, 0);
            }
        }
        #pragma unroll
        for (int t = 0; t < 2; t++){
            const int col = (wave*2 + t)*16 + l15;
            const float bb = encb[col];
            #pragma unroll
            for (int j = 0; j < 4; j++){
                const int row = lhi*4 + j;
                float v = fmaxf(acc[t][j] + bb, 0.f);
                unsigned short h = f2bf(v);
                sHh[row*136 + col] = h;
                sHl[row*136 + col] = f2bf(v - bf2f(h));
            }
        }
    }
    __syncthreads();

    // ---- hoist H A-fragments (shared by critic and actor; K=128) ----
    short8 Ah[4], Al[4];
    #pragma unroll
    for (int kk4 = 0; kk4 < 4; kk4++){
        const int kk = kk4*32 + lhi*8;
        Ah[kk4] = *(const short8*)&sHh[l15*136 + kk];
        Al[kk4] = *(const short8*)&sHl[l15*136 + kk];
    }

    // ---- critic: wave owns 256 cols (16 n-tiles); chunks of 4; tanh + vw dot ----
    {
        float vp[4] = {0,0,0,0};
        #pragma unroll
        for (int ntc = 0; ntc < 4; ntc++){
            f32x4 cacc[4];
            #pragma unroll
            for (int q = 0; q < 4; q++) cacc[q] = f32x4{0,0,0,0};
            #pragma unroll
            for (int q = 0; q < 4; q++){
                const int n = wave*256 + (ntc*4 + q)*16 + l15;
                #pragma unroll
                for (int kk4 = 0; kk4 < 4; kk4++){
                    const short8 bh = *(const short8*)&g_crhi[n*128 + kk4*32 + lhi*8];
                    const short8 bl = *(const short8*)&g_crlo[n*128 + kk4*32 + lhi*8];
                    cacc[q] = __builtin_amdgcn_mfma_f32_16x16x32_bf16(Ah[kk4], bh, cacc[q], 0, 0, 0);
                    cacc[q] = __builtin_amdgcn_mfma_f32_16x16x32_bf16(Al[kk4], bh, cacc[q], 0, 0, 0);
                    cacc[q] = __builtin_amdgcn_mfma_f32_16x16x32_bf16(Ah[kk4], bl, cacc[q], 0, 0, 0);
                }
            }
            #pragma unroll
            for (int q = 0; q < 4; q++){
                const int n = wave*256 + (ntc*4 + q)*16 + l15;
                const float w = vw[n], bb = crb[n];
                #pragma unroll
                for (int j = 0; j < 4; j++)
                    vp[j] += tanhf(cacc[q][j] + bb) * w;
            }
        }
        #pragma unroll
        for (int m = 1; m < 16; m <<= 1)
            #pragma unroll
            for (int j = 0; j < 4; j++) vp[j] += __shfl_xor(vp[j], m, 64);
        if (l15 == 0){
            #pragma unroll
            for (int j = 0; j < 4; j++)
                svred[wave*16 + lhi*4 + j] = vp[j];
        }
    }

    // ---- actor chunks (hi-only LDS) + query mini-GEMM (wave-split K) ----
    f32x4 qacc = {0,0,0,0};
    #pragma unroll
    for (int cc = 0; cc < 2; cc++){
        const int c = wave*2 + cc;                       // chunk 0..7 (64 actor cols each)
        f32x4 aacc[4];
        #pragma unroll
        for (int nt = 0; nt < 4; nt++) aacc[nt] = f32x4{0,0,0,0};
        #pragma unroll
        for (int kk4 = 0; kk4 < 4; kk4++){
            #pragma unroll
            for (int nt = 0; nt < 4; nt++){
                const int n = c*64 + nt*16 + l15;
                const short8 bh = *(const short8*)&g_achi[n*128 + kk4*32 + lhi*8];
                const short8 bl = *(const short8*)&g_aclo[n*128 + kk4*32 + lhi*8];
                aacc[nt] = __builtin_amdgcn_mfma_f32_16x16x32_bf16(Ah[kk4], bh, aacc[nt], 0, 0, 0);
                aacc[nt] = __builtin_amdgcn_mfma_f32_16x16x32_bf16(Al[kk4], bh, aacc[nt], 0, 0, 0);
                aacc[nt] = __builtin_amdgcn_mfma_f32_16x16x32_bf16(Ah[kk4], bl, aacc[nt], 0, 0, 0);
            }
        }
        // relu + bias -> per-wave LDS chunk [16 rows][64 cols], hi only
        #pragma unroll
        for (int nt = 0; nt < 4; nt++){
            const int col = nt*16 + l15;
            const float bb = acb[c*64 + col];
            #pragma unroll
            for (int j = 0; j < 4; j++){
                const int row = lhi*4 + j;
                cb[(wave*16 + row)*72 + col] = f2bf(fmaxf(aacc[nt][j] + bb, 0.f));
            }
        }
        // query partial over this chunk (K=64), B = qW^T rows e=l15 (A hi-only: 2 MFMAs)
        #pragma unroll
        for (int kk2 = 0; kk2 < 2; kk2++){
            const int kk = kk2*32 + lhi*8;
            const short8 qbh = *(const short8*)&g_qWhi[l15*512 + c*64 + kk];
            const short8 qbl = *(const short8*)&g_qWlo[l15*512 + c*64 + kk];
            const short8 qah = *(const short8*)&cb[(wave*16 + l15)*72 + kk];
            qacc = __builtin_amdgcn_mfma_f32_16x16x32_bf16(qah, qbh, qacc, 0, 0, 0);
            qacc = __builtin_amdgcn_mfma_f32_16x16x32_bf16(qah, qbl, qacc, 0, 0, 0);
        }
    }
    #pragma unroll
    for (int j = 0; j < 4; j++)
        qpart[wave*256 + (lhi*4 + j)*16 + l15] = qacc[j];
    __syncthreads();

    // value out
    if (tid < 16)
        out[B_*100 + r0 + tid] = svred[tid] + svred[16 + tid] + svred[32 + tid]
                               + svred[48 + tid] + vb[0];
    // finalize q (exactly 256 entries = 1 per thread)
    {
        int row = tid >> 4, e = tid & 15;
        sq[row*17 + e] = tanhf(qpart[row*16 + e] + qpart[256 + row*16 + e]
                             + qpart[512 + row*16 + e] + qpart[768 + row*16 + e]);
    }
    for (int k = tid; k < 1600; k += 256) semb[k] = emb[k];
    __syncthreads();
    // logits
    for (int i = tid; i < 1600; i += 256){
        int row = i / 100, a = i - row*100;
        float s = abias[0];
        #pragma unroll
        for (int e = 0; e < 16; e++) s += sq[row*17 + e] * semb[a*16 + e];
        out[(r0 + row)*100 + a] = s;
    }
}

// ---------------- launch ----------------
extern "C" void kernel_launch(void* const* d_in, const int* in_sizes, int n_in,
                              void* d_out, int out_size, void* d_ws, size_t ws_size,
                              hipStream_t stream) {
    const int*   obs   = (const int*)  d_in[0];
    const float* maxv  = (const float*)d_in[1];
    const float* w1    = (const float*)d_in[2];
    const float* b1    = (const float*)d_in[3];
    const float* w2    = (const float*)d_in[4];
    const float* b2    = (const float*)d_in[5];
    const float* fc1w  = (const float*)d_in[6];
    const float* fc1b  = (const float*)d_in[7];
    const float* encw  = (const float*)d_in[8];
    const float* encb  = (const float*)d_in[9];
    const float* crw   = (const float*)d_in[10];
    const float* crb   = (const float*)d_in[11];
    const float* vw    = (const float*)d_in[12];
    const float* vb    = (const float*)d_in[13];
    const float* acw   = (const float*)d_in[14];
    const float* acb   = (const float*)d_in[15];
    const float* emb   = (const float*)d_in[16];
    const float* aW    = (const float*)d_in[17];
    const float* abias = (const float*)d_in[18];
    float* out = (float*)d_out;

    prep_kernel<<<1336, 256, 0, stream>>>(w1, maxv, w2, fc1w, encw, crw, acw, aW);
    conv1_kernel<<<B_/2, 256, 0, stream>>>(obs, b1);
    conv2_kernel<<<512, 256, 0, stream>>>(b2);
    tail_kernel<<<512, 256, 0, stream>>>(fc1b, encb, crb, vw, vb, acb, emb, abias, out);
}

// Round 18
// 186.221 us; speedup vs baseline: 1.4693x; 1.0678x over previous
//
#include <hip/hip_runtime.h>
#include <math.h>

#define B_ 8192

typedef __attribute__((ext_vector_type(8))) short short8;
typedef __attribute__((ext_vector_type(4))) float f32x4;

// ---------------- persistent device buffers (rewritten every call) ----------------
// conv1 W^T in wave-coalesced layout [kc(25)][ng(4)][r(16)][k^(32)], /maxv:
//   a wave's 16x16B load is one contiguous 1KB block; per-kc stride = 2048 shorts.
__device__ unsigned short g_w1ph[51200], g_w1pl[51200];
__device__ unsigned short g_w2hi[36864],  g_w2lo[36864];   // conv2 [64][576], k'=(kx*3+ky)*64+ic
__device__ unsigned short g_fc1hi[32768], g_fc1lo[32768];  // fc1   [128][256] (k'=pos*64+oc)
__device__ unsigned short g_enchi[16384], g_enclo[16384];  // enc   [128][128]
__device__ unsigned short g_crhi[131072], g_crlo[131072];  // critic[1024][128]
__device__ unsigned short g_achi[65536],  g_aclo[65536];   // actor [512][128]
__device__ unsigned short g_qWhi[8192],   g_qWlo[8192];    // actor_W^T [16][512]
// activations (hi/lo split bf16)
__device__ unsigned short g_ACT1hi[8192*1024], g_ACT1lo[8192*1024]; // conv1 out [s][pos*64+oc]
__device__ unsigned short g_A1hi[8192*256],  g_A1lo[8192*256];  // conv2 out [s][pos*64+oc]

__device__ __forceinline__ unsigned short f2bf(float v){
    unsigned u = __builtin_bit_cast(unsigned, v);
    unsigned r = (u + 0x7fffu + ((u >> 16) & 1u)) >> 16;   // RN-even (finite inputs)
    return (unsigned short)r;
}
__device__ __forceinline__ float bf2f(unsigned short h){
    unsigned u = ((unsigned)h) << 16;
    return __builtin_bit_cast(float, u);
}
__device__ __forceinline__ void split_store(float v, unsigned short* hi, unsigned short* lo){
    unsigned short h = f2bf(v);
    *hi = h;
    *lo = f2bf(v - bf2f(h));
}

// ---------------- prep: transpose + split all weights ----------------
__global__ __launch_bounds__(256) void prep_kernel(
    const float* __restrict__ w1, const float* __restrict__ maxv,
    const float* __restrict__ w2, const float* __restrict__ fc1,
    const float* __restrict__ enc, const float* __restrict__ cr,
    const float* __restrict__ ac, const float* __restrict__ aW)
{
    int d = blockIdx.x * 256 + threadIdx.x;
    if (d < 51200){
        // w1 natural [oc=n][k=(l,dx,dy)] -> coalesced [kc][ng][r][k^], scaled by 1/maxv[l]
        int n = d / 800, k = d - n*800;
        int l = k / 25;
        float v = w1[d] / maxv[l];
        int kc = k >> 5, kh = k & 31, ng = n >> 4, r = n & 15;
        int idx = ((kc*4 + ng)*16 + r)*32 + kh;
        split_store(v, &g_w1ph[idx], &g_w1pl[idx]);
        return;
    }
    d -= 51200;
    if (d < 36864){
        int oc = d / 576, k2 = d - oc*576;
        int kxy = k2 >> 6, ic = k2 & 63;               // k' = kxy*64 + ic
        split_store(w2[oc*576 + ic*9 + kxy], &g_w2hi[d], &g_w2lo[d]);
        return;
    }
    d -= 36864;
    if (d < 32768){
        int o = d >> 8, kp = d & 255;                  // k' = pos*64+oc
        split_store(fc1[o*256 + (kp & 63)*4 + (kp >> 6)], &g_fc1hi[d], &g_fc1lo[d]);
        return;
    }
    d -= 32768;
    if (d < 16384){ split_store(enc[d], &g_enchi[d], &g_enclo[d]); return; }
    d -= 16384;
    if (d < 131072){ split_store(cr[d], &g_crhi[d], &g_crlo[d]); return; }
    d -= 131072;
    if (d < 65536){ split_store(ac[d], &g_achi[d], &g_aclo[d]); return; }
    d -= 65536;
    { int e = d >> 9, j = d & 511; split_store(aW[j*16 + e], &g_qWhi[d], &g_qWlo[d]); }
}

// ---------------- conv1: pack-max dedup + MFMA GEMM (coalesced B, 4-deep prefetch) --------
// 2 samples/block, 256 threads (4 waves). Wave = nt; both m-tiles per B-load.
// LDS = exactly the 51712B A-tile (winner table overlays it pre-zeroing) -> 3 blocks/CU.
#define APITCH 808   // 800 + 8 shorts pad
__global__ __launch_bounds__(256) void conv1_kernel(const int* __restrict__ obs,
                                                    const float* __restrict__ b1)
{
    const int b = blockIdx.x;                 // samples b*2, b*2+1
    const int tid = threadIdx.x;
    const int wave = tid >> 6, lane = tid & 63;
    const int l15 = lane & 15, lhi = lane >> 4;

    __shared__ unsigned short sA[32 * APITCH];      // 51712 B; first 32KB doubles as wtab
    int* wtab = (int*)sA;                           // 8192-entry winner table (per pass)

    // slot mapping: slot = tid + u*256 (<400); si = slot>=200; k = slot - si*200
    int   cells[2], xs[2], ys[2], ls[2];
    float vals[2];
    bool  valids[2], kept[2];
    #pragma unroll
    for (int u = 0; u < 2; u++){
        const int slot = tid + u*256;
        valids[u] = false; kept[u] = false; cells[u] = 0;
        if (slot < 400){
            const int si = (slot >= 200) ? 1 : 0;
            const int k  = slot - si*200;
            const int base = (b*2 + si)*600 + k*3;
            int coord = obs[base], atr = obs[base+1], val = obs[base+2];
            bool valid = (coord != 255) && (atr < 32);
            xs[u] = (coord >> 4) & 15;  ys[u] = coord & 15;  ls[u] = atr;
            cells[u] = valid ? (atr*256 + xs[u]*16 + ys[u]) : 0;   // invalid claims cell 0
            vals[u]  = (float)val;
            valids[u] = valid;
        }
    }
    // ---- dedup pass A: sample 0 (all in u=0, tid<200); last slot-index wins ----
    if (tid < 200) wtab[cells[0]] = -1;
    __syncthreads();
    if (tid < 200) atomicMax(&wtab[cells[0]], tid);
    __syncthreads();
    if (tid < 200) kept[0] = (wtab[cells[0]] == tid);
    __syncthreads();
    // ---- dedup pass B: sample 1 (u=0 tid>=200 -> k=tid-200; u=1 tid<144 -> k=tid+56) ----
    if (tid >= 200) wtab[cells[0]] = -1;
    if (tid < 144)  wtab[cells[1]] = -1;
    __syncthreads();
    if (tid >= 200) atomicMax(&wtab[cells[0]], tid - 200);
    if (tid < 144)  atomicMax(&wtab[cells[1]], tid + 56);
    __syncthreads();
    if (tid >= 200) kept[0] = (wtab[cells[0]] == tid - 200);
    if (tid < 144)  kept[1] = (wtab[cells[1]] == tid + 56);
    __syncthreads();

    // ---- zero A-tile (overwrites winner table) ----
    for (int i = tid; i < 4 * APITCH; i += 256)
        *(short8*)&sA[i * 8] = short8{0,0,0,0,0,0,0,0};
    __syncthreads();

    // ---- scatter (writes exclusive: (pos,l,dx,dy) <-> box cell bijective;
    //      x>=14 / y>=14 taps auto-excluded by wx/wy < 5 bounds) ----
    #pragma unroll
    for (int u = 0; u < 2; u++){
        const int slot = tid + u*256;
        if (slot < 400 && kept[u] && valids[u]){
            const int si = (slot >= 200) ? 1 : 0;
            const int x3 = xs[u]/3, rx = xs[u] - 3*x3;
            const int y3 = ys[u]/3, ry = ys[u] - 3*y3;
            const unsigned short hv = f2bf(vals[u]);     // exact (integer <= 255)
            #pragma unroll
            for (int d = 0; d < 4; d++){
                const int dxd = d >> 1, dyd = d & 1;
                const int ox = x3 - dxd, oy = y3 - dyd;
                const int wx = rx + 3*dxd, wy = ry + 3*dyd;
                if (((unsigned)ox <= 3u) && ((unsigned)oy <= 3u) && (wx < 5) && (wy < 5))
                    sA[(si*16 + ox*4 + oy)*APITCH + ls[u]*25 + wx*5 + wy] = hv;
            }
        }
    }
    __syncthreads();

    // MFMA: wave = ng; n = ng*16 + l15; both m-tiles per B-load; 4-deep B prefetch;
    // B loads are contiguous 1KB/wave (lane addr = base + l15*64B + lhi*16B).
    const int n = wave*16 + l15;
    const unsigned short* Bh = &g_w1ph[wave*512 + l15*32 + lhi*8];
    const unsigned short* Bl = &g_w1pl[wave*512 + l15*32 + lhi*8];
    const unsigned short* A0 = &sA[l15*APITCH + lhi*8];
    const unsigned short* A1 = &sA[(16 + l15)*APITCH + lhi*8];
    f32x4 acc0 = {0,0,0,0}, acc1 = {0,0,0,0};
    short8 bh0 = *(const short8*)&Bh[0*2048];
    short8 bh1 = *(const short8*)&Bh[1*2048];
    short8 bh2 = *(const short8*)&Bh[2*2048];
    short8 bh3 = *(const short8*)&Bh[3*2048];
    short8 bl0 = *(const short8*)&Bl[0*2048];
    short8 bl1 = *(const short8*)&Bl[1*2048];
    short8 bl2 = *(const short8*)&Bl[2*2048];
    short8 bl3 = *(const short8*)&Bl[3*2048];
    #pragma unroll
    for (int kc = 0; kc < 25; kc++){
        short8 a0 = *(const short8*)&A0[kc*32];
        short8 a1 = *(const short8*)&A1[kc*32];
        short8 bhn, bln;
        if (kc < 21){
            bhn = *(const short8*)&Bh[(kc + 4)*2048];
            bln = *(const short8*)&Bl[(kc + 4)*2048];
        }
        acc0 = __builtin_amdgcn_mfma_f32_16x16x32_bf16(a0, bh0, acc0, 0, 0, 0);
        acc1 = __builtin_amdgcn_mfma_f32_16x16x32_bf16(a1, bh0, acc1, 0, 0, 0);
        acc0 = __builtin_amdgcn_mfma_f32_16x16x32_bf16(a0, bl0, acc0, 0, 0, 0);
        acc1 = __builtin_amdgcn_mfma_f32_16x16x32_bf16(a1, bl0, acc1, 0, 0, 0);
        bh0 = bh1; bh1 = bh2; bh2 = bh3; bh3 = bhn;
        bl0 = bl1; bl1 = bl2; bl2 = bl3; bl3 = bln;
    }
    const float bb = b1[n];
    #pragma unroll
    for (int j = 0; j < 4; j++){
        const int pos = lhi*4 + j;
        float v0 = fmaxf(acc0[j] + bb, 0.f);
        float v1 = fmaxf(acc1[j] + bb, 0.f);
        unsigned short h0 = f2bf(v0), h1 = f2bf(v1);
        const int g0 = (b*2    )*1024 + pos*64 + n;
        const int g1 = (b*2 + 1)*1024 + pos*64 + n;
        g_ACT1hi[g0] = h0;  g_ACT1lo[g0] = f2bf(v0 - bf2f(h0));
        g_ACT1hi[g1] = h1;  g_ACT1lo[g1] = f2bf(v1 - bf2f(h1));
    }
}

// ---------------- conv2: im2col-on-load MFMA GEMM (M=32768, N=64, K=576) ----------------
__global__ __launch_bounds__(256) void conv2_kernel(const float* __restrict__ bias)
{
    const int r0 = blockIdx.x * 64;                      // 16 samples x 4 pos
    const int tid = threadIdx.x, wave = tid >> 6, lane = tid & 63;
    const int l15 = lane & 15, lhi = lane >> 4;

    __shared__ unsigned short sAhi[64][72];
    __shared__ unsigned short sAlo[64][72];

    f32x4 acc[4] = {{0,0,0,0},{0,0,0,0},{0,0,0,0},{0,0,0,0}};
    for (int kc = 0; kc < 9; kc++){                      // (kx,ky) chunk of 64 k's
        const int kx = kc / 3, ky = kc - 3*kx;
        __syncthreads();
        #pragma unroll
        for (int u = 0; u < 2; u++){
            int unit = tid + u*256;
            int row = unit >> 3, ch8 = (unit & 7) * 8;
            int px = (row >> 1) & 1, py = row & 1;       // pos = row&3
            int cell = (px + kx)*4 + (py + ky);
            int g = ((r0 >> 2) + (row >> 2))*1024 + cell*64 + ch8;
            *(short8*)&sAhi[row][ch8] = *(const short8*)&g_ACT1hi[g];
            *(short8*)&sAlo[row][ch8] = *(const short8*)&g_ACT1lo[g];
        }
        __syncthreads();
        #pragma unroll
        for (int ks = 0; ks < 2; ks++){
            const int kk = ks*32 + lhi*8;
            short8 ah = *(const short8*)&sAhi[wave*16 + l15][kk];
            short8 al = *(const short8*)&sAlo[wave*16 + l15][kk];
            #pragma unroll
            for (int nt = 0; nt < 4; nt++){
                const int n = nt*16 + l15;
                const short8 bh = *(const short8*)&g_w2hi[n*576 + kc*64 + kk];
                const short8 bl = *(const short8*)&g_w2lo[n*576 + kc*64 + kk];
                acc[nt] = __builtin_amdgcn_mfma_f32_16x16x32_bf16(ah, bh, acc[nt], 0, 0, 0);
                acc[nt] = __builtin_amdgcn_mfma_f32_16x16x32_bf16(al, bh, acc[nt], 0, 0, 0);
                acc[nt] = __builtin_amdgcn_mfma_f32_16x16x32_bf16(ah, bl, acc[nt], 0, 0, 0);
            }
        }
    }
    #pragma unroll
    for (int nt = 0; nt < 4; nt++){
        const int col = nt*16 + l15;
        const float bb = bias[col];
        #pragma unroll
        for (int j = 0; j < 4; j++){
            const int row = r0 + wave*16 + lhi*4 + j;
            float v = fmaxf(acc[nt][j] + bb, 0.f);
            unsigned short h = f2bf(v);
            g_A1hi[row*64 + col] = h;                    // == [s][pos*64+oc]
            g_A1lo[row*64 + col] = f2bf(v - bf2f(h));
        }
    }
}

// ---------------- tail: fc1+enc+critic+actor+query+logits fused ----------------
// M=16 samples/block, grid 512 -> 2 blocks/CU x 4 waves = 8 waves/CU.
__global__ __launch_bounds__(256, 2) void tail_kernel(
    const float* __restrict__ fc1b, const float* __restrict__ encb,
    const float* __restrict__ crb,  const float* __restrict__ vw,
    const float* __restrict__ vb,   const float* __restrict__ acb,
    const float* __restrict__ emb,  const float* __restrict__ abias,
    float* __restrict__ out)
{
    const int r0 = blockIdx.x * 16;
    const int tid = threadIdx.x, wave = tid >> 6, lane = tid & 63;
    const int l15 = lane & 15, lhi = lane >> 4;

    __shared__ unsigned short sA1h[16*264], sA1l[16*264];   // 16.9 KB
    __shared__ unsigned short sXh[16*136],  sXl[16*136];    // 8.7 KB
    __shared__ unsigned short sHh[16*136],  sHl[16*136];    // 8.7 KB
    __shared__ unsigned short cb[4*16*72];                  // 9.2 KB (hi-only actor chunks)
    __shared__ float qpart[4*16*16];                        // 4 KB
    __shared__ float sq[16*17];                             // 1.1 KB
    __shared__ float svred[4*16];                           // 0.25 KB
    __shared__ float semb[1600];                            // 6.4 KB

    // ---- stage A1 [16][256] hi/lo ----
    for (int u = tid; u < 512; u += 256){
        int row = u >> 5, ch8 = (u & 31) * 8;
        *(short8*)&sA1h[row*264 + ch8] = *(const short8*)&g_A1hi[(r0+row)*256 + ch8];
        *(short8*)&sA1l[row*264 + ch8] = *(const short8*)&g_A1lo[(r0+row)*256 + ch8];
    }
    __syncthreads();

    // ---- fc1: M=16, N=128 (wave owns nt = 2w, 2w+1), K=256 -> sX ----
    {
        f32x4 acc[2] = {{0,0,0,0},{0,0,0,0}};
        #pragma unroll
        for (int kk8 = 0; kk8 < 8; kk8++){
            const int kk = kk8*32 + lhi*8;
            short8 ah = *(const short8*)&sA1h[l15*264 + kk];
            short8 al = *(const short8*)&sA1l[l15*264 + kk];
            #pragma unroll
            for (int t = 0; t < 2; t++){
                const int n = (wave*2 + t)*16 + l15;
                const short8 bh = *(const short8*)&g_fc1hi[n*256 + kk];
                const short8 bl = *(const short8*)&g_fc1lo[n*256 + kk];
                acc[t] = __builtin_amdgcn_mfma_f32_16x16x32_bf16(ah, bh, acc[t], 0, 0, 0);
                acc[t] = __builtin_amdgcn_mfma_f32_16x16x32_bf16(al, bh, acc[t], 0, 0, 0);
                acc[t] = __builtin_amdgcn_mfma_f32_16x16x32_bf16(ah, bl, acc[t], 0, 0, 0);
            }
        }
        #pragma unroll
        for (int t = 0; t < 2; t++){
            const int col = (wave*2 + t)*16 + l15;
            const float bb = fc1b[col];
            #pragma unroll
            for (int j = 0; j < 4; j++){
                const int row = lhi*4 + j;
                float v = fmaxf(acc[t][j] + bb, 0.f);
                unsigned short h = f2bf(v);
                sXh[row*136 + col] = h;
                sXl[row*136 + col] = f2bf(v - bf2f(h));
            }
        }
    }
    __syncthreads();

    // ---- enc: M=16, N=128, K=128 -> sH ----
    {
        f32x4 acc[2] = {{0,0,0,0},{0,0,0,0}};
        #pragma unroll
        for (int kk4 = 0; kk4 < 4; kk4++){
            const int kk = kk4*32 + lhi*8;
            short8 ah = *(const short8*)&sXh[l15*136 + kk];
            short8 al = *(const short8*)&sXl[l15*136 + kk];
            #pragma unroll
            for (int t = 0; t < 2; t++){
                const int n = (wave*2 + t)*16 + l15;
                const short8 bh = *(const short8*)&g_enchi[n*128 + kk];
                const short8 bl = *(const short8*)&g_enclo[n*128 + kk];
                acc[t] = __builtin_amdgcn_mfma_f32_16x16x32_bf16(ah, bh, acc[t], 0, 0, 0);
                acc[t] = __builtin_amdgcn_mfma_f32_16x16x32_bf16(al, bh, acc[t], 0, 0, 0);
                acc[t] = __builtin_amdgcn_mfma_f32_16x16x32_bf16(ah, bl, acc[t], 0, 0, 0);
            }
        }
        #pragma unroll
        for (int t = 0; t < 2; t++){
            const int col = (wave*2 + t)*16 + l15;
            const float bb = encb[col];
            #pragma unroll
            for (int j = 0; j < 4; j++){
                const int row = lhi*4 + j;
                float v = fmaxf(acc[t][j] + bb, 0.f);
                unsigned short h = f2bf(v);
                sHh[row*136 + col] = h;
                sHl[row*136 + col] = f2bf(v - bf2f(h));
            }
        }
    }
    __syncthreads();

    // ---- hoist H A-fragments (shared by critic and actor; K=128) ----
    short8 Ah[4], Al[4];
    #pragma unroll
    for (int kk4 = 0; kk4 < 4; kk4++){
        const int kk = kk4*32 + lhi*8;
        Ah[kk4] = *(const short8*)&sHh[l15*136 + kk];
        Al[kk4] = *(const short8*)&sHl[l15*136 + kk];
    }

    // ---- critic: wave owns 256 cols (16 n-tiles); chunks of 4; tanh + vw dot ----
    {
        float vp[4] = {0,0,0,0};
        #pragma unroll
        for (int ntc = 0; ntc < 4; ntc++){
            f32x4 cacc[4];
            #pragma unroll
            for (int q = 0; q < 4; q++) cacc[q] = f32x4{0,0,0,0};
            #pragma unroll
            for (int q = 0; q < 4; q++){
                const int n = wave*256 + (ntc*4 + q)*16 + l15;
                #pragma unroll
                for (int kk4 = 0; kk4 < 4; kk4++){
                    const short8 bh = *(const short8*)&g_crhi[n*128 + kk4*32 + lhi*8];
                    const short8 bl = *(const short8*)&g_crlo[n*128 + kk4*32 + lhi*8];
                    cacc[q] = __builtin_amdgcn_mfma_f32_16x16x32_bf16(Ah[kk4], bh, cacc[q], 0, 0, 0);
                    cacc[q] = __builtin_amdgcn_mfma_f32_16x16x32_bf16(Al[kk4], bh, cacc[q], 0, 0, 0);
                    cacc[q] = __builtin_amdgcn_mfma_f32_16x16x32_bf16(Ah[kk4], bl, cacc[q], 0, 0, 0);
                }
            }
            #pragma unroll
            for (int q = 0; q < 4; q++){
                const int n = wave*256 + (ntc*4 + q)*16 + l15;
                const float w = vw[n], bb = crb[n];
                #pragma unroll
                for (int j = 0; j < 4; j++)
                    vp[j] += tanhf(cacc[q][j] + bb) * w;
            }
        }
        #pragma unroll
        for (int m = 1; m < 16; m <<= 1)
            #pragma unroll
            for (int j = 0; j < 4; j++) vp[j] += __shfl_xor(vp[j], m, 64);
        if (l15 == 0){
            #pragma unroll
            for (int j = 0; j < 4; j++)
                svred[wave*16 + lhi*4 + j] = vp[j];
        }
    }

    // ---- actor chunks (hi-only LDS) + query mini-GEMM (wave-split K) ----
    f32x4 qacc = {0,0,0,0};
    #pragma unroll
    for (int cc = 0; cc < 2; cc++){
        const int c = wave*2 + cc;                       // chunk 0..7 (64 actor cols each)
        f32x4 aacc[4];
        #pragma unroll
        for (int nt = 0; nt < 4; nt++) aacc[nt] = f32x4{0,0,0,0};
        #pragma unroll
        for (int kk4 = 0; kk4 < 4; kk4++){
            #pragma unroll
            for (int nt = 0; nt < 4; nt++){
                const int n = c*64 + nt*16 + l15;
                const short8 bh = *(const short8*)&g_achi[n*128 + kk4*32 + lhi*8];
                const short8 bl = *(const short8*)&g_aclo[n*128 + kk4*32 + lhi*8];
                aacc[nt] = __builtin_amdgcn_mfma_f32_16x16x32_bf16(Ah[kk4], bh, aacc[nt], 0, 0, 0);
                aacc[nt] = __builtin_amdgcn_mfma_f32_16x16x32_bf16(Al[kk4], bh, aacc[nt], 0, 0, 0);
                aacc[nt] = __builtin_amdgcn_mfma_f32_16x16x32_bf16(Ah[kk4], bl, aacc[nt], 0, 0, 0);
            }
        }
        // relu + bias -> per-wave LDS chunk [16 rows][64 cols], hi only
        #pragma unroll
        for (int nt = 0; nt < 4; nt++){
            const int col = nt*16 + l15;
            const float bb = acb[c*64 + col];
            #pragma unroll
            for (int j = 0; j < 4; j++){
                const int row = lhi*4 + j;
                cb[(wave*16 + row)*72 + col] = f2bf(fmaxf(aacc[nt][j] + bb, 0.f));
            }
        }
        // query partial over this chunk (K=64), B = qW^T rows e=l15 (A hi-only: 2 MFMAs)
        #pragma unroll
        for (int kk2 = 0; kk2 < 2; kk2++){
            const int kk = kk2*32 + lhi*8;
            const short8 qbh = *(const short8*)&g_qWhi[l15*512 + c*64 + kk];
            const short8 qbl = *(const short8*)&g_qWlo[l15*512 + c*64 + kk];
            const short8 qah = *(const short8*)&cb[(wave*16 + l15)*72 + kk];
            qacc = __builtin_amdgcn_mfma_f32_16x16x32_bf16(qah, qbh, qacc, 0, 0, 0);
            qacc = __builtin_amdgcn_mfma_f32_16x16x32_bf16(qah, qbl, qacc, 0, 0, 0);
        }
    }
    #pragma unroll
    for (int j = 0; j < 4; j++)
        qpart[wave*256 + (lhi*4 + j)*16 + l15] = qacc[j];
    __syncthreads();

    // value out
    if (tid < 16)
        out[B_*100 + r0 + tid] = svred[tid] + svred[16 + tid] + svred[32 + tid]
                               + svred[48 + tid] + vb[0];
    // finalize q (exactly 256 entries = 1 per thread)
    {
        int row = tid >> 4, e = tid & 15;
        sq[row*17 + e] = tanhf(qpart[row*16 + e] + qpart[256 + row*16 + e]
                             + qpart[512 + row*16 + e] + qpart[768 + row*16 + e]);
    }
    for (int k = tid; k < 1600; k += 256) semb[k] = emb[k];
    __syncthreads();
    // logits
    for (int i = tid; i < 1600; i += 256){
        int row = i / 100, a = i - row*100;
        float s = abias[0];
        #pragma unroll
        for (int e = 0; e < 16; e++) s += sq[row*17 + e] * semb[a*16 + e];
        out[(r0 + row)*100 + a] = s;
    }
}

// ---------------- launch ----------------
extern "C" void kernel_launch(void* const* d_in, const int* in_sizes, int n_in,
                              void* d_out, int out_size, void* d_ws, size_t ws_size,
                              hipStream_t stream) {
    const int*   obs   = (const int*)  d_in[0];
    const float* maxv  = (const float*)d_in[1];
    const float* w1    = (const float*)d_in[2];
    const float* b1    = (const float*)d_in[3];
    const float* w2    = (const float*)d_in[4];
    const float* b2    = (const float*)d_in[5];
    const float* fc1w  = (const float*)d_in[6];
    const float* fc1b  = (const float*)d_in[7];
    const float* encw  = (const float*)d_in[8];
    const float* encb  = (const float*)d_in[9];
    const float* crw   = (const float*)d_in[10];
    const float* crb   = (const float*)d_in[11];
    const float* vw    = (const float*)d_in[12];
    const float* vb    = (const float*)d_in[13];
    const float* acw   = (const float*)d_in[14];
    const float* acb   = (const float*)d_in[15];
    const float* emb   = (const float*)d_in[16];
    const float* aW    = (const float*)d_in[17];
    const float* abias = (const float*)d_in[18];
    float* out = (float*)d_out;

    prep_kernel<<<1336, 256, 0, stream>>>(w1, maxv, w2, fc1w, encw, crw, acw, aW);
    conv1_kernel<<<B_/2, 256, 0, stream>>>(obs, b1);
    conv2_kernel<<<512, 256, 0, stream>>>(b2);
    tail_kernel<<<512, 256, 0, stream>>>(fc1b, encb, crb, vw, vb, acb, emb, abias, out);
}

// Round 20
// 180.292 us; speedup vs baseline: 1.5176x; 1.0329x over previous
//
#include <hip/hip_runtime.h>
#include <math.h>

#define B_ 8192

typedef __attribute__((ext_vector_type(8))) short short8;
typedef __attribute__((ext_vector_type(4))) float f32x4;

// ---------------- persistent device buffers (rewritten every call) ----------------
// conv1 W^T in wave-coalesced layout [kc(25)][ng(4)][r(16)][k^(32)], /maxv:
//   a wave's 16x16B load is one contiguous 1KB block; per-kc stride = 2048 shorts.
__device__ unsigned short g_w1ph[51200], g_w1pl[51200];
__device__ unsigned short g_w2hi[36864],  g_w2lo[36864];   // conv2 [64][576], k'=(kx*3+ky)*64+ic
__device__ unsigned short g_fc1hi[32768], g_fc1lo[32768];  // fc1   [128][256] (k'=pos*64+oc)
__device__ unsigned short g_enchi[16384], g_enclo[16384];  // enc   [128][128]
__device__ unsigned short g_crhi[131072], g_crlo[131072];  // critic[1024][128]
__device__ unsigned short g_achi[65536],  g_aclo[65536];   // actor [512][128]
__device__ unsigned short g_qWhi[8192],   g_qWlo[8192];    // actor_W^T [16][512]
// activations (hi/lo split bf16)
__device__ unsigned short g_ACT1hi[8192*1024], g_ACT1lo[8192*1024]; // conv1 out [s][pos*64+oc]
__device__ unsigned short g_A1hi[8192*256],  g_A1lo[8192*256];  // conv2 out [s][pos*64+oc]

__device__ __forceinline__ unsigned short f2bf(float v){
    unsigned u = __builtin_bit_cast(unsigned, v);
    unsigned r = (u + 0x7fffu + ((u >> 16) & 1u)) >> 16;   // RN-even (finite inputs)
    return (unsigned short)r;
}
__device__ __forceinline__ float bf2f(unsigned short h){
    unsigned u = ((unsigned)h) << 16;
    return __builtin_bit_cast(float, u);
}
__device__ __forceinline__ void split_store(float v, unsigned short* hi, unsigned short* lo){
    unsigned short h = f2bf(v);
    *hi = h;
    *lo = f2bf(v - bf2f(h));
}

// ---------------- prep: transpose + split all weights ----------------
__global__ __launch_bounds__(256) void prep_kernel(
    const float* __restrict__ w1, const float* __restrict__ maxv,
    const float* __restrict__ w2, const float* __restrict__ fc1,
    const float* __restrict__ enc, const float* __restrict__ cr,
    const float* __restrict__ ac, const float* __restrict__ aW)
{
    int d = blockIdx.x * 256 + threadIdx.x;
    if (d < 51200){
        // w1 natural [oc=n][k=(l,dx,dy)] -> coalesced [kc][ng][r][k^], scaled by 1/maxv[l]
        int n = d / 800, k = d - n*800;
        int l = k / 25;
        float v = w1[d] / maxv[l];
        int kc = k >> 5, kh = k & 31, ng = n >> 4, r = n & 15;
        int idx = ((kc*4 + ng)*16 + r)*32 + kh;
        split_store(v, &g_w1ph[idx], &g_w1pl[idx]);
        return;
    }
    d -= 51200;
    if (d < 36864){
        int oc = d / 576, k2 = d - oc*576;
        int kxy = k2 >> 6, ic = k2 & 63;               // k' = kxy*64 + ic
        split_store(w2[oc*576 + ic*9 + kxy], &g_w2hi[d], &g_w2lo[d]);
        return;
    }
    d -= 36864;
    if (d < 32768){
        int o = d >> 8, kp = d & 255;                  // k' = pos*64+oc
        split_store(fc1[o*256 + (kp & 63)*4 + (kp >> 6)], &g_fc1hi[d], &g_fc1lo[d]);
        return;
    }
    d -= 32768;
    if (d < 16384){ split_store(enc[d], &g_enchi[d], &g_enclo[d]); return; }
    d -= 16384;
    if (d < 131072){ split_store(cr[d], &g_crhi[d], &g_crlo[d]); return; }
    d -= 131072;
    if (d < 65536){ split_store(ac[d], &g_achi[d], &g_aclo[d]); return; }
    d -= 65536;
    { int e = d >> 9, j = d & 511; split_store(aW[j*16 + e], &g_qWhi[d], &g_qWlo[d]); }
}

// ---------------- conv1: pack-max dedup + MFMA GEMM (coalesced B, 4-deep prefetch) --------
#define APITCH 808   // 800 + 8 shorts pad
__global__ __launch_bounds__(256) void conv1_kernel(const int* __restrict__ obs,
                                                    const float* __restrict__ b1)
{
    const int b = blockIdx.x;                 // samples b*2, b*2+1
    const int tid = threadIdx.x;
    const int wave = tid >> 6, lane = tid & 63;
    const int l15 = lane & 15, lhi = lane >> 4;

    __shared__ unsigned short sA[32 * APITCH];      // 51712 B; first 32KB doubles as wtab
    int* wtab = (int*)sA;                           // 8192-entry winner table (per pass)

    int   cells[2], xs[2], ys[2], ls[2];
    float vals[2];
    bool  valids[2], kept[2];
    #pragma unroll
    for (int u = 0; u < 2; u++){
        const int slot = tid + u*256;
        valids[u] = false; kept[u] = false; cells[u] = 0;
        if (slot < 400){
            const int si = (slot >= 200) ? 1 : 0;
            const int k  = slot - si*200;
            const int base = (b*2 + si)*600 + k*3;
            int coord = obs[base], atr = obs[base+1], val = obs[base+2];
            bool valid = (coord != 255) && (atr < 32);
            xs[u] = (coord >> 4) & 15;  ys[u] = coord & 15;  ls[u] = atr;
            cells[u] = valid ? (atr*256 + xs[u]*16 + ys[u]) : 0;   // invalid claims cell 0
            vals[u]  = (float)val;
            valids[u] = valid;
        }
    }
    // dedup pass A: sample 0
    if (tid < 200) wtab[cells[0]] = -1;
    __syncthreads();
    if (tid < 200) atomicMax(&wtab[cells[0]], tid);
    __syncthreads();
    if (tid < 200) kept[0] = (wtab[cells[0]] == tid);
    __syncthreads();
    // dedup pass B: sample 1
    if (tid >= 200) wtab[cells[0]] = -1;
    if (tid < 144)  wtab[cells[1]] = -1;
    __syncthreads();
    if (tid >= 200) atomicMax(&wtab[cells[0]], tid - 200);
    if (tid < 144)  atomicMax(&wtab[cells[1]], tid + 56);
    __syncthreads();
    if (tid >= 200) kept[0] = (wtab[cells[0]] == tid - 200);
    if (tid < 144)  kept[1] = (wtab[cells[1]] == tid + 56);
    __syncthreads();

    // zero A-tile (overwrites winner table)
    for (int i = tid; i < 4 * APITCH; i += 256)
        *(short8*)&sA[i * 8] = short8{0,0,0,0,0,0,0,0};
    __syncthreads();

    // scatter
    #pragma unroll
    for (int u = 0; u < 2; u++){
        const int slot = tid + u*256;
        if (slot < 400 && kept[u] && valids[u]){
            const int si = (slot >= 200) ? 1 : 0;
            const int x3 = xs[u]/3, rx = xs[u] - 3*x3;
            const int y3 = ys[u]/3, ry = ys[u] - 3*y3;
            const unsigned short hv = f2bf(vals[u]);     // exact (integer <= 255)
            #pragma unroll
            for (int d = 0; d < 4; d++){
                const int dxd = d >> 1, dyd = d & 1;
                const int ox = x3 - dxd, oy = y3 - dyd;
                const int wx = rx + 3*dxd, wy = ry + 3*dyd;
                if (((unsigned)ox <= 3u) && ((unsigned)oy <= 3u) && (wx < 5) && (wy < 5))
                    sA[(si*16 + ox*4 + oy)*APITCH + ls[u]*25 + wx*5 + wy] = hv;
            }
        }
    }
    __syncthreads();

    // MFMA: wave = ng; coalesced 1KB B loads; 4-deep prefetch
    const int n = wave*16 + l15;
    const unsigned short* Bh = &g_w1ph[wave*512 + l15*32 + lhi*8];
    const unsigned short* Bl = &g_w1pl[wave*512 + l15*32 + lhi*8];
    const unsigned short* A0 = &sA[l15*APITCH + lhi*8];
    const unsigned short* A1 = &sA[(16 + l15)*APITCH + lhi*8];
    f32x4 acc0 = {0,0,0,0}, acc1 = {0,0,0,0};
    short8 bh0 = *(const short8*)&Bh[0*2048];
    short8 bh1 = *(const short8*)&Bh[1*2048];
    short8 bh2 = *(const short8*)&Bh[2*2048];
    short8 bh3 = *(const short8*)&Bh[3*2048];
    short8 bl0 = *(const short8*)&Bl[0*2048];
    short8 bl1 = *(const short8*)&Bl[1*2048];
    short8 bl2 = *(const short8*)&Bl[2*2048];
    short8 bl3 = *(const short8*)&Bl[3*2048];
    #pragma unroll
    for (int kc = 0; kc < 25; kc++){
        short8 a0 = *(const short8*)&A0[kc*32];
        short8 a1 = *(const short8*)&A1[kc*32];
        short8 bhn, bln;
        if (kc < 21){
            bhn = *(const short8*)&Bh[(kc + 4)*2048];
            bln = *(const short8*)&Bl[(kc + 4)*2048];
        }
        acc0 = __builtin_amdgcn_mfma_f32_16x16x32_bf16(a0, bh0, acc0, 0, 0, 0);
        acc1 = __builtin_amdgcn_mfma_f32_16x16x32_bf16(a1, bh0, acc1, 0, 0, 0);
        acc0 = __builtin_amdgcn_mfma_f32_16x16x32_bf16(a0, bl0, acc0, 0, 0, 0);
        acc1 = __builtin_amdgcn_mfma_f32_16x16x32_bf16(a1, bl0, acc1, 0, 0, 0);
        bh0 = bh1; bh1 = bh2; bh2 = bh3; bh3 = bhn;
        bl0 = bl1; bl1 = bl2; bl2 = bl3; bl3 = bln;
    }
    const float bb = b1[n];
    #pragma unroll
    for (int j = 0; j < 4; j++){
        const int pos = lhi*4 + j;
        float v0 = fmaxf(acc0[j] + bb, 0.f);
        float v1 = fmaxf(acc1[j] + bb, 0.f);
        unsigned short h0 = f2bf(v0), h1 = f2bf(v1);
        const int g0 = (b*2    )*1024 + pos*64 + n;
        const int g1 = (b*2 + 1)*1024 + pos*64 + n;
        g_ACT1hi[g0] = h0;  g_ACT1lo[g0] = f2bf(v0 - bf2f(h0));
        g_ACT1hi[g1] = h1;  g_ACT1lo[g1] = f2bf(v1 - bf2f(h1));
    }
}

// ---------------- conv2: im2col-on-load MFMA GEMM (M=32768, N=64, K=576) ----------------
__global__ __launch_bounds__(256) void conv2_kernel(const float* __restrict__ bias)
{
    const int r0 = blockIdx.x * 64;                      // 16 samples x 4 pos
    const int tid = threadIdx.x, wave = tid >> 6, lane = tid & 63;
    const int l15 = lane & 15, lhi = lane >> 4;

    __shared__ unsigned short sAhi[64][72];
    __shared__ unsigned short sAlo[64][72];

    f32x4 acc[4] = {{0,0,0,0},{0,0,0,0},{0,0,0,0},{0,0,0,0}};
    for (int kc = 0; kc < 9; kc++){                      // (kx,ky) chunk of 64 k's
        const int kx = kc / 3, ky = kc - 3*kx;
        __syncthreads();
        #pragma unroll
        for (int u = 0; u < 2; u++){
            int unit = tid + u*256;
            int row = unit >> 3, ch8 = (unit & 7) * 8;
            int px = (row >> 1) & 1, py = row & 1;       // pos = row&3
            int cell = (px + kx)*4 + (py + ky);
            int g = ((r0 >> 2) + (row >> 2))*1024 + cell*64 + ch8;
            *(short8*)&sAhi[row][ch8] = *(const short8*)&g_ACT1hi[g];
            *(short8*)&sAlo[row][ch8] = *(const short8*)&g_ACT1lo[g];
        }
        __syncthreads();
        #pragma unroll
        for (int ks = 0; ks < 2; ks++){
            const int kk = ks*32 + lhi*8;
            short8 ah = *(const short8*)&sAhi[wave*16 + l15][kk];
            short8 al = *(const short8*)&sAlo[wave*16 + l15][kk];
            #pragma unroll
            for (int nt = 0; nt < 4; nt++){
                const int n = nt*16 + l15;
                const short8 bh = *(const short8*)&g_w2hi[n*576 + kc*64 + kk];
                const short8 bl = *(const short8*)&g_w2lo[n*576 + kc*64 + kk];
                acc[nt] = __builtin_amdgcn_mfma_f32_16x16x32_bf16(ah, bh, acc[nt], 0, 0, 0);
                acc[nt] = __builtin_amdgcn_mfma_f32_16x16x32_bf16(al, bh, acc[nt], 0, 0, 0);
                acc[nt] = __builtin_amdgcn_mfma_f32_16x16x32_bf16(ah, bl, acc[nt], 0, 0, 0);
            }
        }
    }
    #pragma unroll
    for (int nt = 0; nt < 4; nt++){
        const int col = nt*16 + l15;
        const float bb = bias[col];
        #pragma unroll
        for (int j = 0; j < 4; j++){
            const int row = r0 + wave*16 + lhi*4 + j;
            float v = fmaxf(acc[nt][j] + bb, 0.f);
            unsigned short h = f2bf(v);
            g_A1hi[row*64 + col] = h;                    // == [s][pos*64+oc]
            g_A1lo[row*64 + col] = f2bf(v - bf2f(h));
        }
    }
}

// ---------------- tail: fc1+enc+critic+actor+query+logits fused, 8 waves ----------------
// M=16 samples/block, 512 threads (8 waves), grid 512 -> 2 blocks/CU = 4 waves/SIMD.
// Per-wave column ownership halves vs R18 (fc1/enc: 1 n-tile; critic: 128 cols; actor:
// 1x64 chunk) -> serial B-load chain ~124 (was ~250). qpart overlays dead sA1 region.
__global__ __launch_bounds__(512, 4) void tail_kernel(
    const float* __restrict__ fc1b, const float* __restrict__ encb,
    const float* __restrict__ crb,  const float* __restrict__ vw,
    const float* __restrict__ vb,   const float* __restrict__ acb,
    const float* __restrict__ emb,  const float* __restrict__ abias,
    float* __restrict__ out)
{
    const int r0 = blockIdx.x * 16;
    const int tid = threadIdx.x, wave = tid >> 6, lane = tid & 63;
    const int l15 = lane & 15, lhi = lane >> 4;

    __shared__ char smem[60736];
    unsigned short* sA1h = (unsigned short*)smem;                 // [16][264] 8448 B
    unsigned short* sA1l = (unsigned short*)(smem + 8448);        // 8448 B
    float*          qpart= (float*)smem;                          // [8][16][16] 8192 B (overlays dead sA1)
    unsigned short* sXh  = (unsigned short*)(smem + 16896);       // [16][136] 4352 B
    unsigned short* sXl  = (unsigned short*)(smem + 21248);
    unsigned short* sHh  = (unsigned short*)(smem + 25600);
    unsigned short* sHl  = (unsigned short*)(smem + 29952);
    unsigned short* cb   = (unsigned short*)(smem + 34304);       // [8][16][72] 18432 B
    float* sq    = (float*)(smem + 52736);                        // [16][17] 1088 B
    float* svred = (float*)(smem + 53824);                        // [8][16]  512 B
    float* semb  = (float*)(smem + 54336);                        // [1600]   6400 B

    // ---- stage A1 [16][256] hi/lo (one 16B unit per thread) ----
    {
        int row = tid >> 5, ch8 = (tid & 31) * 8;
        *(short8*)&sA1h[row*264 + ch8] = *(const short8*)&g_A1hi[(r0+row)*256 + ch8];
        *(short8*)&sA1l[row*264 + ch8] = *(const short8*)&g_A1lo[(r0+row)*256 + ch8];
    }
    __syncthreads();

    // ---- fc1: M=16, N=128 (wave owns n-tile = wave), K=256 -> sX ----
    {
        f32x4 acc = {0,0,0,0};
        const int n = wave*16 + l15;
        #pragma unroll
        for (int kk8 = 0; kk8 < 8; kk8++){
            const int kk = kk8*32 + lhi*8;
            short8 ah = *(const short8*)&sA1h[l15*264 + kk];
            short8 al = *(const short8*)&sA1l[l15*264 + kk];
            const short8 bh = *(const short8*)&g_fc1hi[n*256 + kk];
            const short8 bl = *(const short8*)&g_fc1lo[n*256 + kk];
            acc = __builtin_amdgcn_mfma_f32_16x16x32_bf16(ah, bh, acc, 0, 0, 0);
            acc = __builtin_amdgcn_mfma_f32_16x16x32_bf16(al, bh, acc, 0, 0, 0);
            acc = __builtin_amdgcn_mfma_f32_16x16x32_bf16(ah, bl, acc, 0, 0, 0);
        }
        __syncthreads();                      // sA1 reads done before qpart may overlay later
        const float bb = fc1b[n];
        #pragma unroll
        for (int j = 0; j < 4; j++){
            const int row = lhi*4 + j;
            float v = fmaxf(acc[j] + bb, 0.f);
            unsigned short h = f2bf(v);
            sXh[row*136 + n] = h;
            sXl[row*136 + n] = f2bf(v - bf2f(h));
        }
    }
    __syncthreads();

    // ---- enc: M=16, N=128 (wave owns n-tile = wave), K=128 -> sH ----
    {
        f32x4 acc = {0,0,0,0};
        const int n = wave*16 + l15;
        #pragma unroll
        for (int kk4 = 0; kk4 < 4; kk4++){
            const int kk = kk4*32 + lhi*8;
            short8 ah = *(const short8*)&sXh[l15*136 + kk];
            short8 al = *(const short8*)&sXl[l15*136 + kk];
            const short8 bh = *(const short8*)&g_enchi[n*128 + kk];
            const short8 bl = *(const short8*)&g_enclo[n*128 + kk];
            acc = __builtin_amdgcn_mfma_f32_16x16x32_bf16(ah, bh, acc, 0, 0, 0);
            acc = __builtin_amdgcn_mfma_f32_16x16x32_bf16(al, bh, acc, 0, 0, 0);
            acc = __builtin_amdgcn_mfma_f32_16x16x32_bf16(ah, bl, acc, 0, 0, 0);
        }
        const float bb = encb[n];
        #pragma unroll
        for (int j = 0; j < 4; j++){
            const int row = lhi*4 + j;
            float v = fmaxf(acc[j] + bb, 0.f);
            unsigned short h = f2bf(v);
            sHh[row*136 + n] = h;
            sHl[row*136 + n] = f2bf(v - bf2f(h));
        }
    }
    __syncthreads();

    // ---- hoist H A-fragments (shared by critic and actor; K=128) ----
    short8 Ah[4], Al[4];
    #pragma unroll
    for (int kk4 = 0; kk4 < 4; kk4++){
        const int kk = kk4*32 + lhi*8;
        Ah[kk4] = *(const short8*)&sHh[l15*136 + kk];
        Al[kk4] = *(const short8*)&sHl[l15*136 + kk];
    }

    // ---- critic: wave owns 128 cols (8 n-tiles); chunks of 4; tanh + vw dot ----
    {
        float vp[4] = {0,0,0,0};
        #pragma unroll
        for (int ntc = 0; ntc < 2; ntc++){
            f32x4 cacc[4];
            #pragma unroll
            for (int q = 0; q < 4; q++) cacc[q] = f32x4{0,0,0,0};
            #pragma unroll
            for (int q = 0; q < 4; q++){
                const int n = wave*128 + (ntc*4 + q)*16 + l15;
                #pragma unroll
                for (int kk4 = 0; kk4 < 4; kk4++){
                    const short8 bh = *(const short8*)&g_crhi[n*128 + kk4*32 + lhi*8];
                    const short8 bl = *(const short8*)&g_crlo[n*128 + kk4*32 + lhi*8];
                    cacc[q] = __builtin_amdgcn_mfma_f32_16x16x32_bf16(Ah[kk4], bh, cacc[q], 0, 0, 0);
                    cacc[q] = __builtin_amdgcn_mfma_f32_16x16x32_bf16(Al[kk4], bh, cacc[q], 0, 0, 0);
                    cacc[q] = __builtin_amdgcn_mfma_f32_16x16x32_bf16(Ah[kk4], bl, cacc[q], 0, 0, 0);
                }
            }
            #pragma unroll
            for (int q = 0; q < 4; q++){
                const int n = wave*128 + (ntc*4 + q)*16 + l15;
                const float w = vw[n], bb = crb[n];
                #pragma unroll
                for (int j = 0; j < 4; j++)
                    vp[j] += tanhf(cacc[q][j] + bb) * w;
            }
        }
        #pragma unroll
        for (int m = 1; m < 16; m <<= 1)
            #pragma unroll
            for (int j = 0; j < 4; j++) vp[j] += __shfl_xor(vp[j], m, 64);
        if (l15 == 0){
            #pragma unroll
            for (int j = 0; j < 4; j++)
                svred[wave*16 + lhi*4 + j] = vp[j];
        }
    }

    // ---- actor chunk (c = wave, 64 cols, hi-only LDS) + query mini-GEMM ----
    f32x4 qacc = {0,0,0,0};
    {
        const int c = wave;
        f32x4 aacc[4];
        #pragma unroll
        for (int nt = 0; nt < 4; nt++) aacc[nt] = f32x4{0,0,0,0};
        #pragma unroll
        for (int kk4 = 0; kk4 < 4; kk4++){
            #pragma unroll
            for (int nt = 0; nt < 4; nt++){
                const int n = c*64 + nt*16 + l15;
                const short8 bh = *(const short8*)&g_achi[n*128 + kk4*32 + lhi*8];
                const short8 bl = *(const short8*)&g_aclo[n*128 + kk4*32 + lhi*8];
                aacc[nt] = __builtin_amdgcn_mfma_f32_16x16x32_bf16(Ah[kk4], bh, aacc[nt], 0, 0, 0);
                aacc[nt] = __builtin_amdgcn_mfma_f32_16x16x32_bf16(Al[kk4], bh, aacc[nt], 0, 0, 0);
                aacc[nt] = __builtin_amdgcn_mfma_f32_16x16x32_bf16(Ah[kk4], bl, aacc[nt], 0, 0, 0);
            }
        }
        // relu + bias -> per-wave LDS chunk [16 rows][64 cols], hi only
        #pragma unroll
        for (int nt = 0; nt < 4; nt++){
            const int col = nt*16 + l15;
            const float bb = acb[c*64 + col];
            #pragma unroll
            for (int j = 0; j < 4; j++){
                const int row = lhi*4 + j;
                cb[(wave*16 + row)*72 + col] = f2bf(fmaxf(aacc[nt][j] + bb, 0.f));
            }
        }
        // query partial over this chunk (K=64), B = qW^T rows e=l15 (A hi-only: 2 MFMAs)
        #pragma unroll
        for (int kk2 = 0; kk2 < 2; kk2++){
            const int kk = kk2*32 + lhi*8;
            const short8 qbh = *(const short8*)&g_qWhi[l15*512 + c*64 + kk];
            const short8 qbl = *(const short8*)&g_qWlo[l15*512 + c*64 + kk];
            const short8 qah = *(const short8*)&cb[(wave*16 + l15)*72 + kk];
            qacc = __builtin_amdgcn_mfma_f32_16x16x32_bf16(qah, qbh, qacc, 0, 0, 0);
            qacc = __builtin_amdgcn_mfma_f32_16x16x32_bf16(qah, qbl, qacc, 0, 0, 0);
        }
    }
    #pragma unroll
    for (int j = 0; j < 4; j++)
        qpart[wave*256 + (lhi*4 + j)*16 + l15] = qacc[j];
    __syncthreads();

    // value out
    if (tid < 16){
        float s = vb[0];
        #pragma unroll
        for (int w = 0; w < 8; w++) s += svred[w*16 + tid];
        out[B_*100 + r0 + tid] = s;
    }
    // finalize q (256 entries)
    if (tid < 256){
        int row = tid >> 4, e = tid & 15;
        float s = 0.f;
        #pragma unroll
        for (int w = 0; w < 8; w++) s += qpart[w*256 + row*16 + e];
        sq[row*17 + e] = tanhf(s);
    }
    for (int k = tid; k < 1600; k += 512) semb[k] = emb[k];
    __syncthreads();
    // logits
    for (int i = tid; i < 1600; i += 512){
        int row = i / 100, a = i - row*100;
        float s = abias[0];
        #pragma unroll
        for (int e = 0; e < 16; e++) s += sq[row*17 + e] * semb[a*16 + e];
        out[(r0 + row)*100 + a] = s;
    }
}

// ---------------- launch ----------------
extern "C" void kernel_launch(void* const* d_in, const int* in_sizes, int n_in,
                              void* d_out, int out_size, void* d_ws, size_t ws_size,
                              hipStream_t stream) {
    const int*   obs   = (const int*)  d_in[0];
    const float* maxv  = (const float*)d_in[1];
    const float* w1    = (const float*)d_in[2];
    const float* b1    = (const float*)d_in[3];
    const float* w2    = (const float*)d_in[4];
    const float* b2    = (const float*)d_in[5];
    const float* fc1w  = (const float*)d_in[6];
    const float* fc1b  = (const float*)d_in[7];
    const float* encw  = (const float*)d_in[8];
    const float* encb  = (const float*)d_in[9];
    const float* crw   = (const float*)d_in[10];
    const float* crb   = (const float*)d_in[11];
    const float* vw    = (const float*)d_in[12];
    const float* vb    = (const float*)d_in[13];
    const float* acw   = (const float*)d_in[14];
    const float* acb   = (const float*)d_in[15];
    const float* emb   = (const float*)d_in[16];
    const float* aW    = (const float*)d_in[17];
    const float* abias = (const float*)d_in[18];
    float* out = (float*)d_out;

    prep_kernel<<<1336, 256, 0, stream>>>(w1, maxv, w2, fc1w, encw, crw, acw, aW);
    conv1_kernel<<<B_/2, 256, 0, stream>>>(obs, b1);
    conv2_kernel<<<512, 256, 0, stream>>>(b2);
    tail_kernel<<<512, 512, 0, stream>>>(fc1b, encb, crb, vw, vb, acb, emb, abias, out);
}

// Round 21
// 153.791 us; speedup vs baseline: 1.7791x; 1.1723x over previous
//
#include <hip/hip_runtime.h>
#include <math.h>

#define B_ 8192

typedef __attribute__((ext_vector_type(8))) short short8;
typedef __attribute__((ext_vector_type(4))) float f32x4;

// ---------------- persistent device buffers (rewritten every call) ----------------
// ALL GEMM B-matrices stored wave-coalesced: [tile][kkc][r(16)][k^(32)] so one wave
// load = one contiguous 1KB block (lane addr = base + l15*64B + lhi*16B).
__device__ unsigned short g_w1ph[51200], g_w1pl[51200];    // conv1 [kc25][ng4][r][k^], /maxv
__device__ unsigned short g_w2hi[36864],  g_w2lo[36864];   // conv2 [64][576], k'=(kx*3+ky)*64+ic (legacy layout)
__device__ unsigned short g_fc1hi[32768], g_fc1lo[32768];  // fc1   [tn8][kk8][r][k^] (k'=pos*64+oc)
__device__ unsigned short g_enchi[16384], g_enclo[16384];  // enc   [tn8][kk4][r][k^]
__device__ unsigned short g_crhi[131072], g_crlo[131072];  // critic[tn64][kk4][r][k^]
__device__ unsigned short g_achi[65536],  g_aclo[65536];   // actor [tn32][kk4][r][k^]
__device__ unsigned short g_qWhi[8192],   g_qWlo[8192];    // qW^T  [ck16][e16][k^32]
// activations (hi/lo split bf16)
__device__ unsigned short g_ACT1hi[8192*1024], g_ACT1lo[8192*1024]; // conv1 out [s][pos*64+oc]
__device__ unsigned short g_A1hi[8192*256],  g_A1lo[8192*256];  // conv2 out [s][pos*64+oc]

__device__ __forceinline__ unsigned short f2bf(float v){
    unsigned u = __builtin_bit_cast(unsigned, v);
    unsigned r = (u + 0x7fffu + ((u >> 16) & 1u)) >> 16;   // RN-even (finite inputs)
    return (unsigned short)r;
}
__device__ __forceinline__ float bf2f(unsigned short h){
    unsigned u = ((unsigned)h) << 16;
    return __builtin_bit_cast(float, u);
}
__device__ __forceinline__ void split_store(float v, unsigned short* hi, unsigned short* lo){
    unsigned short h = f2bf(v);
    *hi = h;
    *lo = f2bf(v - bf2f(h));
}

// ---------------- prep: transpose + split all weights ----------------
__global__ __launch_bounds__(256) void prep_kernel(
    const float* __restrict__ w1, const float* __restrict__ maxv,
    const float* __restrict__ w2, const float* __restrict__ fc1,
    const float* __restrict__ enc, const float* __restrict__ cr,
    const float* __restrict__ ac, const float* __restrict__ aW)
{
    int d = blockIdx.x * 256 + threadIdx.x;
    if (d < 51200){
        // w1 natural [oc=n][k=(l,dx,dy)] -> coalesced [kc][ng][r][k^], scaled by 1/maxv[l]
        int n = d / 800, k = d - n*800;
        int l = k / 25;
        float v = w1[d] / maxv[l];
        int kc = k >> 5, kh = k & 31, ng = n >> 4, r = n & 15;
        int idx = ((kc*4 + ng)*16 + r)*32 + kh;
        split_store(v, &g_w1ph[idx], &g_w1pl[idx]);
        return;
    }
    d -= 51200;
    if (d < 36864){
        int oc = d / 576, k2 = d - oc*576;
        int kxy = k2 >> 6, ic = k2 & 63;               // k' = kxy*64 + ic
        split_store(w2[oc*576 + ic*9 + kxy], &g_w2hi[d], &g_w2lo[d]);
        return;
    }
    d -= 36864;
    if (d < 32768){
        // fc1: n = d>>8, k' = d&255; value fc1[n][ (k'&63)*4 + (k'>>6) ]; coalesced idx
        int n = d >> 8, kp = d & 255;
        float v = fc1[n*256 + (kp & 63)*4 + (kp >> 6)];
        int idx = ((((n >> 4)*8) + (kp >> 5))*16 + (n & 15))*32 + (kp & 31);
        split_store(v, &g_fc1hi[idx], &g_fc1lo[idx]);
        return;
    }
    d -= 32768;
    if (d < 16384){
        int n = d >> 7, k = d & 127;
        int idx = ((((n >> 4)*4) + (k >> 5))*16 + (n & 15))*32 + (k & 31);
        split_store(enc[d], &g_enchi[idx], &g_enclo[idx]);
        return;
    }
    d -= 16384;
    if (d < 131072){
        int n = d >> 7, k = d & 127;
        int idx = ((((n >> 4)*4) + (k >> 5))*16 + (n & 15))*32 + (k & 31);
        split_store(cr[d], &g_crhi[idx], &g_crlo[idx]);
        return;
    }
    d -= 131072;
    if (d < 65536){
        int n = d >> 7, k = d & 127;
        int idx = ((((n >> 4)*4) + (k >> 5))*16 + (n & 15))*32 + (k & 31);
        split_store(ac[d], &g_achi[idx], &g_aclo[idx]);
        return;
    }
    d -= 65536;
    {   // qW^T: e = d>>9, j(k) = d&511; coalesced [ck][e][k^]
        int e = d >> 9, j = d & 511;
        int idx = ((j >> 5)*16 + e)*32 + (j & 31);
        split_store(aW[j*16 + e], &g_qWhi[idx], &g_qWlo[idx]);
    }
}

// ---------------- conv1: pack-max dedup + MFMA GEMM (coalesced B, 4-deep prefetch) --------
#define APITCH 808   // 800 + 8 shorts pad
__global__ __launch_bounds__(256) void conv1_kernel(const int* __restrict__ obs,
                                                    const float* __restrict__ b1)
{
    const int b = blockIdx.x;                 // samples b*2, b*2+1
    const int tid = threadIdx.x;
    const int wave = tid >> 6, lane = tid & 63;
    const int l15 = lane & 15, lhi = lane >> 4;

    __shared__ unsigned short sA[32 * APITCH];      // 51712 B; first 32KB doubles as wtab
    int* wtab = (int*)sA;                           // 8192-entry winner table (per pass)

    int   cells[2], xs[2], ys[2], ls[2];
    float vals[2];
    bool  valids[2], kept[2];
    #pragma unroll
    for (int u = 0; u < 2; u++){
        const int slot = tid + u*256;
        valids[u] = false; kept[u] = false; cells[u] = 0;
        if (slot < 400){
            const int si = (slot >= 200) ? 1 : 0;
            const int k  = slot - si*200;
            const int base = (b*2 + si)*600 + k*3;
            int coord = obs[base], atr = obs[base+1], val = obs[base+2];
            bool valid = (coord != 255) && (atr < 32);
            xs[u] = (coord >> 4) & 15;  ys[u] = coord & 15;  ls[u] = atr;
            cells[u] = valid ? (atr*256 + xs[u]*16 + ys[u]) : 0;   // invalid claims cell 0
            vals[u]  = (float)val;
            valids[u] = valid;
        }
    }
    // dedup pass A: sample 0
    if (tid < 200) wtab[cells[0]] = -1;
    __syncthreads();
    if (tid < 200) atomicMax(&wtab[cells[0]], tid);
    __syncthreads();
    if (tid < 200) kept[0] = (wtab[cells[0]] == tid);
    __syncthreads();
    // dedup pass B: sample 1
    if (tid >= 200) wtab[cells[0]] = -1;
    if (tid < 144)  wtab[cells[1]] = -1;
    __syncthreads();
    if (tid >= 200) atomicMax(&wtab[cells[0]], tid - 200);
    if (tid < 144)  atomicMax(&wtab[cells[1]], tid + 56);
    __syncthreads();
    if (tid >= 200) kept[0] = (wtab[cells[0]] == tid - 200);
    if (tid < 144)  kept[1] = (wtab[cells[1]] == tid + 56);
    __syncthreads();

    // zero A-tile (overwrites winner table)
    for (int i = tid; i < 4 * APITCH; i += 256)
        *(short8*)&sA[i * 8] = short8{0,0,0,0,0,0,0,0};
    __syncthreads();

    // scatter
    #pragma unroll
    for (int u = 0; u < 2; u++){
        const int slot = tid + u*256;
        if (slot < 400 && kept[u] && valids[u]){
            const int si = (slot >= 200) ? 1 : 0;
            const int x3 = xs[u]/3, rx = xs[u] - 3*x3;
            const int y3 = ys[u]/3, ry = ys[u] - 3*y3;
            const unsigned short hv = f2bf(vals[u]);     // exact (integer <= 255)
            #pragma unroll
            for (int d = 0; d < 4; d++){
                const int dxd = d >> 1, dyd = d & 1;
                const int ox = x3 - dxd, oy = y3 - dyd;
                const int wx = rx + 3*dxd, wy = ry + 3*dyd;
                if (((unsigned)ox <= 3u) && ((unsigned)oy <= 3u) && (wx < 5) && (wy < 5))
                    sA[(si*16 + ox*4 + oy)*APITCH + ls[u]*25 + wx*5 + wy] = hv;
            }
        }
    }
    __syncthreads();

    // MFMA: wave = ng; coalesced 1KB B loads; 4-deep prefetch
    const int n = wave*16 + l15;
    const unsigned short* Bh = &g_w1ph[wave*512 + l15*32 + lhi*8];
    const unsigned short* Bl = &g_w1pl[wave*512 + l15*32 + lhi*8];
    const unsigned short* A0 = &sA[l15*APITCH + lhi*8];
    const unsigned short* A1 = &sA[(16 + l15)*APITCH + lhi*8];
    f32x4 acc0 = {0,0,0,0}, acc1 = {0,0,0,0};
    short8 bh0 = *(const short8*)&Bh[0*2048];
    short8 bh1 = *(const short8*)&Bh[1*2048];
    short8 bh2 = *(const short8*)&Bh[2*2048];
    short8 bh3 = *(const short8*)&Bh[3*2048];
    short8 bl0 = *(const short8*)&Bl[0*2048];
    short8 bl1 = *(const short8*)&Bl[1*2048];
    short8 bl2 = *(const short8*)&Bl[2*2048];
    short8 bl3 = *(const short8*)&Bl[3*2048];
    #pragma unroll
    for (int kc = 0; kc < 25; kc++){
        short8 a0 = *(const short8*)&A0[kc*32];
        short8 a1 = *(const short8*)&A1[kc*32];
        short8 bhn, bln;
        if (kc < 21){
            bhn = *(const short8*)&Bh[(kc + 4)*2048];
            bln = *(const short8*)&Bl[(kc + 4)*2048];
        }
        acc0 = __builtin_amdgcn_mfma_f32_16x16x32_bf16(a0, bh0, acc0, 0, 0, 0);
        acc1 = __builtin_amdgcn_mfma_f32_16x16x32_bf16(a1, bh0, acc1, 0, 0, 0);
        acc0 = __builtin_amdgcn_mfma_f32_16x16x32_bf16(a0, bl0, acc0, 0, 0, 0);
        acc1 = __builtin_amdgcn_mfma_f32_16x16x32_bf16(a1, bl0, acc1, 0, 0, 0);
        bh0 = bh1; bh1 = bh2; bh2 = bh3; bh3 = bhn;
        bl0 = bl1; bl1 = bl2; bl2 = bl3; bl3 = bln;
    }
    const float bb = b1[n];
    #pragma unroll
    for (int j = 0; j < 4; j++){
        const int pos = lhi*4 + j;
        float v0 = fmaxf(acc0[j] + bb, 0.f);
        float v1 = fmaxf(acc1[j] + bb, 0.f);
        unsigned short h0 = f2bf(v0), h1 = f2bf(v1);
        const int g0 = (b*2    )*1024 + pos*64 + n;
        const int g1 = (b*2 + 1)*1024 + pos*64 + n;
        g_ACT1hi[g0] = h0;  g_ACT1lo[g0] = f2bf(v0 - bf2f(h0));
        g_ACT1hi[g1] = h1;  g_ACT1lo[g1] = f2bf(v1 - bf2f(h1));
    }
}

// ---------------- conv2: im2col-on-load MFMA GEMM (M=32768, N=64, K=576) ----------------
__global__ __launch_bounds__(256) void conv2_kernel(const float* __restrict__ bias)
{
    const int r0 = blockIdx.x * 64;                      // 16 samples x 4 pos
    const int tid = threadIdx.x, wave = tid >> 6, lane = tid & 63;
    const int l15 = lane & 15, lhi = lane >> 4;

    __shared__ unsigned short sAhi[64][72];
    __shared__ unsigned short sAlo[64][72];

    f32x4 acc[4] = {{0,0,0,0},{0,0,0,0},{0,0,0,0},{0,0,0,0}};
    for (int kc = 0; kc < 9; kc++){                      // (kx,ky) chunk of 64 k's
        const int kx = kc / 3, ky = kc - 3*kx;
        __syncthreads();
        #pragma unroll
        for (int u = 0; u < 2; u++){
            int unit = tid + u*256;
            int row = unit >> 3, ch8 = (unit & 7) * 8;
            int px = (row >> 1) & 1, py = row & 1;       // pos = row&3
            int cell = (px + kx)*4 + (py + ky);
            int g = ((r0 >> 2) + (row >> 2))*1024 + cell*64 + ch8;
            *(short8*)&sAhi[row][ch8] = *(const short8*)&g_ACT1hi[g];
            *(short8*)&sAlo[row][ch8] = *(const short8*)&g_ACT1lo[g];
        }
        __syncthreads();
        #pragma unroll
        for (int ks = 0; ks < 2; ks++){
            const int kk = ks*32 + lhi*8;
            short8 ah = *(const short8*)&sAhi[wave*16 + l15][kk];
            short8 al = *(const short8*)&sAlo[wave*16 + l15][kk];
            #pragma unroll
            for (int nt = 0; nt < 4; nt++){
                const int n = nt*16 + l15;
                const short8 bh = *(const short8*)&g_w2hi[n*576 + kc*64 + kk];
                const short8 bl = *(const short8*)&g_w2lo[n*576 + kc*64 + kk];
                acc[nt] = __builtin_amdgcn_mfma_f32_16x16x32_bf16(ah, bh, acc[nt], 0, 0, 0);
                acc[nt] = __builtin_amdgcn_mfma_f32_16x16x32_bf16(al, bh, acc[nt], 0, 0, 0);
                acc[nt] = __builtin_amdgcn_mfma_f32_16x16x32_bf16(ah, bl, acc[nt], 0, 0, 0);
            }
        }
    }
    #pragma unroll
    for (int nt = 0; nt < 4; nt++){
        const int col = nt*16 + l15;
        const float bb = bias[col];
        #pragma unroll
        for (int j = 0; j < 4; j++){
            const int row = r0 + wave*16 + lhi*4 + j;
            float v = fmaxf(acc[nt][j] + bb, 0.f);
            unsigned short h = f2bf(v);
            g_A1hi[row*64 + col] = h;                    // == [s][pos*64+oc]
            g_A1lo[row*64 + col] = f2bf(v - bf2f(h));
        }
    }
}

// ---------------- tail: fc1+enc+critic+actor+query+logits fused, 8 waves ----------------
// M=16 samples/block, 512 threads (8 waves), grid 512 -> 2 blocks/CU = 4 waves/SIMD.
// ALL B loads now wave-coalesced 1KB blocks (R20 had lane-stride-K scatter: 16x64B
// requests per load instruction).
__global__ __launch_bounds__(512, 4) void tail_kernel(
    const float* __restrict__ fc1b, const float* __restrict__ encb,
    const float* __restrict__ crb,  const float* __restrict__ vw,
    const float* __restrict__ vb,   const float* __restrict__ acb,
    const float* __restrict__ emb,  const float* __restrict__ abias,
    float* __restrict__ out)
{
    const int r0 = blockIdx.x * 16;
    const int tid = threadIdx.x, wave = tid >> 6, lane = tid & 63;
    const int l15 = lane & 15, lhi = lane >> 4;
    const int coff = l15*32 + lhi*8;                     // coalesced lane offset

    __shared__ char smem[60736];
    unsigned short* sA1h = (unsigned short*)smem;                 // [16][264] 8448 B
    unsigned short* sA1l = (unsigned short*)(smem + 8448);        // 8448 B
    float*          qpart= (float*)smem;                          // [8][16][16] 8192 B (overlays dead sA1)
    unsigned short* sXh  = (unsigned short*)(smem + 16896);       // [16][136] 4352 B
    unsigned short* sXl  = (unsigned short*)(smem + 21248);
    unsigned short* sHh  = (unsigned short*)(smem + 25600);
    unsigned short* sHl  = (unsigned short*)(smem + 29952);
    unsigned short* cb   = (unsigned short*)(smem + 34304);       // [8][16][72] 18432 B
    float* sq    = (float*)(smem + 52736);                        // [16][17] 1088 B
    float* svred = (float*)(smem + 53824);                        // [8][16]  512 B
    float* semb  = (float*)(smem + 54336);                        // [1600]   6400 B

    // ---- stage A1 [16][256] hi/lo (one 16B unit per thread) ----
    {
        int row = tid >> 5, ch8 = (tid & 31) * 8;
        *(short8*)&sA1h[row*264 + ch8] = *(const short8*)&g_A1hi[(r0+row)*256 + ch8];
        *(short8*)&sA1l[row*264 + ch8] = *(const short8*)&g_A1lo[(r0+row)*256 + ch8];
    }
    __syncthreads();

    // ---- fc1: M=16, N=128 (wave owns n-tile = wave), K=256 -> sX ----
    {
        f32x4 acc = {0,0,0,0};
        const int n = wave*16 + l15;
        #pragma unroll
        for (int kk8 = 0; kk8 < 8; kk8++){
            const int kk = kk8*32 + lhi*8;
            short8 ah = *(const short8*)&sA1h[l15*264 + kk];
            short8 al = *(const short8*)&sA1l[l15*264 + kk];
            const short8 bh = *(const short8*)&g_fc1hi[(wave*8 + kk8)*512 + coff];
            const short8 bl = *(const short8*)&g_fc1lo[(wave*8 + kk8)*512 + coff];
            acc = __builtin_amdgcn_mfma_f32_16x16x32_bf16(ah, bh, acc, 0, 0, 0);
            acc = __builtin_amdgcn_mfma_f32_16x16x32_bf16(al, bh, acc, 0, 0, 0);
            acc = __builtin_amdgcn_mfma_f32_16x16x32_bf16(ah, bl, acc, 0, 0, 0);
        }
        __syncthreads();                      // sA1 reads done before qpart overlays later
        const float bb = fc1b[n];
        #pragma unroll
        for (int j = 0; j < 4; j++){
            const int row = lhi*4 + j;
            float v = fmaxf(acc[j] + bb, 0.f);
            unsigned short h = f2bf(v);
            sXh[row*136 + n] = h;
            sXl[row*136 + n] = f2bf(v - bf2f(h));
        }
    }
    __syncthreads();

    // ---- enc: M=16, N=128 (wave owns n-tile = wave), K=128 -> sH ----
    {
        f32x4 acc = {0,0,0,0};
        const int n = wave*16 + l15;
        #pragma unroll
        for (int kk4 = 0; kk4 < 4; kk4++){
            const int kk = kk4*32 + lhi*8;
            short8 ah = *(const short8*)&sXh[l15*136 + kk];
            short8 al = *(const short8*)&sXl[l15*136 + kk];
            const short8 bh = *(const short8*)&g_enchi[(wave*4 + kk4)*512 + coff];
            const short8 bl = *(const short8*)&g_enclo[(wave*4 + kk4)*512 + coff];
            acc = __builtin_amdgcn_mfma_f32_16x16x32_bf16(ah, bh, acc, 0, 0, 0);
            acc = __builtin_amdgcn_mfma_f32_16x16x32_bf16(al, bh, acc, 0, 0, 0);
            acc = __builtin_amdgcn_mfma_f32_16x16x32_bf16(ah, bl, acc, 0, 0, 0);
        }
        const float bb = encb[n];
        #pragma unroll
        for (int j = 0; j < 4; j++){
            const int row = lhi*4 + j;
            float v = fmaxf(acc[j] + bb, 0.f);
            unsigned short h = f2bf(v);
            sHh[row*136 + n] = h;
            sHl[row*136 + n] = f2bf(v - bf2f(h));
        }
    }
    __syncthreads();

    // ---- hoist H A-fragments (shared by critic and actor; K=128) ----
    short8 Ah[4], Al[4];
    #pragma unroll
    for (int kk4 = 0; kk4 < 4; kk4++){
        const int kk = kk4*32 + lhi*8;
        Ah[kk4] = *(const short8*)&sHh[l15*136 + kk];
        Al[kk4] = *(const short8*)&sHl[l15*136 + kk];
    }

    // ---- critic: wave owns 128 cols (8 n-tiles); chunks of 4; tanh + vw dot ----
    {
        float vp[4] = {0,0,0,0};
        #pragma unroll
        for (int ntc = 0; ntc < 2; ntc++){
            f32x4 cacc[4];
            #pragma unroll
            for (int q = 0; q < 4; q++) cacc[q] = f32x4{0,0,0,0};
            #pragma unroll
            for (int q = 0; q < 4; q++){
                const int t = wave*8 + ntc*4 + q;        // critic n-tile index
                #pragma unroll
                for (int kk4 = 0; kk4 < 4; kk4++){
                    const short8 bh = *(const short8*)&g_crhi[(t*4 + kk4)*512 + coff];
                    const short8 bl = *(const short8*)&g_crlo[(t*4 + kk4)*512 + coff];
                    cacc[q] = __builtin_amdgcn_mfma_f32_16x16x32_bf16(Ah[kk4], bh, cacc[q], 0, 0, 0);
                    cacc[q] = __builtin_amdgcn_mfma_f32_16x16x32_bf16(Al[kk4], bh, cacc[q], 0, 0, 0);
                    cacc[q] = __builtin_amdgcn_mfma_f32_16x16x32_bf16(Ah[kk4], bl, cacc[q], 0, 0, 0);
                }
            }
            #pragma unroll
            for (int q = 0; q < 4; q++){
                const int n = wave*128 + (ntc*4 + q)*16 + l15;
                const float w = vw[n], bb = crb[n];
                #pragma unroll
                for (int j = 0; j < 4; j++)
                    vp[j] += tanhf(cacc[q][j] + bb) * w;
            }
        }
        #pragma unroll
        for (int m = 1; m < 16; m <<= 1)
            #pragma unroll
            for (int j = 0; j < 4; j++) vp[j] += __shfl_xor(vp[j], m, 64);
        if (l15 == 0){
            #pragma unroll
            for (int j = 0; j < 4; j++)
                svred[wave*16 + lhi*4 + j] = vp[j];
        }
    }

    // ---- actor chunk (c = wave, 64 cols, hi-only LDS) + query mini-GEMM ----
    f32x4 qacc = {0,0,0,0};
    {
        const int c = wave;
        f32x4 aacc[4];
        #pragma unroll
        for (int nt = 0; nt < 4; nt++) aacc[nt] = f32x4{0,0,0,0};
        #pragma unroll
        for (int kk4 = 0; kk4 < 4; kk4++){
            #pragma unroll
            for (int nt = 0; nt < 4; nt++){
                const int t = c*4 + nt;                  // actor n-tile index
                const short8 bh = *(const short8*)&g_achi[(t*4 + kk4)*512 + coff];
                const short8 bl = *(const short8*)&g_aclo[(t*4 + kk4)*512 + coff];
                aacc[nt] = __builtin_amdgcn_mfma_f32_16x16x32_bf16(Ah[kk4], bh, aacc[nt], 0, 0, 0);
                aacc[nt] = __builtin_amdgcn_mfma_f32_16x16x32_bf16(Al[kk4], bh, aacc[nt], 0, 0, 0);
                aacc[nt] = __builtin_amdgcn_mfma_f32_16x16x32_bf16(Ah[kk4], bl, aacc[nt], 0, 0, 0);
            }
        }
        // relu + bias -> per-wave LDS chunk [16 rows][64 cols], hi only
        #pragma unroll
        for (int nt = 0; nt < 4; nt++){
            const int col = nt*16 + l15;
            const float bb = acb[c*64 + col];
            #pragma unroll
            for (int j = 0; j < 4; j++){
                const int row = lhi*4 + j;
                cb[(wave*16 + row)*72 + col] = f2bf(fmaxf(aacc[nt][j] + bb, 0.f));
            }
        }
        // query partial over this chunk (K=64), B = qW^T (coalesced [ck][e][k^])
        #pragma unroll
        for (int kk2 = 0; kk2 < 2; kk2++){
            const int kk = kk2*32 + lhi*8;
            const short8 qbh = *(const short8*)&g_qWhi[(c*2 + kk2)*512 + coff];
            const short8 qbl = *(const short8*)&g_qWlo[(c*2 + kk2)*512 + coff];
            const short8 qah = *(const short8*)&cb[(wave*16 + l15)*72 + kk];
            qacc = __builtin_amdgcn_mfma_f32_16x16x32_bf16(qah, qbh, qacc, 0, 0, 0);
            qacc = __builtin_amdgcn_mfma_f32_16x16x32_bf16(qah, qbl, qacc, 0, 0, 0);
        }
    }
    #pragma unroll
    for (int j = 0; j < 4; j++)
        qpart[wave*256 + (lhi*4 + j)*16 + l15] = qacc[j];
    __syncthreads();

    // value out
    if (tid < 16){
        float s = vb[0];
        #pragma unroll
        for (int w = 0; w < 8; w++) s += svred[w*16 + tid];
        out[B_*100 + r0 + tid] = s;
    }
    // finalize q (256 entries)
    if (tid < 256){
        int row = tid >> 4, e = tid & 15;
        float s = 0.f;
        #pragma unroll
        for (int w = 0; w < 8; w++) s += qpart[w*256 + row*16 + e];
        sq[row*17 + e] = tanhf(s);
    }
    for (int k = tid; k < 1600; k += 512) semb[k] = emb[k];
    __syncthreads();
    // logits
    for (int i = tid; i < 1600; i += 512){
        int row = i / 100, a = i - row*100;
        float s = abias[0];
        #pragma unroll
        for (int e = 0; e < 16; e++) s += sq[row*17 + e] * semb[a*16 + e];
        out[(r0 + row)*100 + a] = s;
    }
}

// ---------------- launch ----------------
extern "C" void kernel_launch(void* const* d_in, const int* in_sizes, int n_in,
                              void* d_out, int out_size, void* d_ws, size_t ws_size,
                              hipStream_t stream) {
    const int*   obs   = (const int*)  d_in[0];
    const float* maxv  = (const float*)d_in[1];
    const float* w1    = (const float*)d_in[2];
    const float* b1    = (const float*)d_in[3];
    const float* w2    = (const float*)d_in[4];
    const float* b2    = (const float*)d_in[5];
    const float* fc1w  = (const float*)d_in[6];
    const float* fc1b  = (const float*)d_in[7];
    const float* encw  = (const float*)d_in[8];
    const float* encb  = (const float*)d_in[9];
    const float* crw   = (const float*)d_in[10];
    const float* crb   = (const float*)d_in[11];
    const float* vw    = (const float*)d_in[12];
    const float* vb    = (const float*)d_in[13];
    const float* acw   = (const float*)d_in[14];
    const float* acb   = (const float*)d_in[15];
    const float* emb   = (const float*)d_in[16];
    const float* aW    = (const float*)d_in[17];
    const float* abias = (const float*)d_in[18];
    float* out = (float*)d_out;

    prep_kernel<<<1336, 256, 0, stream>>>(w1, maxv, w2, fc1w, encw, crw, acw, aW);
    conv1_kernel<<<B_/2, 256, 0, stream>>>(obs, b1);
    conv2_kernel<<<512, 256, 0, stream>>>(b2);
    tail_kernel<<<512, 512, 0, stream>>>(fc1b, encb, crb, vw, vb, acb, emb, abias, out);
}

// Round 22
// 151.649 us; speedup vs baseline: 1.8042x; 1.0141x over previous
//
#include <hip/hip_runtime.h>
#include <math.h>

#define B_ 8192

typedef __attribute__((ext_vector_type(8))) short short8;
typedef __attribute__((ext_vector_type(4))) float f32x4;

// ---------------- persistent device buffers (rewritten every call) ----------------
// ALL GEMM B-matrices stored wave-coalesced: [tile][kkc][r(16)][k^(32)] so one wave
// load = one contiguous 1KB block (lane addr = base + l15*64B + lhi*16B).
__device__ unsigned short g_w1ph[51200], g_w1pl[51200];    // conv1 [kc25][ng4][r][k^], /maxv
__device__ unsigned short g_w2hi[36864],  g_w2lo[36864];   // conv2 [64][576], k'=(kx*3+ky)*64+ic (legacy layout)
__device__ unsigned short g_fc1hi[32768], g_fc1lo[32768];  // fc1   [tn8][kk8][r][k^] (k'=pos*64+oc)
__device__ unsigned short g_enchi[16384], g_enclo[16384];  // enc   [tn8][kk4][r][k^]
__device__ unsigned short g_crhi[131072], g_crlo[131072];  // critic[tn64][kk4][r][k^]
__device__ unsigned short g_achi[65536],  g_aclo[65536];   // actor [tn32][kk4][r][k^]
__device__ unsigned short g_qWhi[8192],   g_qWlo[8192];    // qW^T  [ck16][e16][k^32]
// activations (hi/lo split bf16)
__device__ unsigned short g_ACT1hi[8192*1024], g_ACT1lo[8192*1024]; // conv1 out [s][pos*64+oc]
__device__ unsigned short g_A1hi[8192*256],  g_A1lo[8192*256];  // conv2 out [s][pos*64+oc]

__device__ __forceinline__ unsigned short f2bf(float v){
    unsigned u = __builtin_bit_cast(unsigned, v);
    unsigned r = (u + 0x7fffu + ((u >> 16) & 1u)) >> 16;   // RN-even (finite inputs)
    return (unsigned short)r;
}
__device__ __forceinline__ float bf2f(unsigned short h){
    unsigned u = ((unsigned)h) << 16;
    return __builtin_bit_cast(float, u);
}
__device__ __forceinline__ void split_store(float v, unsigned short* hi, unsigned short* lo){
    unsigned short h = f2bf(v);
    *hi = h;
    *lo = f2bf(v - bf2f(h));
}

// ---------------- prep: transpose + split all weights ----------------
__global__ __launch_bounds__(256) void prep_kernel(
    const float* __restrict__ w1, const float* __restrict__ maxv,
    const float* __restrict__ w2, const float* __restrict__ fc1,
    const float* __restrict__ enc, const float* __restrict__ cr,
    const float* __restrict__ ac, const float* __restrict__ aW)
{
    int d = blockIdx.x * 256 + threadIdx.x;
    if (d < 51200){
        // w1 natural [oc=n][k=(l,dx,dy)] -> coalesced [kc][ng][r][k^], scaled by 1/maxv[l]
        int n = d / 800, k = d - n*800;
        int l = k / 25;
        float v = w1[d] / maxv[l];
        int kc = k >> 5, kh = k & 31, ng = n >> 4, r = n & 15;
        int idx = ((kc*4 + ng)*16 + r)*32 + kh;
        split_store(v, &g_w1ph[idx], &g_w1pl[idx]);
        return;
    }
    d -= 51200;
    if (d < 36864){
        int oc = d / 576, k2 = d - oc*576;
        int kxy = k2 >> 6, ic = k2 & 63;               // k' = kxy*64 + ic
        split_store(w2[oc*576 + ic*9 + kxy], &g_w2hi[d], &g_w2lo[d]);
        return;
    }
    d -= 36864;
    if (d < 32768){
        int n = d >> 8, kp = d & 255;
        float v = fc1[n*256 + (kp & 63)*4 + (kp >> 6)];
        int idx = ((((n >> 4)*8) + (kp >> 5))*16 + (n & 15))*32 + (kp & 31);
        split_store(v, &g_fc1hi[idx], &g_fc1lo[idx]);
        return;
    }
    d -= 32768;
    if (d < 16384){
        int n = d >> 7, k = d & 127;
        int idx = ((((n >> 4)*4) + (k >> 5))*16 + (n & 15))*32 + (k & 31);
        split_store(enc[d], &g_enchi[idx], &g_enclo[idx]);
        return;
    }
    d -= 16384;
    if (d < 131072){
        int n = d >> 7, k = d & 127;
        int idx = ((((n >> 4)*4) + (k >> 5))*16 + (n & 15))*32 + (k & 31);
        split_store(cr[d], &g_crhi[idx], &g_crlo[idx]);
        return;
    }
    d -= 131072;
    if (d < 65536){
        int n = d >> 7, k = d & 127;
        int idx = ((((n >> 4)*4) + (k >> 5))*16 + (n & 15))*32 + (k & 31);
        split_store(ac[d], &g_achi[idx], &g_aclo[idx]);
        return;
    }
    d -= 65536;
    {   // qW^T: e = d>>9, j(k) = d&511; coalesced [ck][e][k^]
        int e = d >> 9, j = d & 511;
        int idx = ((j >> 5)*16 + e)*32 + (j & 31);
        split_store(aW[j*16 + e], &g_qWhi[idx], &g_qWlo[idx]);
    }
}

// ---------------- conv1: pack-max dedup + MFMA GEMM ----------------------------------------
// Coalesced 1KB B loads; 4-deep prefetch HOISTED to kernel entry (hides under dedup phase);
// K-loop processes kc in pairs with 4 independent accumulator chains (even/odd) to double
// MFMA dependency distance. 2 samples/block, 4 waves; 51712B LDS -> 3 blocks/CU.
#define APITCH 808   // 800 + 8 shorts pad
__global__ __launch_bounds__(256) void conv1_kernel(const int* __restrict__ obs,
                                                    const float* __restrict__ b1)
{
    const int b = blockIdx.x;                 // samples b*2, b*2+1
    const int tid = threadIdx.x;
    const int wave = tid >> 6, lane = tid & 63;
    const int l15 = lane & 15, lhi = lane >> 4;

    __shared__ unsigned short sA[32 * APITCH];      // 51712 B; first 32KB doubles as wtab
    int* wtab = (int*)sA;                           // 8192-entry winner table (per pass)

    // ---- early B prefetch (addresses independent of data; flies during dedup) ----
    const unsigned short* Bh = &g_w1ph[wave*512 + l15*32 + lhi*8];
    const unsigned short* Bl = &g_w1pl[wave*512 + l15*32 + lhi*8];
    short8 bh0 = *(const short8*)&Bh[0*2048];
    short8 bh1 = *(const short8*)&Bh[1*2048];
    short8 bh2 = *(const short8*)&Bh[2*2048];
    short8 bh3 = *(const short8*)&Bh[3*2048];
    short8 bl0 = *(const short8*)&Bl[0*2048];
    short8 bl1 = *(const short8*)&Bl[1*2048];
    short8 bl2 = *(const short8*)&Bl[2*2048];
    short8 bl3 = *(const short8*)&Bl[3*2048];

    int   cells[2], xs[2], ys[2], ls[2];
    float vals[2];
    bool  valids[2], kept[2];
    #pragma unroll
    for (int u = 0; u < 2; u++){
        const int slot = tid + u*256;
        valids[u] = false; kept[u] = false; cells[u] = 0;
        if (slot < 400){
            const int si = (slot >= 200) ? 1 : 0;
            const int k  = slot - si*200;
            const int base = (b*2 + si)*600 + k*3;
            int coord = obs[base], atr = obs[base+1], val = obs[base+2];
            bool valid = (coord != 255) && (atr < 32);
            xs[u] = (coord >> 4) & 15;  ys[u] = coord & 15;  ls[u] = atr;
            cells[u] = valid ? (atr*256 + xs[u]*16 + ys[u]) : 0;   // invalid claims cell 0
            vals[u]  = (float)val;
            valids[u] = valid;
        }
    }
    // dedup pass A: sample 0
    if (tid < 200) wtab[cells[0]] = -1;
    __syncthreads();
    if (tid < 200) atomicMax(&wtab[cells[0]], tid);
    __syncthreads();
    if (tid < 200) kept[0] = (wtab[cells[0]] == tid);
    __syncthreads();
    // dedup pass B: sample 1
    if (tid >= 200) wtab[cells[0]] = -1;
    if (tid < 144)  wtab[cells[1]] = -1;
    __syncthreads();
    if (tid >= 200) atomicMax(&wtab[cells[0]], tid - 200);
    if (tid < 144)  atomicMax(&wtab[cells[1]], tid + 56);
    __syncthreads();
    if (tid >= 200) kept[0] = (wtab[cells[0]] == tid - 200);
    if (tid < 144)  kept[1] = (wtab[cells[1]] == tid + 56);
    __syncthreads();

    // zero A-tile (overwrites winner table)
    for (int i = tid; i < 4 * APITCH; i += 256)
        *(short8*)&sA[i * 8] = short8{0,0,0,0,0,0,0,0};
    __syncthreads();

    // scatter
    #pragma unroll
    for (int u = 0; u < 2; u++){
        const int slot = tid + u*256;
        if (slot < 400 && kept[u] && valids[u]){
            const int si = (slot >= 200) ? 1 : 0;
            const int x3 = xs[u]/3, rx = xs[u] - 3*x3;
            const int y3 = ys[u]/3, ry = ys[u] - 3*y3;
            const unsigned short hv = f2bf(vals[u]);     // exact (integer <= 255)
            #pragma unroll
            for (int d = 0; d < 4; d++){
                const int dxd = d >> 1, dyd = d & 1;
                const int ox = x3 - dxd, oy = y3 - dyd;
                const int wx = rx + 3*dxd, wy = ry + 3*dyd;
                if (((unsigned)ox <= 3u) && ((unsigned)oy <= 3u) && (wx < 5) && (wy < 5))
                    sA[(si*16 + ox*4 + oy)*APITCH + ls[u]*25 + wx*5 + wy] = hv;
            }
        }
    }
    __syncthreads();

    // MFMA K-loop: kc pairs, 4 independent acc chains (even/odd), 4-deep rolling prefetch
    const int n = wave*16 + l15;
    const unsigned short* A0 = &sA[l15*APITCH + lhi*8];
    const unsigned short* A1 = &sA[(16 + l15)*APITCH + lhi*8];
    f32x4 acc0e = {0,0,0,0}, acc1e = {0,0,0,0};
    f32x4 acc0o = {0,0,0,0}, acc1o = {0,0,0,0};
    #pragma unroll
    for (int kc2 = 0; kc2 < 12; kc2++){              // kc = 2*kc2, 2*kc2+1  (0..23)
        const int kc = kc2*2;
        short8 a0e = *(const short8*)&A0[kc*32];
        short8 a1e = *(const short8*)&A1[kc*32];
        short8 a0o = *(const short8*)&A0[(kc+1)*32];
        short8 a1o = *(const short8*)&A1[(kc+1)*32];
        short8 bhn0, bln0, bhn1, bln1;
        if (kc2 < 10){
            bhn0 = *(const short8*)&Bh[(kc + 4)*2048];
            bln0 = *(const short8*)&Bl[(kc + 4)*2048];
            bhn1 = *(const short8*)&Bh[(kc + 5)*2048];
            bln1 = *(const short8*)&Bl[(kc + 5)*2048];
        } else if (kc2 == 10){
            bhn0 = *(const short8*)&Bh[24*2048];
            bln0 = *(const short8*)&Bl[24*2048];
        }
        acc0e = __builtin_amdgcn_mfma_f32_16x16x32_bf16(a0e, bh0, acc0e, 0, 0, 0);
        acc1e = __builtin_amdgcn_mfma_f32_16x16x32_bf16(a1e, bh0, acc1e, 0, 0, 0);
        acc0o = __builtin_amdgcn_mfma_f32_16x16x32_bf16(a0o, bh1, acc0o, 0, 0, 0);
        acc1o = __builtin_amdgcn_mfma_f32_16x16x32_bf16(a1o, bh1, acc1o, 0, 0, 0);
        acc0e = __builtin_amdgcn_mfma_f32_16x16x32_bf16(a0e, bl0, acc0e, 0, 0, 0);
        acc1e = __builtin_amdgcn_mfma_f32_16x16x32_bf16(a1e, bl0, acc1e, 0, 0, 0);
        acc0o = __builtin_amdgcn_mfma_f32_16x16x32_bf16(a0o, bl1, acc0o, 0, 0, 0);
        acc1o = __builtin_amdgcn_mfma_f32_16x16x32_bf16(a1o, bl1, acc1o, 0, 0, 0);
        bh0 = bh2; bh1 = bh3; bh2 = bhn0; bh3 = bhn1;
        bl0 = bl2; bl1 = bl3; bl2 = bln0; bl3 = bln1;
    }
    {   // tail kc = 24 (in bh0/bl0 after 12 rotations)
        short8 a0e = *(const short8*)&A0[24*32];
        short8 a1e = *(const short8*)&A1[24*32];
        acc0e = __builtin_amdgcn_mfma_f32_16x16x32_bf16(a0e, bh0, acc0e, 0, 0, 0);
        acc1e = __builtin_amdgcn_mfma_f32_16x16x32_bf16(a1e, bh0, acc1e, 0, 0, 0);
        acc0e = __builtin_amdgcn_mfma_f32_16x16x32_bf16(a0e, bl0, acc0e, 0, 0, 0);
        acc1e = __builtin_amdgcn_mfma_f32_16x16x32_bf16(a1e, bl0, acc1e, 0, 0, 0);
    }
    f32x4 acc0, acc1;
    #pragma unroll
    for (int j = 0; j < 4; j++){ acc0[j] = acc0e[j] + acc0o[j]; acc1[j] = acc1e[j] + acc1o[j]; }

    const float bb = b1[n];
    #pragma unroll
    for (int j = 0; j < 4; j++){
        const int pos = lhi*4 + j;
        float v0 = fmaxf(acc0[j] + bb, 0.f);
        float v1 = fmaxf(acc1[j] + bb, 0.f);
        unsigned short h0 = f2bf(v0), h1 = f2bf(v1);
        const int g0 = (b*2    )*1024 + pos*64 + n;
        const int g1 = (b*2 + 1)*1024 + pos*64 + n;
        g_ACT1hi[g0] = h0;  g_ACT1lo[g0] = f2bf(v0 - bf2f(h0));
        g_ACT1hi[g1] = h1;  g_ACT1lo[g1] = f2bf(v1 - bf2f(h1));
    }
}

// ---------------- conv2: im2col-on-load MFMA GEMM (M=32768, N=64, K=576) ----------------
__global__ __launch_bounds__(256) void conv2_kernel(const float* __restrict__ bias)
{
    const int r0 = blockIdx.x * 64;                      // 16 samples x 4 pos
    const int tid = threadIdx.x, wave = tid >> 6, lane = tid & 63;
    const int l15 = lane & 15, lhi = lane >> 4;

    __shared__ unsigned short sAhi[64][72];
    __shared__ unsigned short sAlo[64][72];

    f32x4 acc[4] = {{0,0,0,0},{0,0,0,0},{0,0,0,0},{0,0,0,0}};
    for (int kc = 0; kc < 9; kc++){                      // (kx,ky) chunk of 64 k's
        const int kx = kc / 3, ky = kc - 3*kx;
        __syncthreads();
        #pragma unroll
        for (int u = 0; u < 2; u++){
            int unit = tid + u*256;
            int row = unit >> 3, ch8 = (unit & 7) * 8;
            int px = (row >> 1) & 1, py = row & 1;       // pos = row&3
            int cell = (px + kx)*4 + (py + ky);
            int g = ((r0 >> 2) + (row >> 2))*1024 + cell*64 + ch8;
            *(short8*)&sAhi[row][ch8] = *(const short8*)&g_ACT1hi[g];
            *(short8*)&sAlo[row][ch8] = *(const short8*)&g_ACT1lo[g];
        }
        __syncthreads();
        #pragma unroll
        for (int ks = 0; ks < 2; ks++){
            const int kk = ks*32 + lhi*8;
            short8 ah = *(const short8*)&sAhi[wave*16 + l15][kk];
            short8 al = *(const short8*)&sAlo[wave*16 + l15][kk];
            #pragma unroll
            for (int nt = 0; nt < 4; nt++){
                const int n = nt*16 + l15;
                const short8 bh = *(const short8*)&g_w2hi[n*576 + kc*64 + kk];
                const short8 bl = *(const short8*)&g_w2lo[n*576 + kc*64 + kk];
                acc[nt] = __builtin_amdgcn_mfma_f32_16x16x32_bf16(ah, bh, acc[nt], 0, 0, 0);
                acc[nt] = __builtin_amdgcn_mfma_f32_16x16x32_bf16(al, bh, acc[nt], 0, 0, 0);
                acc[nt] = __builtin_amdgcn_mfma_f32_16x16x32_bf16(ah, bl, acc[nt], 0, 0, 0);
            }
        }
    }
    #pragma unroll
    for (int nt = 0; nt < 4; nt++){
        const int col = nt*16 + l15;
        const float bb = bias[col];
        #pragma unroll
        for (int j = 0; j < 4; j++){
            const int row = r0 + wave*16 + lhi*4 + j;
            float v = fmaxf(acc[nt][j] + bb, 0.f);
            unsigned short h = f2bf(v);
            g_A1hi[row*64 + col] = h;                    // == [s][pos*64+oc]
            g_A1lo[row*64 + col] = f2bf(v - bf2f(h));
        }
    }
}

// ---------------- tail: fc1+enc+critic+actor+query+logits fused, 8 waves ----------------
// M=16 samples/block, 512 threads (8 waves), grid 512 -> 2 blocks/CU = 4 waves/SIMD.
// ALL B loads wave-coalesced 1KB blocks.
__global__ __launch_bounds__(512, 4) void tail_kernel(
    const float* __restrict__ fc1b, const float* __restrict__ encb,
    const float* __restrict__ crb,  const float* __restrict__ vw,
    const float* __restrict__ vb,   const float* __restrict__ acb,
    const float* __restrict__ emb,  const float* __restrict__ abias,
    float* __restrict__ out)
{
    const int r0 = blockIdx.x * 16;
    const int tid = threadIdx.x, wave = tid >> 6, lane = tid & 63;
    const int l15 = lane & 15, lhi = lane >> 4;
    const int coff = l15*32 + lhi*8;                     // coalesced lane offset

    __shared__ char smem[60736];
    unsigned short* sA1h = (unsigned short*)smem;                 // [16][264] 8448 B
    unsigned short* sA1l = (unsigned short*)(smem + 8448);        // 8448 B
    float*          qpart= (float*)smem;                          // [8][16][16] 8192 B (overlays dead sA1)
    unsigned short* sXh  = (unsigned short*)(smem + 16896);       // [16][136] 4352 B
    unsigned short* sXl  = (unsigned short*)(smem + 21248);
    unsigned short* sHh  = (unsigned short*)(smem + 25600);
    unsigned short* sHl  = (unsigned short*)(smem + 29952);
    unsigned short* cb   = (unsigned short*)(smem + 34304);       // [8][16][72] 18432 B
    float* sq    = (float*)(smem + 52736);                        // [16][17] 1088 B
    float* svred = (float*)(smem + 53824);                        // [8][16]  512 B
    float* semb  = (float*)(smem + 54336);                        // [1600]   6400 B

    // ---- stage A1 [16][256] hi/lo (one 16B unit per thread) ----
    {
        int row = tid >> 5, ch8 = (tid & 31) * 8;
        *(short8*)&sA1h[row*264 + ch8] = *(const short8*)&g_A1hi[(r0+row)*256 + ch8];
        *(short8*)&sA1l[row*264 + ch8] = *(const short8*)&g_A1lo[(r0+row)*256 + ch8];
    }
    __syncthreads();

    // ---- fc1: M=16, N=128 (wave owns n-tile = wave), K=256 -> sX ----
    {
        f32x4 acc = {0,0,0,0};
        const int n = wave*16 + l15;
        #pragma unroll
        for (int kk8 = 0; kk8 < 8; kk8++){
            const int kk = kk8*32 + lhi*8;
            short8 ah = *(const short8*)&sA1h[l15*264 + kk];
            short8 al = *(const short8*)&sA1l[l15*264 + kk];
            const short8 bh = *(const short8*)&g_fc1hi[(wave*8 + kk8)*512 + coff];
            const short8 bl = *(const short8*)&g_fc1lo[(wave*8 + kk8)*512 + coff];
            acc = __builtin_amdgcn_mfma_f32_16x16x32_bf16(ah, bh, acc, 0, 0, 0);
            acc = __builtin_amdgcn_mfma_f32_16x16x32_bf16(al, bh, acc, 0, 0, 0);
            acc = __builtin_amdgcn_mfma_f32_16x16x32_bf16(ah, bl, acc, 0, 0, 0);
        }
        __syncthreads();                      // sA1 reads done before qpart overlays later
        const float bb = fc1b[n];
        #pragma unroll
        for (int j = 0; j < 4; j++){
            const int row = lhi*4 + j;
            float v = fmaxf(acc[j] + bb, 0.f);
            unsigned short h = f2bf(v);
            sXh[row*136 + n] = h;
            sXl[row*136 + n] = f2bf(v - bf2f(h));
        }
    }
    __syncthreads();

    // ---- enc: M=16, N=128 (wave owns n-tile = wave), K=128 -> sH ----
    {
        f32x4 acc = {0,0,0,0};
        const int n = wave*16 + l15;
        #pragma unroll
        for (int kk4 = 0; kk4 < 4; kk4++){
            const int kk = kk4*32 + lhi*8;
            short8 ah = *(const short8*)&sXh[l15*136 + kk];
            short8 al = *(const short8*)&sXl[l15*136 + kk];
            const short8 bh = *(const short8*)&g_enchi[(wave*4 + kk4)*512 + coff];
            const short8 bl = *(const short8*)&g_enclo[(wave*4 + kk4)*512 + coff];
            acc = __builtin_amdgcn_mfma_f32_16x16x32_bf16(ah, bh, acc, 0, 0, 0);
            acc = __builtin_amdgcn_mfma_f32_16x16x32_bf16(al, bh, acc, 0, 0, 0);
            acc = __builtin_amdgcn_mfma_f32_16x16x32_bf16(ah, bl, acc, 0, 0, 0);
        }
        const float bb = encb[n];
        #pragma unroll
        for (int j = 0; j < 4; j++){
            const int row = lhi*4 + j;
            float v = fmaxf(acc[j] + bb, 0.f);
            unsigned short h = f2bf(v);
            sHh[row*136 + n] = h;
            sHl[row*136 + n] = f2bf(v - bf2f(h));
        }
    }
    __syncthreads();

    // ---- hoist H A-fragments (shared by critic and actor; K=128) ----
    short8 Ah[4], Al[4];
    #pragma unroll
    for (int kk4 = 0; kk4 < 4; kk4++){
        const int kk = kk4*32 + lhi*8;
        Ah[kk4] = *(const short8*)&sHh[l15*136 + kk];
        Al[kk4] = *(const short8*)&sHl[l15*136 + kk];
    }

    // ---- critic: wave owns 128 cols (8 n-tiles); chunks of 4; tanh + vw dot ----
    {
        float vp[4] = {0,0,0,0};
        #pragma unroll
        for (int ntc = 0; ntc < 2; ntc++){
            f32x4 cacc[4];
            #pragma unroll
            for (int q = 0; q < 4; q++) cacc[q] = f32x4{0,0,0,0};
            #pragma unroll
            for (int q = 0; q < 4; q++){
                const int t = wave*8 + ntc*4 + q;        // critic n-tile index
                #pragma unroll
                for (int kk4 = 0; kk4 < 4; kk4++){
                    const short8 bh = *(const short8*)&g_crhi[(t*4 + kk4)*512 + coff];
                    const short8 bl = *(const short8*)&g_crlo[(t*4 + kk4)*512 + coff];
                    cacc[q] = __builtin_amdgcn_mfma_f32_16x16x32_bf16(Ah[kk4], bh, cacc[q], 0, 0, 0);
                    cacc[q] = __builtin_amdgcn_mfma_f32_16x16x32_bf16(Al[kk4], bh, cacc[q], 0, 0, 0);
                    cacc[q] = __builtin_amdgcn_mfma_f32_16x16x32_bf16(Ah[kk4], bl, cacc[q], 0, 0, 0);
                }
            }
            #pragma unroll
            for (int q = 0; q < 4; q++){
                const int n = wave*128 + (ntc*4 + q)*16 + l15;
                const float w = vw[n], bb = crb[n];
                #pragma unroll
                for (int j = 0; j < 4; j++)
                    vp[j] += tanhf(cacc[q][j] + bb) * w;
            }
        }
        #pragma unroll
        for (int m = 1; m < 16; m <<= 1)
            #pragma unroll
            for (int j = 0; j < 4; j++) vp[j] += __shfl_xor(vp[j], m, 64);
        if (l15 == 0){
            #pragma unroll
            for (int j = 0; j < 4; j++)
                svred[wave*16 + lhi*4 + j] = vp[j];
        }
    }

    // ---- actor chunk (c = wave, 64 cols, hi-only LDS) + query mini-GEMM ----
    f32x4 qacc = {0,0,0,0};
    {
        const int c = wave;
        f32x4 aacc[4];
        #pragma unroll
        for (int nt = 0; nt < 4; nt++) aacc[nt] = f32x4{0,0,0,0};
        #pragma unroll
        for (int kk4 = 0; kk4 < 4; kk4++){
            #pragma unroll
            for (int nt = 0; nt < 4; nt++){
                const int t = c*4 + nt;                  // actor n-tile index
                const short8 bh = *(const short8*)&g_achi[(t*4 + kk4)*512 + coff];
                const short8 bl = *(const short8*)&g_aclo[(t*4 + kk4)*512 + coff];
                aacc[nt] = __builtin_amdgcn_mfma_f32_16x16x32_bf16(Ah[kk4], bh, aacc[nt], 0, 0, 0);
                aacc[nt] = __builtin_amdgcn_mfma_f32_16x16x32_bf16(Al[kk4], bh, aacc[nt], 0, 0, 0);
                aacc[nt] = __builtin_amdgcn_mfma_f32_16x16x32_bf16(Ah[kk4], bl, aacc[nt], 0, 0, 0);
            }
        }
        // relu + bias -> per-wave LDS chunk [16 rows][64 cols], hi only
        #pragma unroll
        for (int nt = 0; nt < 4; nt++){
            const int col = nt*16 + l15;
            const float bb = acb[c*64 + col];
            #pragma unroll
            for (int j = 0; j < 4; j++){
                const int row = lhi*4 + j;
                cb[(wave*16 + row)*72 + col] = f2bf(fmaxf(aacc[nt][j] + bb, 0.f));
            }
        }
        // query partial over this chunk (K=64), B = qW^T (coalesced [ck][e][k^])
        #pragma unroll
        for (int kk2 = 0; kk2 < 2; kk2++){
            const int kk = kk2*32 + lhi*8;
            const short8 qbh = *(const short8*)&g_qWhi[(c*2 + kk2)*512 + coff];
            const short8 qbl = *(const short8*)&g_qWlo[(c*2 + kk2)*512 + coff];
            const short8 qah = *(const short8*)&cb[(wave*16 + l15)*72 + kk];
            qacc = __builtin_amdgcn_mfma_f32_16x16x32_bf16(qah, qbh, qacc, 0, 0, 0);
            qacc = __builtin_amdgcn_mfma_f32_16x16x32_bf16(qah, qbl, qacc, 0, 0, 0);
        }
    }
    #pragma unroll
    for (int j = 0; j < 4; j++)
        qpart[wave*256 + (lhi*4 + j)*16 + l15] = qacc[j];
    __syncthreads();

    // value out
    if (tid < 16){
        float s = vb[0];
        #pragma unroll
        for (int w = 0; w < 8; w++) s += svred[w*16 + tid];
        out[B_*100 + r0 + tid] = s;
    }
    // finalize q (256 entries)
    if (tid < 256){
        int row = tid >> 4, e = tid & 15;
        float s = 0.f;
        #pragma unroll
        for (int w = 0; w < 8; w++) s += qpart[w*256 + row*16 + e];
        sq[row*17 + e] = tanhf(s);
    }
    for (int k = tid; k < 1600; k += 512) semb[k] = emb[k];
    __syncthreads();
    // logits
    for (int i = tid; i < 1600; i += 512){
        int row = i / 100, a = i - row*100;
        float s = abias[0];
        #pragma unroll
        for (int e = 0; e < 16; e++) s += sq[row*17 + e] * semb[a*16 + e];
        out[(r0 + row)*100 + a] = s;
    }
}

// ---------------- launch ----------------
extern "C" void kernel_launch(void* const* d_in, const int* in_sizes, int n_in,
                              void* d_out, int out_size, void* d_ws, size_t ws_size,
                              hipStream_t stream) {
    const int*   obs   = (const int*)  d_in[0];
    const float* maxv  = (const float*)d_in[1];
    const float* w1    = (const float*)d_in[2];
    const float* b1    = (const float*)d_in[3];
    const float* w2    = (const float*)d_in[4];
    const float* b2    = (const float*)d_in[5];
    const float* fc1w  = (const float*)d_in[6];
    const float* fc1b  = (const float*)d_in[7];
    const float* encw  = (const float*)d_in[8];
    const float* encb  = (const float*)d_in[9];
    const float* crw   = (const float*)d_in[10];
    const float* crb   = (const float*)d_in[11];
    const float* vw    = (const float*)d_in[12];
    const float* vb    = (const float*)d_in[13];
    const float* acw   = (const float*)d_in[14];
    const float* acb   = (const float*)d_in[15];
    const float* emb   = (const float*)d_in[16];
    const float* aW    = (const float*)d_in[17];
    const float* abias = (const float*)d_in[18];
    float* out = (float*)d_out;

    prep_kernel<<<1336, 256, 0, stream>>>(w1, maxv, w2, fc1w, encw, crw, acw, aW);
    conv1_kernel<<<B_/2, 256, 0, stream>>>(obs, b1);
    conv2_kernel<<<512, 256, 0, stream>>>(b2);
    tail_kernel<<<512, 512, 0, stream>>>(fc1b, encb, crb, vw, vb, acb, emb, abias, out);
}

// Round 23
// 105.312 us; speedup vs baseline: 2.5981x; 1.4400x over previous
//
#include <hip/hip_runtime.h>
#include <math.h>

#define B_ 8192

typedef __attribute__((ext_vector_type(8))) short short8;
typedef __attribute__((ext_vector_type(4))) float f32x4;

// ---------------- persistent device buffers (rewritten every call) ----------------
// ALL GEMM B-matrices stored wave-coalesced: [tile][kkc][r(16)][k^(32)] so one wave
// load = one contiguous 1KB block (lane addr = base + l15*64B + lhi*16B).
__device__ unsigned short g_w1p[51200];                    // conv1 [kc25][ng4][r][k^], /maxv, HI-ONLY
                                                           // (A is exact -> B hi-only = 2^-9 rel err)
__device__ unsigned short g_w2hi[36864],  g_w2lo[36864];   // conv2 [kc9*ks2*nt4][r][k^] coalesced
__device__ unsigned short g_fc1hi[32768], g_fc1lo[32768];  // fc1   [tn8][kk8][r][k^] (k'=pos*64+oc)
__device__ unsigned short g_enchi[16384], g_enclo[16384];  // enc   [tn8][kk4][r][k^]
__device__ unsigned short g_crhi[131072], g_crlo[131072];  // critic[tn64][kk4][r][k^]
__device__ unsigned short g_achi[65536],  g_aclo[65536];   // actor [tn32][kk4][r][k^]
__device__ unsigned short g_qWhi[8192],   g_qWlo[8192];    // qW^T  [ck16][e16][k^32]
// activations (hi/lo split bf16)
__device__ unsigned short g_ACT1hi[8192*1024], g_ACT1lo[8192*1024]; // conv1 out [s][pos*64+oc]
__device__ unsigned short g_A1hi[8192*256],  g_A1lo[8192*256];  // conv2 out [s][pos*64+oc]

__device__ __forceinline__ unsigned short f2bf(float v){
    unsigned u = __builtin_bit_cast(unsigned, v);
    unsigned r = (u + 0x7fffu + ((u >> 16) & 1u)) >> 16;   // RN-even (finite inputs)
    return (unsigned short)r;
}
__device__ __forceinline__ float bf2f(unsigned short h){
    unsigned u = ((unsigned)h) << 16;
    return __builtin_bit_cast(float, u);
}
__device__ __forceinline__ void split_store(float v, unsigned short* hi, unsigned short* lo){
    unsigned short h = f2bf(v);
    *hi = h;
    *lo = f2bf(v - bf2f(h));
}

// ---------------- prep: transpose + split all weights ----------------
__global__ __launch_bounds__(256) void prep_kernel(
    const float* __restrict__ w1, const float* __restrict__ maxv,
    const float* __restrict__ w2, const float* __restrict__ fc1,
    const float* __restrict__ enc, const float* __restrict__ cr,
    const float* __restrict__ ac, const float* __restrict__ aW)
{
    int d = blockIdx.x * 256 + threadIdx.x;
    if (d < 51200){
        // w1 natural [oc=n][k=(l,dx,dy)] -> coalesced [kc][ng][r][k^], /maxv, hi-only RN
        int n = d / 800, k = d - n*800;
        int l = k / 25;
        float v = w1[d] / maxv[l];
        int kc = k >> 5, kh = k & 31, ng = n >> 4, r = n & 15;
        int idx = ((kc*4 + ng)*16 + r)*32 + kh;
        g_w1p[idx] = f2bf(v);
        return;
    }
    d -= 51200;
    if (d < 36864){
        // conv2: oc = d/576, k2 = kc*64+ks*32+kq (k' = kxy*64+ic = k2); coalesced
        int oc = d / 576, k2 = d - oc*576;
        int kxy = k2 >> 6, ic = k2 & 63;
        float v = w2[oc*576 + ic*9 + kxy];
        int kc = k2 >> 6, ks = (k2 >> 5) & 1, kq = k2 & 31, nt = oc >> 4, r = oc & 15;
        int idx = (((kc*2 + ks)*4 + nt)*16 + r)*32 + kq;
        split_store(v, &g_w2hi[idx], &g_w2lo[idx]);
        return;
    }
    d -= 36864;
    if (d < 32768){
        int n = d >> 8, kp = d & 255;
        float v = fc1[n*256 + (kp & 63)*4 + (kp >> 6)];
        int idx = ((((n >> 4)*8) + (kp >> 5))*16 + (n & 15))*32 + (kp & 31);
        split_store(v, &g_fc1hi[idx], &g_fc1lo[idx]);
        return;
    }
    d -= 32768;
    if (d < 16384){
        int n = d >> 7, k = d & 127;
        int idx = ((((n >> 4)*4) + (k >> 5))*16 + (n & 15))*32 + (k & 31);
        split_store(enc[d], &g_enchi[idx], &g_enclo[idx]);
        return;
    }
    d -= 16384;
    if (d < 131072){
        int n = d >> 7, k = d & 127;
        int idx = ((((n >> 4)*4) + (k >> 5))*16 + (n & 15))*32 + (k & 31);
        split_store(cr[d], &g_crhi[idx], &g_crlo[idx]);
        return;
    }
    d -= 131072;
    if (d < 65536){
        int n = d >> 7, k = d & 127;
        int idx = ((((n >> 4)*4) + (k >> 5))*16 + (n & 15))*32 + (k & 31);
        split_store(ac[d], &g_achi[idx], &g_aclo[idx]);
        return;
    }
    d -= 65536;
    {   // qW^T: e = d>>9, j(k) = d&511; coalesced [ck][e][k^]
        int e = d >> 9, j = d & 511;
        int idx = ((j >> 5)*16 + e)*32 + (j & 31);
        split_store(aW[j*16 + e], &g_qWhi[idx], &g_qWlo[idx]);
    }
}

// ---------------- conv1: pack-max dedup + MFMA GEMM (hi-only B) ----------------------------
// Coalesced 1KB B loads; 4-deep prefetch hoisted to kernel entry; kc pairs with even/odd
// independent acc chains. B hi-only: 25 loads + 50 MFMAs per wave (was 50/100).
#define APITCH 808   // 800 + 8 shorts pad
__global__ __launch_bounds__(256) void conv1_kernel(const int* __restrict__ obs,
                                                    const float* __restrict__ b1)
{
    const int b = blockIdx.x;                 // samples b*2, b*2+1
    const int tid = threadIdx.x;
    const int wave = tid >> 6, lane = tid & 63;
    const int l15 = lane & 15, lhi = lane >> 4;

    __shared__ unsigned short sA[32 * APITCH];      // 51712 B; first 32KB doubles as wtab
    int* wtab = (int*)sA;                           // 8192-entry winner table (per pass)

    // ---- early B prefetch (addresses independent of data; flies during dedup) ----
    const unsigned short* Bh = &g_w1p[wave*512 + l15*32 + lhi*8];
    short8 bh0 = *(const short8*)&Bh[0*2048];
    short8 bh1 = *(const short8*)&Bh[1*2048];
    short8 bh2 = *(const short8*)&Bh[2*2048];
    short8 bh3 = *(const short8*)&Bh[3*2048];

    int   cells[2], xs[2], ys[2], ls[2];
    float vals[2];
    bool  valids[2], kept[2];
    #pragma unroll
    for (int u = 0; u < 2; u++){
        const int slot = tid + u*256;
        valids[u] = false; kept[u] = false; cells[u] = 0;
        if (slot < 400){
            const int si = (slot >= 200) ? 1 : 0;
            const int k  = slot - si*200;
            const int base = (b*2 + si)*600 + k*3;
            int coord = obs[base], atr = obs[base+1], val = obs[base+2];
            bool valid = (coord != 255) && (atr < 32);
            xs[u] = (coord >> 4) & 15;  ys[u] = coord & 15;  ls[u] = atr;
            cells[u] = valid ? (atr*256 + xs[u]*16 + ys[u]) : 0;   // invalid claims cell 0
            vals[u]  = (float)val;
            valids[u] = valid;
        }
    }
    // dedup pass A: sample 0
    if (tid < 200) wtab[cells[0]] = -1;
    __syncthreads();
    if (tid < 200) atomicMax(&wtab[cells[0]], tid);
    __syncthreads();
    if (tid < 200) kept[0] = (wtab[cells[0]] == tid);
    __syncthreads();
    // dedup pass B: sample 1
    if (tid >= 200) wtab[cells[0]] = -1;
    if (tid < 144)  wtab[cells[1]] = -1;
    __syncthreads();
    if (tid >= 200) atomicMax(&wtab[cells[0]], tid - 200);
    if (tid < 144)  atomicMax(&wtab[cells[1]], tid + 56);
    __syncthreads();
    if (tid >= 200) kept[0] = (wtab[cells[0]] == tid - 200);
    if (tid < 144)  kept[1] = (wtab[cells[1]] == tid + 56);
    __syncthreads();

    // zero A-tile (overwrites winner table)
    for (int i = tid; i < 4 * APITCH; i += 256)
        *(short8*)&sA[i * 8] = short8{0,0,0,0,0,0,0,0};
    __syncthreads();

    // scatter
    #pragma unroll
    for (int u = 0; u < 2; u++){
        const int slot = tid + u*256;
        if (slot < 400 && kept[u] && valids[u]){
            const int si = (slot >= 200) ? 1 : 0;
            const int x3 = xs[u]/3, rx = xs[u] - 3*x3;
            const int y3 = ys[u]/3, ry = ys[u] - 3*y3;
            const unsigned short hv = f2bf(vals[u]);     // exact (integer <= 255)
            #pragma unroll
            for (int d = 0; d < 4; d++){
                const int dxd = d >> 1, dyd = d & 1;
                const int ox = x3 - dxd, oy = y3 - dyd;
                const int wx = rx + 3*dxd, wy = ry + 3*dyd;
                if (((unsigned)ox <= 3u) && ((unsigned)oy <= 3u) && (wx < 5) && (wy < 5))
                    sA[(si*16 + ox*4 + oy)*APITCH + ls[u]*25 + wx*5 + wy] = hv;
            }
        }
    }
    __syncthreads();

    // MFMA K-loop: kc pairs, even/odd acc chains, 4-deep rolling prefetch, hi-only B
    const int n = wave*16 + l15;
    const unsigned short* A0 = &sA[l15*APITCH + lhi*8];
    const unsigned short* A1 = &sA[(16 + l15)*APITCH + lhi*8];
    f32x4 acc0e = {0,0,0,0}, acc1e = {0,0,0,0};
    f32x4 acc0o = {0,0,0,0}, acc1o = {0,0,0,0};
    #pragma unroll
    for (int kc2 = 0; kc2 < 12; kc2++){              // kc = 2*kc2, 2*kc2+1  (0..23)
        const int kc = kc2*2;
        short8 a0e = *(const short8*)&A0[kc*32];
        short8 a1e = *(const short8*)&A1[kc*32];
        short8 a0o = *(const short8*)&A0[(kc+1)*32];
        short8 a1o = *(const short8*)&A1[(kc+1)*32];
        short8 bhn0, bhn1;
        if (kc2 < 10){
            bhn0 = *(const short8*)&Bh[(kc + 4)*2048];
            bhn1 = *(const short8*)&Bh[(kc + 5)*2048];
        } else if (kc2 == 10){
            bhn0 = *(const short8*)&Bh[24*2048];
        }
        acc0e = __builtin_amdgcn_mfma_f32_16x16x32_bf16(a0e, bh0, acc0e, 0, 0, 0);
        acc1e = __builtin_amdgcn_mfma_f32_16x16x32_bf16(a1e, bh0, acc1e, 0, 0, 0);
        acc0o = __builtin_amdgcn_mfma_f32_16x16x32_bf16(a0o, bh1, acc0o, 0, 0, 0);
        acc1o = __builtin_amdgcn_mfma_f32_16x16x32_bf16(a1o, bh1, acc1o, 0, 0, 0);
        bh0 = bh2; bh1 = bh3; bh2 = bhn0; bh3 = bhn1;
    }
    {   // tail kc = 24 (in bh0 after 12 rotations)
        short8 a0e = *(const short8*)&A0[24*32];
        short8 a1e = *(const short8*)&A1[24*32];
        acc0e = __builtin_amdgcn_mfma_f32_16x16x32_bf16(a0e, bh0, acc0e, 0, 0, 0);
        acc1e = __builtin_amdgcn_mfma_f32_16x16x32_bf16(a1e, bh0, acc1e, 0, 0, 0);
    }
    f32x4 acc0, acc1;
    #pragma unroll
    for (int j = 0; j < 4; j++){ acc0[j] = acc0e[j] + acc0o[j]; acc1[j] = acc1e[j] + acc1o[j]; }

    const float bb = b1[n];
    #pragma unroll
    for (int j = 0; j < 4; j++){
        const int pos = lhi*4 + j;
        float v0 = fmaxf(acc0[j] + bb, 0.f);
        float v1 = fmaxf(acc1[j] + bb, 0.f);
        unsigned short h0 = f2bf(v0), h1 = f2bf(v1);
        const int g0 = (b*2    )*1024 + pos*64 + n;
        const int g1 = (b*2 + 1)*1024 + pos*64 + n;
        g_ACT1hi[g0] = h0;  g_ACT1lo[g0] = f2bf(v0 - bf2f(h0));
        g_ACT1hi[g1] = h1;  g_ACT1lo[g1] = f2bf(v1 - bf2f(h1));
    }
}

// ---------------- conv2: im2col-on-load MFMA GEMM (M=32768, N=64, K=576), coalesced B -----
__global__ __launch_bounds__(256) void conv2_kernel(const float* __restrict__ bias)
{
    const int r0 = blockIdx.x * 64;                      // 16 samples x 4 pos
    const int tid = threadIdx.x, wave = tid >> 6, lane = tid & 63;
    const int l15 = lane & 15, lhi = lane >> 4;
    const int coff = l15*32 + lhi*8;

    __shared__ unsigned short sAhi[64][72];
    __shared__ unsigned short sAlo[64][72];

    f32x4 acc[4] = {{0,0,0,0},{0,0,0,0},{0,0,0,0},{0,0,0,0}};
    for (int kc = 0; kc < 9; kc++){                      // (kx,ky) chunk of 64 k's
        const int kx = kc / 3, ky = kc - 3*kx;
        __syncthreads();
        #pragma unroll
        for (int u = 0; u < 2; u++){
            int unit = tid + u*256;
            int row = unit >> 3, ch8 = (unit & 7) * 8;
            int px = (row >> 1) & 1, py = row & 1;       // pos = row&3
            int cell = (px + kx)*4 + (py + ky);
            int g = ((r0 >> 2) + (row >> 2))*1024 + cell*64 + ch8;
            *(short8*)&sAhi[row][ch8] = *(const short8*)&g_ACT1hi[g];
            *(short8*)&sAlo[row][ch8] = *(const short8*)&g_ACT1lo[g];
        }
        __syncthreads();
        #pragma unroll
        for (int ks = 0; ks < 2; ks++){
            const int kk = ks*32 + lhi*8;
            short8 ah = *(const short8*)&sAhi[wave*16 + l15][kk];
            short8 al = *(const short8*)&sAlo[wave*16 + l15][kk];
            #pragma unroll
            for (int nt = 0; nt < 4; nt++){
                const int t = (kc*2 + ks)*4 + nt;        // coalesced B tile index
                const short8 bh = *(const short8*)&g_w2hi[t*512 + coff];
                const short8 bl = *(const short8*)&g_w2lo[t*512 + coff];
                acc[nt] = __builtin_amdgcn_mfma_f32_16x16x32_bf16(ah, bh, acc[nt], 0, 0, 0);
                acc[nt] = __builtin_amdgcn_mfma_f32_16x16x32_bf16(al, bh, acc[nt], 0, 0, 0);
                acc[nt] = __builtin_amdgcn_mfma_f32_16x16x32_bf16(ah, bl, acc[nt], 0, 0, 0);
            }
        }
    }
    #pragma unroll
    for (int nt = 0; nt < 4; nt++){
        const int col = nt*16 + l15;
        const float bb = bias[col];
        #pragma unroll
        for (int j = 0; j < 4; j++){
            const int row = r0 + wave*16 + lhi*4 + j;
            float v = fmaxf(acc[nt][j] + bb, 0.f);
            unsigned short h = f2bf(v);
            g_A1hi[row*64 + col] = h;                    // == [s][pos*64+oc]
            g_A1lo[row*64 + col] = f2bf(v - bf2f(h));
        }
    }
}

// ---------------- tail: fc1+enc+critic+actor+query+logits fused, 8 waves ----------------
// M=16 samples/block, 512 threads (8 waves), grid 512 -> 2 blocks/CU = 4 waves/SIMD.
__global__ __launch_bounds__(512, 4) void tail_kernel(
    const float* __restrict__ fc1b, const float* __restrict__ encb,
    const float* __restrict__ crb,  const float* __restrict__ vw,
    const float* __restrict__ vb,   const float* __restrict__ acb,
    const float* __restrict__ emb,  const float* __restrict__ abias,
    float* __restrict__ out)
{
    const int r0 = blockIdx.x * 16;
    const int tid = threadIdx.x, wave = tid >> 6, lane = tid & 63;
    const int l15 = lane & 15, lhi = lane >> 4;
    const int coff = l15*32 + lhi*8;                     // coalesced lane offset

    __shared__ char smem[60736];
    unsigned short* sA1h = (unsigned short*)smem;                 // [16][264] 8448 B
    unsigned short* sA1l = (unsigned short*)(smem + 8448);        // 8448 B
    float*          qpart= (float*)smem;                          // [8][16][16] 8192 B (overlays dead sA1)
    unsigned short* sXh  = (unsigned short*)(smem + 16896);       // [16][136] 4352 B
    unsigned short* sXl  = (unsigned short*)(smem + 21248);
    unsigned short* sHh  = (unsigned short*)(smem + 25600);
    unsigned short* sHl  = (unsigned short*)(smem + 29952);
    unsigned short* cb   = (unsigned short*)(smem + 34304);       // [8][16][72] 18432 B
    float* sq    = (float*)(smem + 52736);                        // [16][17] 1088 B
    float* svred = (float*)(smem + 53824);                        // [8][16]  512 B
    float* semb  = (float*)(smem + 54336);                        // [1600]   6400 B

    // ---- stage A1 [16][256] hi/lo (one 16B unit per thread) ----
    {
        int row = tid >> 5, ch8 = (tid & 31) * 8;
        *(short8*)&sA1h[row*264 + ch8] = *(const short8*)&g_A1hi[(r0+row)*256 + ch8];
        *(short8*)&sA1l[row*264 + ch8] = *(const short8*)&g_A1lo[(r0+row)*256 + ch8];
    }
    __syncthreads();

    // ---- fc1: M=16, N=128 (wave owns n-tile = wave), K=256 -> sX ----
    {
        f32x4 acc = {0,0,0,0};
        const int n = wave*16 + l15;
        #pragma unroll
        for (int kk8 = 0; kk8 < 8; kk8++){
            const int kk = kk8*32 + lhi*8;
            short8 ah = *(const short8*)&sA1h[l15*264 + kk];
            short8 al = *(const short8*)&sA1l[l15*264 + kk];
            const short8 bh = *(const short8*)&g_fc1hi[(wave*8 + kk8)*512 + coff];
            const short8 bl = *(const short8*)&g_fc1lo[(wave*8 + kk8)*512 + coff];
            acc = __builtin_amdgcn_mfma_f32_16x16x32_bf16(ah, bh, acc, 0, 0, 0);
            acc = __builtin_amdgcn_mfma_f32_16x16x32_bf16(al, bh, acc, 0, 0, 0);
            acc = __builtin_amdgcn_mfma_f32_16x16x32_bf16(ah, bl, acc, 0, 0, 0);
        }
        __syncthreads();                      // sA1 reads done before qpart overlays later
        const float bb = fc1b[n];
        #pragma unroll
        for (int j = 0; j < 4; j++){
            const int row = lhi*4 + j;
            float v = fmaxf(acc[j] + bb, 0.f);
            unsigned short h = f2bf(v);
            sXh[row*136 + n] = h;
            sXl[row*136 + n] = f2bf(v - bf2f(h));
        }
    }
    __syncthreads();

    // ---- enc: M=16, N=128 (wave owns n-tile = wave), K=128 -> sH ----
    {
        f32x4 acc = {0,0,0,0};
        const int n = wave*16 + l15;
        #pragma unroll
        for (int kk4 = 0; kk4 < 4; kk4++){
            const int kk = kk4*32 + lhi*8;
            short8 ah = *(const short8*)&sXh[l15*136 + kk];
            short8 al = *(const short8*)&sXl[l15*136 + kk];
            const short8 bh = *(const short8*)&g_enchi[(wave*4 + kk4)*512 + coff];
            const short8 bl = *(const short8*)&g_enclo[(wave*4 + kk4)*512 + coff];
            acc = __builtin_amdgcn_mfma_f32_16x16x32_bf16(ah, bh, acc, 0, 0, 0);
            acc = __builtin_amdgcn_mfma_f32_16x16x32_bf16(al, bh, acc, 0, 0, 0);
            acc = __builtin_amdgcn_mfma_f32_16x16x32_bf16(ah, bl, acc, 0, 0, 0);
        }
        const float bb = encb[n];
        #pragma unroll
        for (int j = 0; j < 4; j++){
            const int row = lhi*4 + j;
            float v = fmaxf(acc[j] + bb, 0.f);
            unsigned short h = f2bf(v);
            sHh[row*136 + n] = h;
            sHl[row*136 + n] = f2bf(v - bf2f(h));
        }
    }
    __syncthreads();

    // ---- hoist H A-fragments (shared by critic and actor; K=128) ----
    short8 Ah[4], Al[4];
    #pragma unroll
    for (int kk4 = 0; kk4 < 4; kk4++){
        const int kk = kk4*32 + lhi*8;
        Ah[kk4] = *(const short8*)&sHh[l15*136 + kk];
        Al[kk4] = *(const short8*)&sHl[l15*136 + kk];
    }

    // ---- critic: wave owns 128 cols (8 n-tiles); chunks of 4; tanh + vw dot ----
    {
        float vp[4] = {0,0,0,0};
        #pragma unroll
        for (int ntc = 0; ntc < 2; ntc++){
            f32x4 cacc[4];
            #pragma unroll
            for (int q = 0; q < 4; q++) cacc[q] = f32x4{0,0,0,0};
            #pragma unroll
            for (int q = 0; q < 4; q++){
                const int t = wave*8 + ntc*4 + q;        // critic n-tile index
                #pragma unroll
                for (int kk4 = 0; kk4 < 4; kk4++){
                    const short8 bh = *(const short8*)&g_crhi[(t*4 + kk4)*512 + coff];
                    const short8 bl = *(const short8*)&g_crlo[(t*4 + kk4)*512 + coff];
                    cacc[q] = __builtin_amdgcn_mfma_f32_16x16x32_bf16(Ah[kk4], bh, cacc[q], 0, 0, 0);
                    cacc[q] = __builtin_amdgcn_mfma_f32_16x16x32_bf16(Al[kk4], bh, cacc[q], 0, 0, 0);
                    cacc[q] = __builtin_amdgcn_mfma_f32_16x16x32_bf16(Ah[kk4], bl, cacc[q], 0, 0, 0);
                }
            }
            #pragma unroll
            for (int q = 0; q < 4; q++){
                const int n = wave*128 + (ntc*4 + q)*16 + l15;
                const float w = vw[n], bb = crb[n];
                #pragma unroll
                for (int j = 0; j < 4; j++)
                    vp[j] += tanhf(cacc[q][j] + bb) * w;
            }
        }
        #pragma unroll
        for (int m = 1; m < 16; m <<= 1)
            #pragma unroll
            for (int j = 0; j < 4; j++) vp[j] += __shfl_xor(vp[j], m, 64);
        if (l15 == 0){
            #pragma unroll
            for (int j = 0; j < 4; j++)
                svred[wave*16 + lhi*4 + j] = vp[j];
        }
    }

    // ---- actor chunk (c = wave, 64 cols, hi-only LDS) + query mini-GEMM ----
    f32x4 qacc = {0,0,0,0};
    {
        const int c = wave;
        f32x4 aacc[4];
        #pragma unroll
        for (int nt = 0; nt < 4; nt++) aacc[nt] = f32x4{0,0,0,0};
        #pragma unroll
        for (int kk4 = 0; kk4 < 4; kk4++){
            #pragma unroll
            for (int nt = 0; nt < 4; nt++){
                const int t = c*4 + nt;                  // actor n-tile index
                const short8 bh = *(const short8*)&g_achi[(t*4 + kk4)*512 + coff];
                const short8 bl = *(const short8*)&g_aclo[(t*4 + kk4)*512 + coff];
                aacc[nt] = __builtin_amdgcn_mfma_f32_16x16x32_bf16(Ah[kk4], bh, aacc[nt], 0, 0, 0);
                aacc[nt] = __builtin_amdgcn_mfma_f32_16x16x32_bf16(Al[kk4], bh, aacc[nt], 0, 0, 0);
                aacc[nt] = __builtin_amdgcn_mfma_f32_16x16x32_bf16(Ah[kk4], bl, aacc[nt], 0, 0, 0);
            }
        }
        // relu + bias -> per-wave LDS chunk [16 rows][64 cols], hi only
        #pragma unroll
        for (int nt = 0; nt < 4; nt++){
            const int col = nt*16 + l15;
            const float bb = acb[c*64 + col];
            #pragma unroll
            for (int j = 0; j < 4; j++){
                const int row = lhi*4 + j;
                cb[(wave*16 + row)*72 + col] = f2bf(fmaxf(aacc[nt][j] + bb, 0.f));
            }
        }
        // query partial over this chunk (K=64), B = qW^T (coalesced [ck][e][k^])
        #pragma unroll
        for (int kk2 = 0; kk2 < 2; kk2++){
            const int kk = kk2*32 + lhi*8;
            const short8 qbh = *(const short8*)&g_qWhi[(c*2 + kk2)*512 + coff];
            const short8 qbl = *(const short8*)&g_qWlo[(c*2 + kk2)*512 + coff];
            const short8 qah = *(const short8*)&cb[(wave*16 + l15)*72 + kk];
            qacc = __builtin_amdgcn_mfma_f32_16x16x32_bf16(qah, qbh, qacc, 0, 0, 0);
            qacc = __builtin_amdgcn_mfma_f32_16x16x32_bf16(qah, qbl, qacc, 0, 0, 0);
        }
    }
    #pragma unroll
    for (int j = 0; j < 4; j++)
        qpart[wave*256 + (lhi*4 + j)*16 + l15] = qacc[j];
    __syncthreads();

    // value out
    if (tid < 16){
        float s = vb[0];
        #pragma unroll
        for (int w = 0; w < 8; w++) s += svred[w*16 + tid];
        out[B_*100 + r0 + tid] = s;
    }
    // finalize q (256 entries)
    if (tid < 256){
        int row = tid >> 4, e = tid & 15;
        float s = 0.f;
        #pragma unroll
        for (int w = 0; w < 8; w++) s += qpart[w*256 + row*16 + e];
        sq[row*17 + e] = tanhf(s);
    }
    for (int k = tid; k < 1600; k += 512) semb[k] = emb[k];
    __syncthreads();
    // logits
    for (int i = tid; i < 1600; i += 512){
        int row = i / 100, a = i - row*100;
        float s = abias[0];
        #pragma unroll
        for (int e = 0; e < 16; e++) s += sq[row*17 + e] * semb[a*16 + e];
        out[(r0 + row)*100 + a] = s;
    }
}

// ---------------- launch ----------------
extern "C" void kernel_launch(void* const* d_in, const int* in_sizes, int n_in,
                              void* d_out, int out_size, void* d_ws, size_t ws_size,
                              hipStream_t stream) {
    const int*   obs   = (const int*)  d_in[0];
    const float* maxv  = (const float*)d_in[1];
    const float* w1    = (const float*)d_in[2];
    const float* b1    = (const float*)d_in[3];
    const float* w2    = (const float*)d_in[4];
    const float* b2    = (const float*)d_in[5];
    const float* fc1w  = (const float*)d_in[6];
    const float* fc1b  = (const float*)d_in[7];
    const float* encw  = (const float*)d_in[8];
    const float* encb  = (const float*)d_in[9];
    const float* crw   = (const float*)d_in[10];
    const float* crb   = (const float*)d_in[11];
    const float* vw    = (const float*)d_in[12];
    const float* vb    = (const float*)d_in[13];
    const float* acw   = (const float*)d_in[14];
    const float* acb   = (const float*)d_in[15];
    const float* emb   = (const float*)d_in[16];
    const float* aW    = (const float*)d_in[17];
    const float* abias = (const float*)d_in[18];
    float* out = (float*)d_out;

    prep_kernel<<<1336, 256, 0, stream>>>(w1, maxv, w2, fc1w, encw, crw, acw, aW);
    conv1_kernel<<<B_/2, 256, 0, stream>>>(obs, b1);
    conv2_kernel<<<512, 256, 0, stream>>>(b2);
    tail_kernel<<<512, 512, 0, stream>>>(fc1b, encb, crb, vw, vb, acb, emb, abias, out);
}

// Round 24
// 99.522 us; speedup vs baseline: 2.7493x; 1.0582x over previous
//
#include <hip/hip_runtime.h>
#include <math.h>

#define B_ 8192

typedef __attribute__((ext_vector_type(8))) short short8;
typedef __attribute__((ext_vector_type(4))) float f32x4;

// ---------------- persistent device buffers (rewritten every call) ----------------
// ALL GEMM B-matrices stored wave-coalesced: [tile][kkc][r(16)][k^(32)] so one wave
// load = one contiguous 1KB block (lane addr = base + l15*64B + lhi*16B).
__device__ unsigned short g_w1p[51200];                    // conv1 [kc25][ng4][r][k^], /maxv, HI-ONLY
__device__ unsigned short g_w2hi[36864],  g_w2lo[36864];   // conv2 [kc9*ks2*nt4][r][k^] coalesced
__device__ unsigned short g_fc1hi[32768], g_fc1lo[32768];  // fc1   [tn8][kk8][r][k^] (k'=pos*64+oc)
__device__ unsigned short g_enchi[16384], g_enclo[16384];  // enc   [tn8][kk4][r][k^]
__device__ unsigned short g_crhi[131072], g_crlo[131072];  // critic[tn64][kk4][r][k^]
__device__ unsigned short g_achi[65536],  g_aclo[65536];   // actor [tn32][kk4][r][k^]
__device__ unsigned short g_qWhi[8192],   g_qWlo[8192];    // qW^T  [ck16][e16][k^32]
// activations
__device__ unsigned short g_ACT1hi[8192*1024];             // conv1 out [s][pos*64+oc], HI-ONLY

__device__ __forceinline__ unsigned short f2bf(float v){
    unsigned u = __builtin_bit_cast(unsigned, v);
    unsigned r = (u + 0x7fffu + ((u >> 16) & 1u)) >> 16;   // RN-even (finite inputs)
    return (unsigned short)r;
}
__device__ __forceinline__ float bf2f(unsigned short h){
    unsigned u = ((unsigned)h) << 16;
    return __builtin_bit_cast(float, u);
}
__device__ __forceinline__ void split_store(float v, unsigned short* hi, unsigned short* lo){
    unsigned short h = f2bf(v);
    *hi = h;
    *lo = f2bf(v - bf2f(h));
}

// ---------------- prep: transpose + split all weights ----------------
__global__ __launch_bounds__(256) void prep_kernel(
    const float* __restrict__ w1, const float* __restrict__ maxv,
    const float* __restrict__ w2, const float* __restrict__ fc1,
    const float* __restrict__ enc, const float* __restrict__ cr,
    const float* __restrict__ ac, const float* __restrict__ aW)
{
    int d = blockIdx.x * 256 + threadIdx.x;
    if (d < 51200){
        int n = d / 800, k = d - n*800;
        int l = k / 25;
        float v = w1[d] / maxv[l];
        int kc = k >> 5, kh = k & 31, ng = n >> 4, r = n & 15;
        int idx = ((kc*4 + ng)*16 + r)*32 + kh;
        g_w1p[idx] = f2bf(v);
        return;
    }
    d -= 51200;
    if (d < 36864){
        int oc = d / 576, k2 = d - oc*576;
        int kxy = k2 >> 6, ic = k2 & 63;
        float v = w2[oc*576 + ic*9 + kxy];
        int kc = k2 >> 6, ks = (k2 >> 5) & 1, kq = k2 & 31, nt = oc >> 4, r = oc & 15;
        int idx = (((kc*2 + ks)*4 + nt)*16 + r)*32 + kq;
        split_store(v, &g_w2hi[idx], &g_w2lo[idx]);
        return;
    }
    d -= 36864;
    if (d < 32768){
        int n = d >> 8, kp = d & 255;
        float v = fc1[n*256 + (kp & 63)*4 + (kp >> 6)];
        int idx = ((((n >> 4)*8) + (kp >> 5))*16 + (n & 15))*32 + (kp & 31);
        split_store(v, &g_fc1hi[idx], &g_fc1lo[idx]);
        return;
    }
    d -= 32768;
    if (d < 16384){
        int n = d >> 7, k = d & 127;
        int idx = ((((n >> 4)*4) + (k >> 5))*16 + (n & 15))*32 + (k & 31);
        split_store(enc[d], &g_enchi[idx], &g_enclo[idx]);
        return;
    }
    d -= 16384;
    if (d < 131072){
        int n = d >> 7, k = d & 127;
        int idx = ((((n >> 4)*4) + (k >> 5))*16 + (n & 15))*32 + (k & 31);
        split_store(cr[d], &g_crhi[idx], &g_crlo[idx]);
        return;
    }
    d -= 131072;
    if (d < 65536){
        int n = d >> 7, k = d & 127;
        int idx = ((((n >> 4)*4) + (k >> 5))*16 + (n & 15))*32 + (k & 31);
        split_store(ac[d], &g_achi[idx], &g_aclo[idx]);
        return;
    }
    d -= 65536;
    {
        int e = d >> 9, j = d & 511;
        int idx = ((j >> 5)*16 + e)*32 + (j & 31);
        split_store(aW[j*16 + e], &g_qWhi[idx], &g_qWlo[idx]);
    }
}

// ---------------- conv1: pack-max dedup + MFMA GEMM (hi-only B, hi-only ACT1 out) ---------
#define APITCH 808   // 800 + 8 shorts pad
__global__ __launch_bounds__(256) void conv1_kernel(const int* __restrict__ obs,
                                                    const float* __restrict__ b1)
{
    const int b = blockIdx.x;                 // samples b*2, b*2+1
    const int tid = threadIdx.x;
    const int wave = tid >> 6, lane = tid & 63;
    const int l15 = lane & 15, lhi = lane >> 4;

    __shared__ unsigned short sA[32 * APITCH];      // 51712 B; first 32KB doubles as wtab
    int* wtab = (int*)sA;                           // 8192-entry winner table (per pass)

    // ---- early B prefetch (addresses independent of data; flies during dedup) ----
    const unsigned short* Bh = &g_w1p[wave*512 + l15*32 + lhi*8];
    short8 bh0 = *(const short8*)&Bh[0*2048];
    short8 bh1 = *(const short8*)&Bh[1*2048];
    short8 bh2 = *(const short8*)&Bh[2*2048];
    short8 bh3 = *(const short8*)&Bh[3*2048];

    int   cells[2], xs[2], ys[2], ls[2];
    float vals[2];
    bool  valids[2], kept[2];
    #pragma unroll
    for (int u = 0; u < 2; u++){
        const int slot = tid + u*256;
        valids[u] = false; kept[u] = false; cells[u] = 0;
        if (slot < 400){
            const int si = (slot >= 200) ? 1 : 0;
            const int k  = slot - si*200;
            const int base = (b*2 + si)*600 + k*3;
            int coord = obs[base], atr = obs[base+1], val = obs[base+2];
            bool valid = (coord != 255) && (atr < 32);
            xs[u] = (coord >> 4) & 15;  ys[u] = coord & 15;  ls[u] = atr;
            cells[u] = valid ? (atr*256 + xs[u]*16 + ys[u]) : 0;   // invalid claims cell 0
            vals[u]  = (float)val;
            valids[u] = valid;
        }
    }
    // dedup pass A: sample 0
    if (tid < 200) wtab[cells[0]] = -1;
    __syncthreads();
    if (tid < 200) atomicMax(&wtab[cells[0]], tid);
    __syncthreads();
    if (tid < 200) kept[0] = (wtab[cells[0]] == tid);
    __syncthreads();
    // dedup pass B: sample 1
    if (tid >= 200) wtab[cells[0]] = -1;
    if (tid < 144)  wtab[cells[1]] = -1;
    __syncthreads();
    if (tid >= 200) atomicMax(&wtab[cells[0]], tid - 200);
    if (tid < 144)  atomicMax(&wtab[cells[1]], tid + 56);
    __syncthreads();
    if (tid >= 200) kept[0] = (wtab[cells[0]] == tid - 200);
    if (tid < 144)  kept[1] = (wtab[cells[1]] == tid + 56);
    __syncthreads();

    // zero A-tile (overwrites winner table)
    for (int i = tid; i < 4 * APITCH; i += 256)
        *(short8*)&sA[i * 8] = short8{0,0,0,0,0,0,0,0};
    __syncthreads();

    // scatter
    #pragma unroll
    for (int u = 0; u < 2; u++){
        const int slot = tid + u*256;
        if (slot < 400 && kept[u] && valids[u]){
            const int si = (slot >= 200) ? 1 : 0;
            const int x3 = xs[u]/3, rx = xs[u] - 3*x3;
            const int y3 = ys[u]/3, ry = ys[u] - 3*y3;
            const unsigned short hv = f2bf(vals[u]);     // exact (integer <= 255)
            #pragma unroll
            for (int d = 0; d < 4; d++){
                const int dxd = d >> 1, dyd = d & 1;
                const int ox = x3 - dxd, oy = y3 - dyd;
                const int wx = rx + 3*dxd, wy = ry + 3*dyd;
                if (((unsigned)ox <= 3u) && ((unsigned)oy <= 3u) && (wx < 5) && (wy < 5))
                    sA[(si*16 + ox*4 + oy)*APITCH + ls[u]*25 + wx*5 + wy] = hv;
            }
        }
    }
    __syncthreads();

    // MFMA K-loop: kc pairs, even/odd acc chains, 4-deep rolling prefetch, hi-only B
    const int n = wave*16 + l15;
    const unsigned short* A0 = &sA[l15*APITCH + lhi*8];
    const unsigned short* A1 = &sA[(16 + l15)*APITCH + lhi*8];
    f32x4 acc0e = {0,0,0,0}, acc1e = {0,0,0,0};
    f32x4 acc0o = {0,0,0,0}, acc1o = {0,0,0,0};
    #pragma unroll
    for (int kc2 = 0; kc2 < 12; kc2++){              // kc = 2*kc2, 2*kc2+1  (0..23)
        const int kc = kc2*2;
        short8 a0e = *(const short8*)&A0[kc*32];
        short8 a1e = *(const short8*)&A1[kc*32];
        short8 a0o = *(const short8*)&A0[(kc+1)*32];
        short8 a1o = *(const short8*)&A1[(kc+1)*32];
        short8 bhn0, bhn1;
        if (kc2 < 10){
            bhn0 = *(const short8*)&Bh[(kc + 4)*2048];
            bhn1 = *(const short8*)&Bh[(kc + 5)*2048];
        } else if (kc2 == 10){
            bhn0 = *(const short8*)&Bh[24*2048];
        }
        acc0e = __builtin_amdgcn_mfma_f32_16x16x32_bf16(a0e, bh0, acc0e, 0, 0, 0);
        acc1e = __builtin_amdgcn_mfma_f32_16x16x32_bf16(a1e, bh0, acc1e, 0, 0, 0);
        acc0o = __builtin_amdgcn_mfma_f32_16x16x32_bf16(a0o, bh1, acc0o, 0, 0, 0);
        acc1o = __builtin_amdgcn_mfma_f32_16x16x32_bf16(a1o, bh1, acc1o, 0, 0, 0);
        bh0 = bh2; bh1 = bh3; bh2 = bhn0; bh3 = bhn1;
    }
    {   // tail kc = 24 (in bh0 after 12 rotations)
        short8 a0e = *(const short8*)&A0[24*32];
        short8 a1e = *(const short8*)&A1[24*32];
        acc0e = __builtin_amdgcn_mfma_f32_16x16x32_bf16(a0e, bh0, acc0e, 0, 0, 0);
        acc1e = __builtin_amdgcn_mfma_f32_16x16x32_bf16(a1e, bh0, acc1e, 0, 0, 0);
    }
    f32x4 acc0, acc1;
    #pragma unroll
    for (int j = 0; j < 4; j++){ acc0[j] = acc0e[j] + acc0o[j]; acc1[j] = acc1e[j] + acc1o[j]; }

    const float bb = b1[n];
    #pragma unroll
    for (int j = 0; j < 4; j++){
        const int pos = lhi*4 + j;
        float v0 = fmaxf(acc0[j] + bb, 0.f);
        float v1 = fmaxf(acc1[j] + bb, 0.f);
        g_ACT1hi[(b*2    )*1024 + pos*64 + n] = f2bf(v0);
        g_ACT1hi[(b*2 + 1)*1024 + pos*64 + n] = f2bf(v1);
    }
}

// ---------------- tail: conv2+fc1+enc+critic+actor+query+logits fused, 8 waves ------------
// M=16 samples/block, 512 threads (8 waves), grid 512 -> 2 blocks/CU = 4 waves/SIMD.
// Phase 0 computes conv2 (M=64 rows, N=64, K=576, ACT1 hi-only A) directly into LDS sA1,
// eliminating the A1 global round-trip and one launch.
__global__ __launch_bounds__(512, 4) void tail_kernel(
    const float* __restrict__ b2,   const float* __restrict__ fc1b,
    const float* __restrict__ encb, const float* __restrict__ crb,
    const float* __restrict__ vw,   const float* __restrict__ vb,
    const float* __restrict__ acb,  const float* __restrict__ emb,
    const float* __restrict__ abias, float* __restrict__ out)
{
    const int r0 = blockIdx.x * 16;
    const int tid = threadIdx.x, wave = tid >> 6, lane = tid & 63;
    const int l15 = lane & 15, lhi = lane >> 4;
    const int coff = l15*32 + lhi*8;                     // coalesced lane offset

    __shared__ char smem[60736];
    unsigned short* sA1h = (unsigned short*)smem;                 // [16][264] 8448 B
    unsigned short* sA1l = (unsigned short*)(smem + 8448);        // 8448 B
    float*          qpart= (float*)smem;                          // [8][16][16] 8192 B (overlays dead sA1)
    unsigned short* sXh  = (unsigned short*)(smem + 16896);       // [16][136] 4352 B
    unsigned short* sXl  = (unsigned short*)(smem + 21248);
    unsigned short* sHh  = (unsigned short*)(smem + 25600);
    unsigned short* sHl  = (unsigned short*)(smem + 29952);
    unsigned short* cb   = (unsigned short*)(smem + 34304);       // [8][16][72] 18432 B
    float* sq    = (float*)(smem + 52736);                        // [16][17] 1088 B
    float* svred = (float*)(smem + 53824);                        // [8][16]  512 B
    float* semb  = (float*)(smem + 54336);                        // [1600]   6400 B

    // ---- phase 0: conv2 -> sA1 (LDS). Staging buffer overlays cb region ([64][72] hi). ----
    {
        unsigned short* sAh = cb;
        f32x4 c2acc[2] = {{0,0,0,0},{0,0,0,0}};
        const int srow = tid >> 3, sch8 = (tid & 7) * 8;       // 64 rows x 8 ch-units
        const int spx = (srow >> 1) & 1, spy = srow & 1;
        const int sbase = (r0 + (srow >> 2))*1024;
        for (int kc = 0; kc < 9; kc++){
            const int kx = kc / 3, ky = kc - 3*kx;
            __syncthreads();
            {
                const int cell = (spx + kx)*4 + (spy + ky);
                *(short8*)&sAh[srow*72 + sch8] = *(const short8*)&g_ACT1hi[sbase + cell*64 + sch8];
            }
            __syncthreads();
            #pragma unroll
            for (int wt = 0; wt < 2; wt++){
                const int tile = wave*2 + wt, mt = tile >> 2, nt = tile & 3;
                #pragma unroll
                for (int ks = 0; ks < 2; ks++){
                    const int kk = ks*32 + lhi*8;
                    short8 a = *(const short8*)&sAh[(mt*16 + l15)*72 + kk];
                    const int t = (kc*2 + ks)*4 + nt;
                    const short8 bh = *(const short8*)&g_w2hi[t*512 + coff];
                    const short8 bl = *(const short8*)&g_w2lo[t*512 + coff];
                    c2acc[wt] = __builtin_amdgcn_mfma_f32_16x16x32_bf16(a, bh, c2acc[wt], 0, 0, 0);
                    c2acc[wt] = __builtin_amdgcn_mfma_f32_16x16x32_bf16(a, bl, c2acc[wt], 0, 0, 0);
                }
            }
        }
        __syncthreads();   // staging reads done before epilogue (sA1 writes are separate region anyway)
        #pragma unroll
        for (int wt = 0; wt < 2; wt++){
            const int tile = wave*2 + wt, mt = tile >> 2, nt = tile & 3;
            const int col = nt*16 + l15;
            const float bb = b2[col];
            #pragma unroll
            for (int j = 0; j < 4; j++){
                const int row = mt*16 + lhi*4 + j;           // 0..63 = sample*4 + pos
                float v = fmaxf(c2acc[wt][j] + bb, 0.f);
                unsigned short h = f2bf(v);
                const int ai = (row >> 2)*264 + (row & 3)*64 + col;
                sA1h[ai] = h;
                sA1l[ai] = f2bf(v - bf2f(h));
            }
        }
    }
    __syncthreads();

    // ---- fc1: M=16, N=128 (wave owns n-tile = wave), K=256 -> sX ----
    {
        f32x4 acc = {0,0,0,0};
        const int n = wave*16 + l15;
        #pragma unroll
        for (int kk8 = 0; kk8 < 8; kk8++){
            const int kk = kk8*32 + lhi*8;
            short8 ah = *(const short8*)&sA1h[l15*264 + kk];
            short8 al = *(const short8*)&sA1l[l15*264 + kk];
            const short8 bh = *(const short8*)&g_fc1hi[(wave*8 + kk8)*512 + coff];
            const short8 bl = *(const short8*)&g_fc1lo[(wave*8 + kk8)*512 + coff];
            acc = __builtin_amdgcn_mfma_f32_16x16x32_bf16(ah, bh, acc, 0, 0, 0);
            acc = __builtin_amdgcn_mfma_f32_16x16x32_bf16(al, bh, acc, 0, 0, 0);
            acc = __builtin_amdgcn_mfma_f32_16x16x32_bf16(ah, bl, acc, 0, 0, 0);
        }
        __syncthreads();                      // sA1 reads done before qpart overlays later
        const float bb = fc1b[n];
        #pragma unroll
        for (int j = 0; j < 4; j++){
            const int row = lhi*4 + j;
            float v = fmaxf(acc[j] + bb, 0.f);
            unsigned short h = f2bf(v);
            sXh[row*136 + n] = h;
            sXl[row*136 + n] = f2bf(v - bf2f(h));
        }
    }
    __syncthreads();

    // ---- enc: M=16, N=128 (wave owns n-tile = wave), K=128 -> sH ----
    {
        f32x4 acc = {0,0,0,0};
        const int n = wave*16 + l15;
        #pragma unroll
        for (int kk4 = 0; kk4 < 4; kk4++){
            const int kk = kk4*32 + lhi*8;
            short8 ah = *(const short8*)&sXh[l15*136 + kk];
            short8 al = *(const short8*)&sXl[l15*136 + kk];
            const short8 bh = *(const short8*)&g_enchi[(wave*4 + kk4)*512 + coff];
            const short8 bl = *(const short8*)&g_enclo[(wave*4 + kk4)*512 + coff];
            acc = __builtin_amdgcn_mfma_f32_16x16x32_bf16(ah, bh, acc, 0, 0, 0);
            acc = __builtin_amdgcn_mfma_f32_16x16x32_bf16(al, bh, acc, 0, 0, 0);
            acc = __builtin_amdgcn_mfma_f32_16x16x32_bf16(ah, bl, acc, 0, 0, 0);
        }
        const float bb = encb[n];
        #pragma unroll
        for (int j = 0; j < 4; j++){
            const int row = lhi*4 + j;
            float v = fmaxf(acc[j] + bb, 0.f);
            unsigned short h = f2bf(v);
            sHh[row*136 + n] = h;
            sHl[row*136 + n] = f2bf(v - bf2f(h));
        }
    }
    __syncthreads();

    // ---- hoist H A-fragments (shared by critic and actor; K=128) ----
    short8 Ah[4], Al[4];
    #pragma unroll
    for (int kk4 = 0; kk4 < 4; kk4++){
        const int kk = kk4*32 + lhi*8;
        Ah[kk4] = *(const short8*)&sHh[l15*136 + kk];
        Al[kk4] = *(const short8*)&sHl[l15*136 + kk];
    }

    // ---- critic: wave owns 128 cols (8 n-tiles); chunks of 4; tanh + vw dot ----
    {
        float vp[4] = {0,0,0,0};
        #pragma unroll
        for (int ntc = 0; ntc < 2; ntc++){
            f32x4 cacc[4];
            #pragma unroll
            for (int q = 0; q < 4; q++) cacc[q] = f32x4{0,0,0,0};
            #pragma unroll
            for (int q = 0; q < 4; q++){
                const int t = wave*8 + ntc*4 + q;        // critic n-tile index
                #pragma unroll
                for (int kk4 = 0; kk4 < 4; kk4++){
                    const short8 bh = *(const short8*)&g_crhi[(t*4 + kk4)*512 + coff];
                    const short8 bl = *(const short8*)&g_crlo[(t*4 + kk4)*512 + coff];
                    cacc[q] = __builtin_amdgcn_mfma_f32_16x16x32_bf16(Ah[kk4], bh, cacc[q], 0, 0, 0);
                    cacc[q] = __builtin_amdgcn_mfma_f32_16x16x32_bf16(Al[kk4], bh, cacc[q], 0, 0, 0);
                    cacc[q] = __builtin_amdgcn_mfma_f32_16x16x32_bf16(Ah[kk4], bl, cacc[q], 0, 0, 0);
                }
            }
            #pragma unroll
            for (int q = 0; q < 4; q++){
                const int n = wave*128 + (ntc*4 + q)*16 + l15;
                const float w = vw[n], bb = crb[n];
                #pragma unroll
                for (int j = 0; j < 4; j++)
                    vp[j] += tanhf(cacc[q][j] + bb) * w;
            }
        }
        #pragma unroll
        for (int m = 1; m < 16; m <<= 1)
            #pragma unroll
            for (int j = 0; j < 4; j++) vp[j] += __shfl_xor(vp[j], m, 64);
        if (l15 == 0){
            #pragma unroll
            for (int j = 0; j < 4; j++)
                svred[wave*16 + lhi*4 + j] = vp[j];
        }
    }

    // ---- actor chunk (c = wave, 64 cols, hi-only LDS) + query mini-GEMM ----
    __syncthreads();    // cb region (conv2 staging) fully dead; reuse for actor chunks
    f32x4 qacc = {0,0,0,0};
    {
        const int c = wave;
        f32x4 aacc[4];
        #pragma unroll
        for (int nt = 0; nt < 4; nt++) aacc[nt] = f32x4{0,0,0,0};
        #pragma unroll
        for (int kk4 = 0; kk4 < 4; kk4++){
            #pragma unroll
            for (int nt = 0; nt < 4; nt++){
                const int t = c*4 + nt;                  // actor n-tile index
                const short8 bh = *(const short8*)&g_achi[(t*4 + kk4)*512 + coff];
                const short8 bl = *(const short8*)&g_aclo[(t*4 + kk4)*512 + coff];
                aacc[nt] = __builtin_amdgcn_mfma_f32_16x16x32_bf16(Ah[kk4], bh, aacc[nt], 0, 0, 0);
                aacc[nt] = __builtin_amdgcn_mfma_f32_16x16x32_bf16(Al[kk4], bh, aacc[nt], 0, 0, 0);
                aacc[nt] = __builtin_amdgcn_mfma_f32_16x16x32_bf16(Ah[kk4], bl, aacc[nt], 0, 0, 0);
            }
        }
        // relu + bias -> per-wave LDS chunk [16 rows][64 cols], hi only
        #pragma unroll
        for (int nt = 0; nt < 4; nt++){
            const int col = nt*16 + l15;
            const float bb = acb[c*64 + col];
            #pragma unroll
            for (int j = 0; j < 4; j++){
                const int row = lhi*4 + j;
                cb[(wave*16 + row)*72 + col] = f2bf(fmaxf(aacc[nt][j] + bb, 0.f));
            }
        }
        // query partial over this chunk (K=64), B = qW^T (coalesced [ck][e][k^])
        #pragma unroll
        for (int kk2 = 0; kk2 < 2; kk2++){
            const int kk = kk2*32 + lhi*8;
            const short8 qbh = *(const short8*)&g_qWhi[(c*2 + kk2)*512 + coff];
            const short8 qbl = *(const short8*)&g_qWlo[(c*2 + kk2)*512 + coff];
            const short8 qah = *(const short8*)&cb[(wave*16 + l15)*72 + kk];
            qacc = __builtin_amdgcn_mfma_f32_16x16x32_bf16(qah, qbh, qacc, 0, 0, 0);
            qacc = __builtin_amdgcn_mfma_f32_16x16x32_bf16(qah, qbl, qacc, 0, 0, 0);
        }
    }
    #pragma unroll
    for (int j = 0; j < 4; j++)
        qpart[wave*256 + (lhi*4 + j)*16 + l15] = qacc[j];
    __syncthreads();

    // value out
    if (tid < 16){
        float s = vb[0];
        #pragma unroll
        for (int w = 0; w < 8; w++) s += svred[w*16 + tid];
        out[B_*100 + r0 + tid] = s;
    }
    // finalize q (256 entries)
    if (tid < 256){
        int row = tid >> 4, e = tid & 15;
        float s = 0.f;
        #pragma unroll
        for (int w = 0; w < 8; w++) s += qpart[w*256 + row*16 + e];
        sq[row*17 + e] = tanhf(s);
    }
    for (int k = tid; k < 1600; k += 512) semb[k] = emb[k];
    __syncthreads();
    // logits
    for (int i = tid; i < 1600; i += 512){
        int row = i / 100, a = i - row*100;
        float s = abias[0];
        #pragma unroll
        for (int e = 0; e < 16; e++) s += sq[row*17 + e] * semb[a*16 + e];
        out[(r0 + row)*100 + a] = s;
    }
}

// ---------------- launch ----------------
extern "C" void kernel_launch(void* const* d_in, const int* in_sizes, int n_in,
                              void* d_out, int out_size, void* d_ws, size_t ws_size,
                              hipStream_t stream) {
    const int*   obs   = (const int*)  d_in[0];
    const float* maxv  = (const float*)d_in[1];
    const float* w1    = (const float*)d_in[2];
    const float* b1    = (const float*)d_in[3];
    const float* w2    = (const float*)d_in[4];
    const float* b2    = (const float*)d_in[5];
    const float* fc1w  = (const float*)d_in[6];
    const float* fc1b  = (const float*)d_in[7];
    const float* encw  = (const float*)d_in[8];
    const float* encb  = (const float*)d_in[9];
    const float* crw   = (const float*)d_in[10];
    const float* crb   = (const float*)d_in[11];
    const float* vw    = (const float*)d_in[12];
    const float* vb    = (const float*)d_in[13];
    const float* acw   = (const float*)d_in[14];
    const float* acb   = (const float*)d_in[15];
    const float* emb   = (const float*)d_in[16];
    const float* aW    = (const float*)d_in[17];
    const float* abias = (const float*)d_in[18];
    float* out = (float*)d_out;

    prep_kernel<<<1336, 256, 0, stream>>>(w1, maxv, w2, fc1w, encw, crw, acw, aW);
    conv1_kernel<<<B_/2, 256, 0, stream>>>(obs, b1);
    tail_kernel<<<512, 512, 0, stream>>>(b2, fc1b, encb, crb, vw, vb, acb, emb, abias, out);
}